// Round 2
// baseline (4999.216 us; speedup 1.0000x reference)
//
#include <hip/hip_runtime.h>
#include <hip/hip_bf16.h>
#include <math.h>

// Problem constants (from reference setup_inputs)
constexpr int BSZ   = 16;
constexpr int NDET  = 48;
constexpr int PAIRS = NDET * (NDET - 1);      // 2256
constexpr int ROWS  = BSZ * PAIRS;            // 36096
constexpr int DF    = 2048;
constexpr int DH    = 1024;
constexpr int DE    = 512;
constexpr int EHALF = 256;
constexpr int NCLS  = 92;
constexpr int LABW  = 1 + 92 + 40;            // 133

struct Accum {
    double s_pos;
    double s_neg;
    double s_dist;
    int    c_pos;
    int    c_neg;
};

__global__ void zero_accum_kernel(Accum* a) {
    a->s_pos = 0.0; a->s_neg = 0.0; a->s_dist = 0.0;
    a->c_pos = 0;   a->c_neg = 0;
}

// ---------------------------------------------------------------------------
// Generic fp32 SGEMM: C[M,N] = act(A[M,K] @ B[K,N] (+ bias)).
// 64x64 tile, BK=16, 256 threads, 4x4 per thread. N%64==0 required; M and K
// arbitrary (guarded). Round-1 correctness kernel; MFMA comes later.
// ---------------------------------------------------------------------------
template <bool BIAS, bool RELU>
__global__ __launch_bounds__(256) void sgemm64(
    const float* __restrict__ A, const float* __restrict__ B,
    const float* __restrict__ bias, float* __restrict__ C,
    int M, int N, int K)
{
    __shared__ float As[16][68];
    __shared__ float Bs[16][64];

    const int tid = threadIdx.x;
    const int n0 = blockIdx.x * 64;
    const int m0 = blockIdx.y * 64;
    const int tx = tid & 15;        // 16 col-groups of 4
    const int ty = tid >> 4;        // 16 row-groups of 4

    float acc[4][4] = {};

    for (int k0 = 0; k0 < K; k0 += 16) {
        // A tile: 64 rows x 16 k (k fastest within a row => 64B runs).
#pragma unroll
        for (int i = 0; i < 4; ++i) {
            int e  = i * 256 + tid;
            int m  = e >> 4;
            int kk = e & 15;
            int kg = k0 + kk;
            As[kk][m] = (kg < K && (m0 + m) < M) ? A[(size_t)(m0 + m) * K + kg] : 0.0f;
        }
        // B tile: 16 k x 64 n (n fastest => fully coalesced).
#pragma unroll
        for (int i = 0; i < 4; ++i) {
            int e  = i * 256 + tid;
            int kk = e >> 6;
            int nn = e & 63;
            int kg = k0 + kk;
            Bs[kk][nn] = (kg < K) ? B[(size_t)kg * N + n0 + nn] : 0.0f;
        }
        __syncthreads();

#pragma unroll
        for (int kk = 0; kk < 16; ++kk) {
            float a0 = As[kk][ty * 4 + 0];
            float a1 = As[kk][ty * 4 + 1];
            float a2 = As[kk][ty * 4 + 2];
            float a3 = As[kk][ty * 4 + 3];
            float b0 = Bs[kk][tx * 4 + 0];
            float b1v = Bs[kk][tx * 4 + 1];
            float b2v = Bs[kk][tx * 4 + 2];
            float b3 = Bs[kk][tx * 4 + 3];
            acc[0][0] += a0 * b0;  acc[0][1] += a0 * b1v;  acc[0][2] += a0 * b2v;  acc[0][3] += a0 * b3;
            acc[1][0] += a1 * b0;  acc[1][1] += a1 * b1v;  acc[1][2] += a1 * b2v;  acc[1][3] += a1 * b3;
            acc[2][0] += a2 * b0;  acc[2][1] += a2 * b1v;  acc[2][2] += a2 * b2v;  acc[2][3] += a2 * b3;
            acc[3][0] += a3 * b0;  acc[3][1] += a3 * b1v;  acc[3][2] += a3 * b2v;  acc[3][3] += a3 * b3;
        }
        __syncthreads();
    }

#pragma unroll
    for (int i = 0; i < 4; ++i) {
        int m = m0 + ty * 4 + i;
        if (m >= M) continue;
#pragma unroll
        for (int j = 0; j < 4; ++j) {
            float v = acc[i][j];
            int n = n0 + tx * 4 + j;
            if (BIAS) v += bias[n];
            if (RELU) v = fmaxf(v, 0.0f);
            C[(size_t)m * N + n] = v;
        }
    }
}

// ---------------------------------------------------------------------------
// h1[r_local,:] = relu(U[b*48+s,:] + V[b*48+o,:] + b1)
// r_global = b0*PAIRS + r_local
// ---------------------------------------------------------------------------
__global__ __launch_bounds__(256) void pairs_kernel(
    const float* __restrict__ U, const float* __restrict__ V,
    const float* __restrict__ b1,
    const int* __restrict__ sids, const int* __restrict__ oids,
    float* __restrict__ h1, int b0)
{
    int r = blockIdx.x;                 // local row within chunk
    int b = b0 + r / PAIRS;
    int p = r % PAIRS;
    int s = sids[p];
    int o = oids[p];
    const float4* u  = (const float4*)(U + (size_t)(b * NDET + s) * DH);
    const float4* v  = (const float4*)(V + (size_t)(b * NDET + o) * DH);
    const float4* bb = (const float4*)b1;
    float4* out = (float4*)(h1 + (size_t)r * DH);

    int j = threadIdx.x;   // 256 threads * float4 = 1024 elems
    float4 x = u[j], y = v[j], z = bb[j];
    float4 h;
    h.x = fmaxf(x.x + y.x + z.x, 0.0f);
    h.y = fmaxf(x.y + y.y + z.y, 0.0f);
    h.z = fmaxf(x.z + y.z + z.z, 0.0f);
    h.w = fmaxf(x.w + y.w + z.w, 0.0f);
    out[j] = h;
}

// ---------------------------------------------------------------------------
// distil partial: sum |concat(traj[b,s], traj[b,o]) - so_proj[r_local]|
// ---------------------------------------------------------------------------
__global__ __launch_bounds__(256) void distil_kernel(
    const float* __restrict__ traj, const float* __restrict__ so_proj,
    const int* __restrict__ sids, const int* __restrict__ oids,
    Accum* acc, int b0)
{
    int r = blockIdx.x;
    int tid = threadIdx.x;
    int b = b0 + r / PAIRS;
    int p = r % PAIRS;
    int s = sids[p];
    int o = oids[p];
    const float* ts  = traj + (size_t)(b * NDET + s) * EHALF;
    const float* to  = traj + (size_t)(b * NDET + o) * EHALF;
    const float* row = so_proj + (size_t)r * DE;

    float v = fabsf(ts[tid] - row[tid]) + fabsf(to[tid] - row[EHALF + tid]);

    __shared__ float red[256];
    red[tid] = v;
    __syncthreads();
    for (int st = 128; st > 0; st >>= 1) {
        if (tid < st) red[tid] += red[tid + st];
        __syncthreads();
    }
    if (tid == 0) atomicAdd(&acc->s_dist, (double)red[0]);
}

// ---------------------------------------------------------------------------
// Per row: normalize so_proj & re_un, combine+normalize, 92 classifier dots,
// focal losses, masked accumulation. One 128-thread block per row.
// ---------------------------------------------------------------------------
__global__ __launch_bounds__(128) void combine_loss_kernel(
    const float* __restrict__ so_proj, const float* __restrict__ re_un,
    const float* __restrict__ cw, const int* __restrict__ labels,
    const float* __restrict__ temperature, Accum* acc, int r0_global)
{
    int r = blockIdx.x;                 // local
    int tid = threadIdx.x;
    __shared__ float comb[DE];
    __shared__ float red[128];
    __shared__ float redB[128];
    __shared__ int   redI[128];

    const float* sp = so_proj + (size_t)r * DE;
    const float* ru = re_un   + (size_t)r * DE;

    float ss = 0.0f, sr = 0.0f;
    for (int j = tid; j < DE; j += 128) {
        float a = sp[j]; ss += a * a;
        float b = ru[j]; sr += b * b;
    }
    red[tid] = ss; redB[tid] = sr;
    __syncthreads();
    for (int st = 64; st > 0; st >>= 1) {
        if (tid < st) { red[tid] += red[tid + st]; redB[tid] += redB[tid + st]; }
        __syncthreads();
    }
    float inv_s = 1.0f / fmaxf(sqrtf(red[0]),  1e-12f);
    float inv_r = 1.0f / fmaxf(sqrtf(redB[0]), 1e-12f);
    __syncthreads();

    float sc = 0.0f;
    for (int j = tid; j < DE; j += 128) {
        float c = sp[j] * inv_s + ru[j] * inv_r;
        comb[j] = c;
        sc += c * c;
    }
    red[tid] = sc;
    __syncthreads();
    for (int st = 64; st > 0; st >>= 1) {
        if (tid < st) red[tid] += red[tid + st];
        __syncthreads();
    }
    float inv_c = 1.0f / fmaxf(sqrtf(red[0]), 1e-12f);
    float scale = inv_c / temperature[0];
    __syncthreads();

    float flp = 0.0f, fln = 0.0f;
    int myt = 0;
    size_t labbase = (size_t)(r0_global + r) * LABW;
    if (tid < NCLS) {
        const float4* c4 = (const float4*)comb;
        const float4* w4 = (const float4*)(cw + (size_t)tid * DE);
        float dot = 0.0f;
#pragma unroll 4
        for (int j = 0; j < DE / 4; ++j) {
            float4 a = c4[j], b = w4[j];
            dot += a.x * b.x + a.y * b.y + a.z * b.z + a.w * b.w;
        }
        float l = dot * scale;
        int t = labels[labbase + 1 + tid];
        myt = (t > 0) ? 1 : 0;
        float tf = (float)t;
        float p  = 1.0f / (1.0f + expf(-l));
        float lg = log1pf(expf(-fabsf(l)));
        float ce = fmaxf(l, 0.0f) - l * tf + lg;
        float pt = p * tf + (1.0f - p) * (1.0f - tf);
        float om = 1.0f - pt;
        float at = 0.25f * tf + 0.75f * (1.0f - tf);
        flp = at * ce * om * om;
        float ce0 = fmaxf(l, 0.0f) + lg;
        fln = 0.75f * ce0 * p * p;
    }
    red[tid] = flp; redB[tid] = fln; redI[tid] = myt;
    __syncthreads();
    for (int st = 64; st > 0; st >>= 1) {
        if (tid < st) {
            red[tid]  += red[tid + st];
            redB[tid] += redB[tid + st];
            redI[tid] += redI[tid + st];
        }
        __syncthreads();
    }
    if (tid == 0) {
        if (redI[0] > 0) {
            atomicAdd(&acc->s_pos, (double)red[0]);
            atomicAdd(&acc->c_pos, 1);
        }
        if (labels[labbase] > 0) {
            atomicAdd(&acc->s_neg, (double)redB[0]);
            atomicAdd(&acc->c_neg, 1);
        }
    }
}

__global__ void finalize_kernel(const Accum* __restrict__ acc, float* __restrict__ out) {
    int cp = acc->c_pos < 1 ? 1 : acc->c_pos;
    int cn = acc->c_neg < 1 ? 1 : acc->c_neg;
    double pos_loss = acc->s_pos / ((double)cp * (double)NCLS);
    double neg_loss = acc->s_neg / ((double)cn * (double)NCLS);
    double distil   = acc->s_dist / ((double)ROWS * (double)DE);
    out[0] = (float)(pos_loss + neg_loss + distil);
}

extern "C" void kernel_launch(void* const* d_in, const int* in_sizes, int n_in,
                              void* d_out, int out_size, void* d_ws, size_t ws_size,
                              hipStream_t stream)
{
    const float* det    = (const float*)d_in[0];   // (16,48,2048)
    const float* traj   = (const float*)d_in[1];   // (16,48,256)
    const float* relpos = (const float*)d_in[2];   // (16,2256,12)
    const float* cw     = (const float*)d_in[3];   // (92,512)
    const float* W1     = (const float*)d_in[4];   // (4096,1024)
    const float* b1     = (const float*)d_in[5];   // (1024,)
    const float* W2     = (const float*)d_in[6];   // (1024,1024)
    const float* b2     = (const float*)d_in[7];   // (1024,)
    const float* W3     = (const float*)d_in[8];   // (1024,512)
    const float* R1     = (const float*)d_in[9];   // (12,256)
    const float* rb1    = (const float*)d_in[10];  // (256,)
    const float* R2     = (const float*)d_in[11];  // (256,512)
    const float* temp   = (const float*)d_in[12];  // (1,)
    const int*   labels = (const int*)d_in[13];    // (16,2256,133)
    const int*   sids   = (const int*)d_in[14];    // (2256,)
    const int*   oids   = (const int*)d_in[15];    // (2256,)
    float* out = (float*)d_out;

    // ---- Adaptive workspace layout (R0 crashed on ws overflow: needed 296MB
    // unconditionally). Pick the largest batches-per-chunk B_CH whose
    // footprint fits ws_size:
    //   256B accum | U (768x1024) | V (768x1024) | region1 | region2
    // region1/2 are each B_CH*2256*1024 floats.
    //   region1: h1  -> then so_proj (x512) @ +0, rh (x256) @ +512*rows
    //   region2: h2  -> then re_un (x512)
    // Footprints: B_CH=1:25MB, 2:43MB, 4:80MB, 8:154MB, 16:302MB.
    constexpr size_t UV_FLOATS = (size_t)BSZ * NDET * DH;  // 786432 each
    int b_ch = 1;
    for (int cand : {16, 8, 4, 2, 1}) {
        size_t rows = (size_t)cand * PAIRS;
        size_t bytes = 256 + 2 * UV_FLOATS * 4 + 2 * rows * DH * 4;
        if (bytes <= ws_size) { b_ch = cand; break; }
    }
    const int chunk_rows = b_ch * PAIRS;
    const int n_chunks = BSZ / b_ch;

    char* ws = (char*)d_ws;
    Accum* acc = (Accum*)ws;
    float* U = (float*)(ws + 256);
    float* V = U + UV_FLOATS;
    float* region1 = V + UV_FLOATS;
    float* region2 = region1 + (size_t)chunk_rows * DH;

    float* h1      = region1;
    float* h2      = region2;
    float* so_proj = region1;                               // chunk_rows x 512
    float* rh      = region1 + (size_t)chunk_rows * DE;     // chunk_rows x 256
    float* re_un   = region2;                               // chunk_rows x 512

    zero_accum_kernel<<<1, 1, 0, stream>>>(acc);

    // U = det2d @ W1[0:2048], V = det2d @ W1[2048:4096]   (768x2048x1024 each)
    sgemm64<false, false><<<dim3(DH / 64, (BSZ * NDET + 63) / 64), 256, 0, stream>>>(
        det, W1, nullptr, U, BSZ * NDET, DH, DF);
    sgemm64<false, false><<<dim3(DH / 64, (BSZ * NDET + 63) / 64), 256, 0, stream>>>(
        det, W1 + (size_t)DF * DH, nullptr, V, BSZ * NDET, DH, DF);

    const int mg = (chunk_rows + 63) / 64;   // GEMM grid rows per chunk

    for (int c = 0; c < n_chunks; ++c) {
        int b0 = c * b_ch;
        int r0 = b0 * PAIRS;

        // h1 = relu(U[s] + V[o] + b1)
        pairs_kernel<<<chunk_rows, 256, 0, stream>>>(U, V, b1, sids, oids, h1, b0);

        // h2 = relu(h1 @ W2 + b2)            (chunk_rows x 1024 x 1024)
        sgemm64<true, true><<<dim3(DH / 64, mg), 256, 0, stream>>>(
            h1, W2, b2, h2, chunk_rows, DH, DH);

        // so_proj = h2 @ W3                  (chunk_rows x 1024 -> 512)
        sgemm64<false, false><<<dim3(DE / 64, mg), 256, 0, stream>>>(
            h2, W3, nullptr, so_proj, chunk_rows, DE, DH);

        // rh = relu(relpos @ R1 + rb1)       (chunk_rows x 12 -> 256)
        sgemm64<true, true><<<dim3(256 / 64, mg), 256, 0, stream>>>(
            relpos + (size_t)r0 * 12, R1, rb1, rh, chunk_rows, 256, 12);

        // re_un = rh @ R2                    (chunk_rows x 256 -> 512)
        sgemm64<false, false><<<dim3(DE / 64, mg), 256, 0, stream>>>(
            rh, R2, nullptr, re_un, chunk_rows, DE, 256);

        // losses for this chunk
        distil_kernel<<<chunk_rows, 256, 0, stream>>>(traj, so_proj, sids, oids, acc, b0);
        combine_loss_kernel<<<chunk_rows, 128, 0, stream>>>(so_proj, re_un, cw, labels, temp, acc, r0);
    }

    finalize_kernel<<<1, 1, 0, stream>>>(acc, out);
}

// Round 3
// 1285.472 us; speedup vs baseline: 3.8890x; 3.8890x over previous
//
#include <hip/hip_runtime.h>
#include <math.h>

// Problem constants
constexpr int BSZ   = 16;
constexpr int NDET  = 48;
constexpr int PAIRS = NDET * (NDET - 1);      // 2256
constexpr int ROWS  = BSZ * PAIRS;            // 36096
constexpr int DF    = 2048;
constexpr int DH    = 1024;
constexpr int DE    = 512;
constexpr int EHALF = 256;
constexpr int NCLS  = 92;
constexpr int LABW  = 1 + 92 + 40;            // 133

typedef __attribute__((ext_vector_type(8))) short bf16x8;   // 8 bf16 in 4 VGPRs
typedef __attribute__((ext_vector_type(4))) float f32x4;

__device__ __forceinline__ short f2bf(float f) {
    union { float f; unsigned u; } a; a.f = f;
    unsigned r = a.u + 0x7fffu + ((a.u >> 16) & 1u);   // RNE
    return (short)(r >> 16);
}

// ---------------------------------------------------------------------------
// fp32 -> bf16 elementwise (vectorized float4 -> short4). n4 = elems/4.
// ---------------------------------------------------------------------------
__global__ __launch_bounds__(256) void convert_bf16_kernel(
    const float* __restrict__ src, short* __restrict__ dst, int n4)
{
    int i = blockIdx.x * 256 + threadIdx.x;
    if (i >= n4) return;
    float4 v = ((const float4*)src)[i];
    short4 o;
    o.x = f2bf(v.x); o.y = f2bf(v.y); o.z = f2bf(v.z); o.w = f2bf(v.w);
    ((short4*)dst)[i] = o;
}

// ---------------------------------------------------------------------------
// Transpose + convert: src fp32 [K][N] -> dst bf16 [N][K]. K,N multiples of 32.
// ---------------------------------------------------------------------------
__global__ __launch_bounds__(256) void transpose_bf16_kernel(
    const float* __restrict__ src, short* __restrict__ dst, int K, int N)
{
    __shared__ float tile[32][33];
    int n0 = blockIdx.x * 32, k0 = blockIdx.y * 32;
    int tx = threadIdx.x & 31, ty = threadIdx.x >> 5;   // 32 x 8
#pragma unroll
    for (int i = ty; i < 32; i += 8)
        tile[i][tx] = src[(size_t)(k0 + i) * N + n0 + tx];
    __syncthreads();
#pragma unroll
    for (int i = ty; i < 32; i += 8)
        dst[(size_t)(n0 + i) * K + k0 + tx] = f2bf(tile[tx][i]);
}

// ---------------------------------------------------------------------------
// MFMA bf16 GEMM (m97 structure): C[M,N] = act(A[M,K] @ B[K,N] (+bias)).
// A bf16 row-major [M,K]; Bt bf16 [N,K] (B transposed). N%128==0, K%32==0;
// M arbitrary (clamped staging + guarded store). 128x128 tile, BK=32,
// 256 threads = 4 waves, each wave a 64x64 quadrant of 4x4 16x16x32 MFMAs.
// ---------------------------------------------------------------------------
__device__ __forceinline__ void load16_lds(const void* g, void* l) {
    __builtin_amdgcn_global_load_lds(
        (const __attribute__((address_space(1))) unsigned int*)g,
        (__attribute__((address_space(3))) unsigned int*)l, 16, 0, 0);
}

template <bool BIAS, bool RELU, bool OUTBF16>
__global__ __launch_bounds__(256) void mfma_gemm(
    const short* __restrict__ A, const short* __restrict__ Bt,
    const float* __restrict__ bias, void* __restrict__ C,
    int M, int N, int K)
{
    __shared__ short As[128 * 32];
    __shared__ short Bs[128 * 32];

    const int tid  = threadIdx.x;
    const int wave = tid >> 6;
    const int lane = tid & 63;
    const int m0 = blockIdx.y * 128;
    const int n0 = blockIdx.x * 128;
    const int wm = (wave & 1) * 64;
    const int wn = (wave >> 1) * 64;

    f32x4 acc[4][4] = {};

    const int q  = lane >> 4;     // quad 0..3
    const int lm = lane & 15;

    for (int k0 = 0; k0 < K; k0 += 32) {
        // Stage A and Bt tiles (128 rows x 32 k, bf16) via LDS-DMA, 16B/lane.
        // chunk c = it*256 + tid -> row c>>2, k-sub (c&3)*8; LDS dest is
        // wave-uniform base + lane*16 (contiguous row-major) per m104/m108.
#pragma unroll
        for (int it = 0; it < 2; ++it) {
            int c   = it * 256 + tid;
            int row = c >> 2;
            int kk  = (c & 3) * 8;
            int ldsc = (it * 256 + wave * 64) * 8;  // wave-uniform chunk base (elems)
            int gm = m0 + row; if (gm >= M) gm = M - 1;   // clamp: stays in-bounds
            load16_lds(A + (size_t)gm * K + k0 + kk, (short*)As + ldsc);
            int gn = n0 + row;                             // N%128==0: no tail
            load16_lds(Bt + (size_t)gn * K + k0 + kk, (short*)Bs + ldsc);
        }
        __syncthreads();   // compiler emits vmcnt(0) drain before barrier

        bf16x8 af[4], bfr[4];
#pragma unroll
        for (int t = 0; t < 4; ++t) {
            af[t]  = *(const bf16x8*)(As + (wm + t * 16 + lm) * 32 + q * 8);
            bfr[t] = *(const bf16x8*)(Bs + (wn + t * 16 + lm) * 32 + q * 8);
        }
#pragma unroll
        for (int tm = 0; tm < 4; ++tm)
#pragma unroll
            for (int tn = 0; tn < 4; ++tn)
                acc[tm][tn] = __builtin_amdgcn_mfma_f32_16x16x32_bf16(
                    af[tm], bfr[tn], acc[tm][tn], 0, 0, 0);
        __syncthreads();
    }

    // Epilogue: C/D layout col=lane&15, row=(lane>>4)*4+reg (m89-verified)
#pragma unroll
    for (int tm = 0; tm < 4; ++tm) {
#pragma unroll
        for (int tn = 0; tn < 4; ++tn) {
            int col = n0 + wn + tn * 16 + lm;
#pragma unroll
            for (int r = 0; r < 4; ++r) {
                int row = m0 + wm + tm * 16 + q * 4 + r;
                if (row < M) {
                    float v = acc[tm][tn][r];
                    if (BIAS) v += bias[col];
                    if (RELU) v = fmaxf(v, 0.0f);
                    if (OUTBF16) ((short*)C)[(size_t)row * N + col] = f2bf(v);
                    else         ((float*)C)[(size_t)row * N + col] = v;
                }
            }
        }
    }
}

// ---------------------------------------------------------------------------
// h1[r,:] = bf16(relu(UV[b*48+s, 0:1024] + UV[b*48+o, 1024:2048] + b1))
// ---------------------------------------------------------------------------
__global__ __launch_bounds__(256) void pairs_kernel(
    const float* __restrict__ UV, const float* __restrict__ b1,
    const int* __restrict__ sids, const int* __restrict__ oids,
    short* __restrict__ h1, int b0)
{
    int r = blockIdx.x;
    int b = b0 + r / PAIRS;
    int p = r % PAIRS;
    const float4* u  = (const float4*)(UV + (size_t)(b * NDET + sids[p]) * 2048);
    const float4* v  = (const float4*)(UV + (size_t)(b * NDET + oids[p]) * 2048 + 1024);
    const float4* bb = (const float4*)b1;
    int j = threadIdx.x;              // 256 threads x 4 elems = 1024
    float4 x = u[j], y = v[j], z = bb[j];
    short4 h;
    h.x = f2bf(fmaxf(x.x + y.x + z.x, 0.0f));
    h.y = f2bf(fmaxf(x.y + y.y + z.y, 0.0f));
    h.z = f2bf(fmaxf(x.z + y.z + z.z, 0.0f));
    h.w = f2bf(fmaxf(x.w + y.w + z.w, 0.0f));
    ((short4*)(h1 + (size_t)r * DH))[j] = h;
}

// ---------------------------------------------------------------------------
// rh[r,j] = bf16(relu(sum_k rp[r,k]*R1[k,j] + rb1[j]))  (K=12, one block/row)
// ---------------------------------------------------------------------------
__global__ __launch_bounds__(256) void rh_kernel(
    const float* __restrict__ rp, const float* __restrict__ R1,
    const float* __restrict__ rb1, short* __restrict__ rh, int r0)
{
    int r = blockIdx.x;
    int j = threadIdx.x;              // 256 = output width
    const float* row = rp + (size_t)(r0 + r) * 12;
    float acc = rb1[j];
#pragma unroll
    for (int k = 0; k < 12; ++k) acc = fmaf(row[k], R1[k * 256 + j], acc);
    rh[(size_t)r * 256 + j] = f2bf(fmaxf(acc, 0.0f));
}

// ---------------------------------------------------------------------------
// Fused per-row loss: norms, combine, 92 classifier dots, focal, distil.
// Writes float4 partial (pos, neg, dist, flags) — NO global atomics.
// ---------------------------------------------------------------------------
__global__ __launch_bounds__(128) void loss_kernel(
    const float* __restrict__ so_proj, const float* __restrict__ re_un,
    const float* __restrict__ traj, const float* __restrict__ cw,
    const int* __restrict__ labels, const float* __restrict__ temperature,
    const int* __restrict__ sids, const int* __restrict__ oids,
    float4* __restrict__ partials, int b0)
{
    int r   = blockIdx.x;             // local row in chunk
    int tid = threadIdx.x;
    int rg  = b0 * PAIRS + r;         // global row
    int b   = b0 + r / PAIRS;
    int p   = r % PAIRS;

    const float* sp = so_proj + (size_t)r * DE;
    const float* ru = re_un   + (size_t)r * DE;
    const float* ts = traj + (size_t)(b * NDET + sids[p]) * EHALF;
    const float* to = traj + (size_t)(b * NDET + oids[p]) * EHALF;

    __shared__ float comb[DE];
    __shared__ float redA[128], redB[128], redC[128];

    float ss = 0.0f, sr = 0.0f, sd = 0.0f;
    for (int j = tid; j < DE; j += 128) {
        float a = sp[j]; ss += a * a;
        float c = ru[j]; sr += c * c;
    }
    for (int j = tid; j < EHALF; j += 128)
        sd += fabsf(ts[j] - sp[j]) + fabsf(to[j] - sp[EHALF + j]);

    redA[tid] = ss; redB[tid] = sr; redC[tid] = sd;
    __syncthreads();
    for (int st = 64; st > 0; st >>= 1) {
        if (tid < st) { redA[tid] += redA[tid + st]; redB[tid] += redB[tid + st]; redC[tid] += redC[tid + st]; }
        __syncthreads();
    }
    float inv_s = 1.0f / fmaxf(sqrtf(redA[0]), 1e-12f);
    float inv_r = 1.0f / fmaxf(sqrtf(redB[0]), 1e-12f);
    float dist_sum = redC[0];
    __syncthreads();

    float sc = 0.0f;
    for (int j = tid; j < DE; j += 128) {
        float c = sp[j] * inv_s + ru[j] * inv_r;
        comb[j] = c;
        sc += c * c;
    }
    redA[tid] = sc;
    __syncthreads();
    for (int st = 64; st > 0; st >>= 1) {
        if (tid < st) redA[tid] += redA[tid + st];
        __syncthreads();
    }
    float scale = (1.0f / fmaxf(sqrtf(redA[0]), 1e-12f)) / temperature[0];
    __syncthreads();

    float flp = 0.0f, fln = 0.0f;
    int myt = 0;
    size_t labbase = (size_t)rg * LABW;
    if (tid < NCLS) {
        const float4* c4 = (const float4*)comb;
        const float4* w4 = (const float4*)(cw + (size_t)tid * DE);
        float dot = 0.0f;
#pragma unroll 4
        for (int j = 0; j < DE / 4; ++j) {
            float4 a = c4[j], w = w4[j];
            dot += a.x * w.x + a.y * w.y + a.z * w.z + a.w * w.w;
        }
        float l = dot * scale;
        int t = labels[labbase + 1 + tid];
        myt = (t > 0) ? 1 : 0;
        float tf = (float)t;
        float pr = 1.0f / (1.0f + expf(-l));
        float lg = log1pf(expf(-fabsf(l)));
        float ce = fmaxf(l, 0.0f) - l * tf + lg;
        float pt = pr * tf + (1.0f - pr) * (1.0f - tf);
        float om = 1.0f - pt;
        float at = 0.25f * tf + 0.75f * (1.0f - tf);
        flp = at * ce * om * om;
        float ce0 = fmaxf(l, 0.0f) + lg;
        fln = 0.75f * ce0 * pr * pr;
    }
    redA[tid] = flp; redB[tid] = fln; redC[tid] = (float)myt;
    __syncthreads();
    for (int st = 64; st > 0; st >>= 1) {
        if (tid < st) { redA[tid] += redA[tid + st]; redB[tid] += redB[tid + st]; redC[tid] += redC[tid + st]; }
        __syncthreads();
    }
    if (tid == 0) {
        int posf = (redC[0] > 0.5f) ? 1 : 0;
        int negf = (labels[labbase] > 0) ? 1 : 0;
        partials[rg] = make_float4(posf ? redA[0] : 0.0f,
                                   negf ? redB[0] : 0.0f,
                                   dist_sum,
                                   (float)(posf + 2 * negf));
    }
}

// ---------------------------------------------------------------------------
// Final reduce: one block, 256 threads over ROWS float4 partials.
// ---------------------------------------------------------------------------
__global__ __launch_bounds__(256) void reduce_kernel(
    const float4* __restrict__ partials, float* __restrict__ out)
{
    int tid = threadIdx.x;
    double sp = 0.0, sn = 0.0, sd = 0.0;
    int cp = 0, cn = 0;
    for (int i = tid; i < ROWS; i += 256) {
        float4 v = partials[i];
        sp += (double)v.x; sn += (double)v.y; sd += (double)v.z;
        int f = (int)v.w;
        cp += f & 1; cn += (f >> 1) & 1;
    }
    __shared__ double A[256], B[256], C[256];
    __shared__ int I[256], J[256];
    A[tid] = sp; B[tid] = sn; C[tid] = sd; I[tid] = cp; J[tid] = cn;
    __syncthreads();
    for (int st = 128; st > 0; st >>= 1) {
        if (tid < st) { A[tid] += A[tid + st]; B[tid] += B[tid + st]; C[tid] += C[tid + st];
                        I[tid] += I[tid + st]; J[tid] += J[tid + st]; }
        __syncthreads();
    }
    if (tid == 0) {
        int cpv = I[0] < 1 ? 1 : I[0];
        int cnv = J[0] < 1 ? 1 : J[0];
        out[0] = (float)(A[0] / ((double)cpv * NCLS) +
                         B[0] / ((double)cnv * NCLS) +
                         C[0] / ((double)ROWS * DE));
    }
}

extern "C" void kernel_launch(void* const* d_in, const int* in_sizes, int n_in,
                              void* d_out, int out_size, void* d_ws, size_t ws_size,
                              hipStream_t stream)
{
    const float* det    = (const float*)d_in[0];
    const float* traj   = (const float*)d_in[1];
    const float* relpos = (const float*)d_in[2];
    const float* cw     = (const float*)d_in[3];
    const float* W1     = (const float*)d_in[4];
    const float* b1     = (const float*)d_in[5];
    const float* W2     = (const float*)d_in[6];
    const float* b2     = (const float*)d_in[7];
    const float* W3     = (const float*)d_in[8];
    const float* R1     = (const float*)d_in[9];
    const float* rb1    = (const float*)d_in[10];
    const float* R2     = (const float*)d_in[11];
    const float* temp   = (const float*)d_in[12];
    const int*   labels = (const int*)d_in[13];
    const int*   sids   = (const int*)d_in[14];
    const int*   oids   = (const int*)d_in[15];
    float* out = (float*)d_out;

    // ---- Workspace carve (all 256B-aligned) -------------------------------
    char* ws = (char*)d_ws;
    size_t off = 0;
    auto carve = [&](size_t bytes) -> char* {
        char* p = ws + off;
        off = (off + bytes + 255) & ~(size_t)255;
        return p;
    };
    float4* partials = (float4*)carve((size_t)ROWS * 16);               // 577KB
    short*  det_bf   = (short*)carve((size_t)BSZ * NDET * DF * 2);      // 3.1MB
    short*  W1t      = (short*)carve((size_t)2048 * 2048 * 2);          // 8.4MB [n<1024: top, else bot][k]
    short*  W2t      = (short*)carve((size_t)DH * DH * 2);              // 2.1MB
    short*  W3t      = (short*)carve((size_t)DE * DH * 2);              // 1.0MB
    short*  R2t      = (short*)carve((size_t)DE * 256 * 2);             // 0.26MB
    float*  UV       = (float*)carve((size_t)BSZ * NDET * 2048 * 4);    // 6.3MB
    size_t fixed_off = off;

    // Adaptive chunking: regions R1r (h1 bf16 / so_proj fp32) and R2r
    // (h2 bf16 / re_un fp32) are rows*2048B each; R3 (rh bf16) rows*512B.
    int b_ch = 1;
    for (int cand : {16, 8, 4, 2, 1}) {
        size_t rows  = (size_t)cand * PAIRS;
        size_t bytes = fixed_off + rows * 2048 + 256 + rows * 2048 + 256 + rows * 512 + 256;
        if (bytes <= ws_size) { b_ch = cand; break; }
    }
    const int chunk_rows = b_ch * PAIRS;
    const int n_chunks = BSZ / b_ch;
    char* reg1 = carve((size_t)chunk_rows * 2048);
    char* reg2 = carve((size_t)chunk_rows * 2048);
    short* rh  = (short*)carve((size_t)chunk_rows * 512);

    short* h1      = (short*)reg1;
    short* h2      = (short*)reg2;
    float* so_proj = (float*)reg1;    // overwrites h1 (dead after h2 GEMM)
    float* re_un   = (float*)reg2;    // overwrites h2 (dead after so_proj GEMM)

    // ---- Weight prep (once per launch, ~12MB of traffic) ------------------
    convert_bf16_kernel<<<(BSZ * NDET * DF / 4 + 255) / 256, 256, 0, stream>>>(
        det, det_bf, BSZ * NDET * DF / 4);
    transpose_bf16_kernel<<<dim3(DH / 32, DF / 32), 256, 0, stream>>>(W1, W1t, DF, DH);
    transpose_bf16_kernel<<<dim3(DH / 32, DF / 32), 256, 0, stream>>>(
        W1 + (size_t)DF * DH, W1t + (size_t)DH * DF, DF, DH);
    transpose_bf16_kernel<<<dim3(DH / 32, DH / 32), 256, 0, stream>>>(W2, W2t, DH, DH);
    transpose_bf16_kernel<<<dim3(DE / 32, DH / 32), 256, 0, stream>>>(W3, W3t, DH, DE);
    transpose_bf16_kernel<<<dim3(DE / 32, 256 / 32), 256, 0, stream>>>(R2, R2t, 256, DE);

    // UV = det_bf @ [W1_top | W1_bot]   (768 x 2048 x 2048)
    mfma_gemm<false, false, false><<<dim3(2048 / 128, (BSZ * NDET) / 128), 256, 0, stream>>>(
        det_bf, W1t, nullptr, UV, BSZ * NDET, 2048, DF);

    const int mg = (chunk_rows + 127) / 128;

    for (int c = 0; c < n_chunks; ++c) {
        int b0 = c * b_ch;
        int r0 = b0 * PAIRS;

        pairs_kernel<<<chunk_rows, 256, 0, stream>>>(UV, b1, sids, oids, h1, b0);

        // h2 = bf16(relu(h1 @ W2 + b2))          (rows x 1024 x 1024)
        mfma_gemm<true, true, true><<<dim3(DH / 128, mg), 256, 0, stream>>>(
            h1, W2t, b2, h2, chunk_rows, DH, DH);

        // so_proj = h2 @ W3                      (rows x 1024 -> 512, fp32)
        mfma_gemm<false, false, false><<<dim3(DE / 128, mg), 256, 0, stream>>>(
            h2, W3t, nullptr, so_proj, chunk_rows, DE, DH);

        rh_kernel<<<chunk_rows, 256, 0, stream>>>(relpos, R1, rb1, rh, r0);

        // re_un = rh @ R2                        (rows x 256 -> 512, fp32)
        mfma_gemm<false, false, false><<<dim3(DE / 128, mg), 256, 0, stream>>>(
            rh, R2t, nullptr, re_un, chunk_rows, DE, 256);

        loss_kernel<<<chunk_rows, 128, 0, stream>>>(
            so_proj, re_un, traj, cw, labels, temp, sids, oids, partials, b0);
    }

    reduce_kernel<<<1, 256, 0, stream>>>(partials, out);
}

// Round 4
// 564.611 us; speedup vs baseline: 8.8543x; 2.2767x over previous
//
#include <hip/hip_runtime.h>
#include <math.h>

// Problem constants
constexpr int BSZ   = 16;
constexpr int NDET  = 48;
constexpr int PAIRS = NDET * (NDET - 1);      // 2256
constexpr int ROWS  = BSZ * PAIRS;            // 36096
constexpr int DF    = 2048;
constexpr int DH    = 1024;
constexpr int DE    = 512;
constexpr int EHALF = 256;
constexpr int NCLS  = 92;
constexpr int NPAD  = 128;                    // logits N padded for GEMM
constexpr int LABW  = 1 + 92 + 40;            // 133

typedef __attribute__((ext_vector_type(8))) short bf16x8;   // 8 bf16 in 4 VGPRs
typedef __attribute__((ext_vector_type(4))) float f32x4;

__device__ __forceinline__ short f2bf(float f) {
    union { float f; unsigned u; } a; a.f = f;
    unsigned r = a.u + 0x7fffu + ((a.u >> 16) & 1u);   // RNE
    return (short)(r >> 16);
}

// ---------------------------------------------------------------------------
// fp32 -> bf16 elementwise (float4 -> short4). n4 = elems/4.
// ---------------------------------------------------------------------------
__global__ __launch_bounds__(256) void convert_bf16_kernel(
    const float* __restrict__ src, short* __restrict__ dst, int n4)
{
    int i = blockIdx.x * 256 + threadIdx.x;
    if (i >= n4) return;
    float4 v = ((const float4*)src)[i];
    short4 o;
    o.x = f2bf(v.x); o.y = f2bf(v.y); o.z = f2bf(v.z); o.w = f2bf(v.w);
    ((short4*)dst)[i] = o;
}

// cw [92][512] fp32 -> cwt [128][512] bf16 (rows 92..127 zero).
__global__ __launch_bounds__(256) void cwt_kernel(
    const float* __restrict__ cw, short* __restrict__ cwt)
{
    int i = blockIdx.x * 256 + threadIdx.x;   // over 128*512
    int n = i >> 9;
    cwt[i] = (n < NCLS) ? f2bf(cw[i]) : (short)0;
}

// ---------------------------------------------------------------------------
// Transpose + convert: src fp32 [K][N] -> dst bf16 [N][K]. K,N multiples of 32.
// ---------------------------------------------------------------------------
__global__ __launch_bounds__(256) void transpose_bf16_kernel(
    const float* __restrict__ src, short* __restrict__ dst, int K, int N)
{
    __shared__ float tile[32][33];
    int n0 = blockIdx.x * 32, k0 = blockIdx.y * 32;
    int tx = threadIdx.x & 31, ty = threadIdx.x >> 5;   // 32 x 8
#pragma unroll
    for (int i = ty; i < 32; i += 8)
        tile[i][tx] = src[(size_t)(k0 + i) * N + n0 + tx];
    __syncthreads();
#pragma unroll
    for (int i = ty; i < 32; i += 8)
        dst[(size_t)(n0 + i) * K + k0 + tx] = f2bf(tile[tx][i]);
}

// ---------------------------------------------------------------------------
// MFMA bf16 GEMM (m97 structure): C[M,N] = act(A[M,K] @ B[K,N] (+bias)).
// A bf16 [M,K]; Bt bf16 [N,K]. N%128==0, K%32==0; M arbitrary (clamped
// staging + guarded store). 128x128 tile, BK=32, 256 threads = 4 waves.
// ---------------------------------------------------------------------------
__device__ __forceinline__ void load16_lds(const void* g, void* l) {
    __builtin_amdgcn_global_load_lds(
        (const __attribute__((address_space(1))) unsigned int*)g,
        (__attribute__((address_space(3))) unsigned int*)l, 16, 0, 0);
}

template <bool BIAS, bool RELU, bool OUTBF16>
__global__ __launch_bounds__(256) void mfma_gemm(
    const short* __restrict__ A, const short* __restrict__ Bt,
    const float* __restrict__ bias, void* __restrict__ C,
    int M, int N, int K)
{
    __shared__ short As[128 * 32];
    __shared__ short Bs[128 * 32];

    const int tid  = threadIdx.x;
    const int wave = tid >> 6;
    const int lane = tid & 63;
    const int m0 = blockIdx.y * 128;
    const int n0 = blockIdx.x * 128;
    const int wm = (wave & 1) * 64;
    const int wn = (wave >> 1) * 64;

    f32x4 acc[4][4] = {};

    const int q  = lane >> 4;     // quad 0..3
    const int lm = lane & 15;

    for (int k0 = 0; k0 < K; k0 += 32) {
#pragma unroll
        for (int it = 0; it < 2; ++it) {
            int c   = it * 256 + tid;
            int row = c >> 2;
            int kk  = (c & 3) * 8;
            int ldsc = (it * 256 + wave * 64) * 8;  // wave-uniform chunk base
            int gm = m0 + row; if (gm >= M) gm = M - 1;
            load16_lds(A + (size_t)gm * K + k0 + kk, (short*)As + ldsc);
            int gn = n0 + row;                       // N%128==0: no tail
            load16_lds(Bt + (size_t)gn * K + k0 + kk, (short*)Bs + ldsc);
        }
        __syncthreads();

        bf16x8 af[4], bfr[4];
#pragma unroll
        for (int t = 0; t < 4; ++t) {
            af[t]  = *(const bf16x8*)(As + (wm + t * 16 + lm) * 32 + q * 8);
            bfr[t] = *(const bf16x8*)(Bs + (wn + t * 16 + lm) * 32 + q * 8);
        }
#pragma unroll
        for (int tm = 0; tm < 4; ++tm)
#pragma unroll
            for (int tn = 0; tn < 4; ++tn)
                acc[tm][tn] = __builtin_amdgcn_mfma_f32_16x16x32_bf16(
                    af[tm], bfr[tn], acc[tm][tn], 0, 0, 0);
        __syncthreads();
    }

    // C/D layout col=lane&15, row=(lane>>4)*4+reg (m89-verified)
#pragma unroll
    for (int tm = 0; tm < 4; ++tm) {
#pragma unroll
        for (int tn = 0; tn < 4; ++tn) {
            int col = n0 + wn + tn * 16 + lm;
#pragma unroll
            for (int r = 0; r < 4; ++r) {
                int row = m0 + wm + tm * 16 + q * 4 + r;
                if (row < M) {
                    float v = acc[tm][tn][r];
                    if (BIAS) v += bias[col];
                    if (RELU) v = fmaxf(v, 0.0f);
                    if (OUTBF16) ((short*)C)[(size_t)row * N + col] = f2bf(v);
                    else         ((float*)C)[(size_t)row * N + col] = v;
                }
            }
        }
    }
}

// ---------------------------------------------------------------------------
// h1[r,:] = bf16(relu(UV[b*48+s, 0:1024] + UV[b*48+o, 1024:2048] + b1))
// ---------------------------------------------------------------------------
__global__ __launch_bounds__(256) void pairs_kernel(
    const float* __restrict__ UV, const float* __restrict__ b1,
    const int* __restrict__ sids, const int* __restrict__ oids,
    short* __restrict__ h1, int b0)
{
    int r = blockIdx.x;
    int b = b0 + r / PAIRS;
    int p = r % PAIRS;
    const float4* u  = (const float4*)(UV + (size_t)(b * NDET + sids[p]) * 2048);
    const float4* v  = (const float4*)(UV + (size_t)(b * NDET + oids[p]) * 2048 + 1024);
    const float4* bb = (const float4*)b1;
    int j = threadIdx.x;
    float4 x = u[j], y = v[j], z = bb[j];
    short4 h;
    h.x = f2bf(fmaxf(x.x + y.x + z.x, 0.0f));
    h.y = f2bf(fmaxf(x.y + y.y + z.y, 0.0f));
    h.z = f2bf(fmaxf(x.z + y.z + z.z, 0.0f));
    h.w = f2bf(fmaxf(x.w + y.w + z.w, 0.0f));
    ((short4*)(h1 + (size_t)r * DH))[j] = h;
}

// ---------------------------------------------------------------------------
// rh[r,j] = bf16(relu(sum_k rp[r,k]*R1[k,j] + rb1[j]))  (K=12, one block/row)
// ---------------------------------------------------------------------------
__global__ __launch_bounds__(256) void rh_kernel(
    const float* __restrict__ rp, const float* __restrict__ R1,
    const float* __restrict__ rb1, short* __restrict__ rh, int r0)
{
    int r = blockIdx.x;
    int j = threadIdx.x;
    const float* row = rp + (size_t)(r0 + r) * 12;
    float acc = rb1[j];
#pragma unroll
    for (int k = 0; k < 12; ++k) acc = fmaf(row[k], R1[k * 256 + j], acc);
    rh[(size_t)r * 256 + j] = f2bf(fmaxf(acc, 0.0f));
}

// ---------------------------------------------------------------------------
// row_prep: one wave per row, butterfly reductions, no __syncthreads.
// comb_bf[r,:] = bf16( normalize(normalize(sp)+normalize(ru)) / temp )
// dist_arr[rg] = sum |concat(traj_s,traj_o) - sp|
// ---------------------------------------------------------------------------
__global__ __launch_bounds__(256) void row_prep_kernel(
    const float* __restrict__ so_proj, const float* __restrict__ re_un,
    const float* __restrict__ traj, const float* __restrict__ temperature,
    const int* __restrict__ sids, const int* __restrict__ oids,
    short* __restrict__ comb_bf, float* __restrict__ dist_arr, int b0)
{
    int wave = threadIdx.x >> 6, lane = threadIdx.x & 63;
    int r = blockIdx.x * 4 + wave;       // local row (chunk_rows % 4 == 0)
    int rg = b0 * PAIRS + r;
    int b = b0 + r / PAIRS;
    int p = r % PAIRS;

    const float4* sp4 = (const float4*)(so_proj + (size_t)r * DE);
    const float4* ru4 = (const float4*)(re_un   + (size_t)r * DE);
    float4 s0 = sp4[lane * 2], s1 = sp4[lane * 2 + 1];
    float4 u0 = ru4[lane * 2], u1 = ru4[lane * 2 + 1];

    // concat(traj_s, traj_o) elements [lane*8, lane*8+8)
    const float* tsrc = (lane < 32)
        ? (traj + (size_t)(b * NDET + sids[p]) * EHALF + lane * 8)
        : (traj + (size_t)(b * NDET + oids[p]) * EHALF + (lane - 32) * 8);
    float4 t0 = ((const float4*)tsrc)[0], t1 = ((const float4*)tsrc)[1];

    float ss = s0.x*s0.x + s0.y*s0.y + s0.z*s0.z + s0.w*s0.w
             + s1.x*s1.x + s1.y*s1.y + s1.z*s1.z + s1.w*s1.w;
    float sr = u0.x*u0.x + u0.y*u0.y + u0.z*u0.z + u0.w*u0.w
             + u1.x*u1.x + u1.y*u1.y + u1.z*u1.z + u1.w*u1.w;
    float sd = fabsf(t0.x - s0.x) + fabsf(t0.y - s0.y) + fabsf(t0.z - s0.z) + fabsf(t0.w - s0.w)
             + fabsf(t1.x - s1.x) + fabsf(t1.y - s1.y) + fabsf(t1.z - s1.z) + fabsf(t1.w - s1.w);

#pragma unroll
    for (int m = 1; m < 64; m <<= 1) {
        ss += __shfl_xor(ss, m);
        sr += __shfl_xor(sr, m);
        sd += __shfl_xor(sd, m);
    }
    float inv_s = 1.0f / fmaxf(sqrtf(ss), 1e-12f);
    float inv_r = 1.0f / fmaxf(sqrtf(sr), 1e-12f);

    float4 c0, c1;
    c0.x = s0.x * inv_s + u0.x * inv_r;  c0.y = s0.y * inv_s + u0.y * inv_r;
    c0.z = s0.z * inv_s + u0.z * inv_r;  c0.w = s0.w * inv_s + u0.w * inv_r;
    c1.x = s1.x * inv_s + u1.x * inv_r;  c1.y = s1.y * inv_s + u1.y * inv_r;
    c1.z = s1.z * inv_s + u1.z * inv_r;  c1.w = s1.w * inv_s + u1.w * inv_r;

    float sc = c0.x*c0.x + c0.y*c0.y + c0.z*c0.z + c0.w*c0.w
             + c1.x*c1.x + c1.y*c1.y + c1.z*c1.z + c1.w*c1.w;
#pragma unroll
    for (int m = 1; m < 64; m <<= 1) sc += __shfl_xor(sc, m);

    float scale = (1.0f / fmaxf(sqrtf(sc), 1e-12f)) / temperature[0];

    short4 o0, o1;
    o0.x = f2bf(c0.x * scale); o0.y = f2bf(c0.y * scale);
    o0.z = f2bf(c0.z * scale); o0.w = f2bf(c0.w * scale);
    o1.x = f2bf(c1.x * scale); o1.y = f2bf(c1.y * scale);
    o1.z = f2bf(c1.z * scale); o1.w = f2bf(c1.w * scale);
    short4* out = (short4*)(comb_bf + (size_t)r * DE + lane * 8);
    out[0] = o0; out[1] = o1;

    if (lane == 0) dist_arr[rg] = sd;
}

// ---------------------------------------------------------------------------
// focal: one wave per row over 92 logits (coalesced). Writes float4 partial
// (pos_masked, neg_masked, 0, flags).
// ---------------------------------------------------------------------------
__global__ __launch_bounds__(256) void focal_kernel(
    const float* __restrict__ logits, const int* __restrict__ labels,
    float4* __restrict__ pn, int b0)
{
    int wave = threadIdx.x >> 6, lane = threadIdx.x & 63;
    int r = blockIdx.x * 4 + wave;
    int rg = b0 * PAIRS + r;
    const float* lrow = logits + (size_t)r * NPAD;
    size_t labbase = (size_t)rg * LABW;

    float flp = 0.0f, fln = 0.0f, fm = 0.0f;
    for (int c = lane; c < NCLS; c += 64) {
        float l = lrow[c];
        int t = labels[labbase + 1 + c];
        if (t > 0) fm = 1.0f;
        float tf = (float)t;
        float pr = 1.0f / (1.0f + expf(-l));
        float lg = log1pf(expf(-fabsf(l)));
        float ce = fmaxf(l, 0.0f) - l * tf + lg;
        float pt = pr * tf + (1.0f - pr) * (1.0f - tf);
        float om = 1.0f - pt;
        float at = 0.25f * tf + 0.75f * (1.0f - tf);
        flp += at * ce * om * om;
        float ce0 = fmaxf(l, 0.0f) + lg;
        fln += 0.75f * ce0 * pr * pr;
    }
#pragma unroll
    for (int m = 1; m < 64; m <<= 1) {
        flp += __shfl_xor(flp, m);
        fln += __shfl_xor(fln, m);
        fm  += __shfl_xor(fm, m);
    }
    if (lane == 0) {
        int posf = (fm > 0.5f) ? 1 : 0;
        int negf = (labels[labbase] > 0) ? 1 : 0;
        pn[rg] = make_float4(posf ? flp : 0.0f, negf ? fln : 0.0f, 0.0f,
                             (float)(posf + 2 * negf));
    }
}

// ---------------------------------------------------------------------------
// Final reduce: one block over ROWS partials.
// ---------------------------------------------------------------------------
__global__ __launch_bounds__(256) void reduce_kernel(
    const float4* __restrict__ pn, const float* __restrict__ dist_arr,
    float* __restrict__ out)
{
    int tid = threadIdx.x;
    double sp = 0.0, sn = 0.0, sd = 0.0;
    int cp = 0, cn = 0;
    for (int i = tid; i < ROWS; i += 256) {
        float4 v = pn[i];
        sp += (double)v.x; sn += (double)v.y; sd += (double)dist_arr[i];
        int f = (int)v.w;
        cp += f & 1; cn += (f >> 1) & 1;
    }
    __shared__ double A[256], B[256], C[256];
    __shared__ int I[256], J[256];
    A[tid] = sp; B[tid] = sn; C[tid] = sd; I[tid] = cp; J[tid] = cn;
    __syncthreads();
    for (int st = 128; st > 0; st >>= 1) {
        if (tid < st) { A[tid] += A[tid + st]; B[tid] += B[tid + st]; C[tid] += C[tid + st];
                        I[tid] += I[tid + st]; J[tid] += J[tid + st]; }
        __syncthreads();
    }
    if (tid == 0) {
        int cpv = I[0] < 1 ? 1 : I[0];
        int cnv = J[0] < 1 ? 1 : J[0];
        out[0] = (float)(A[0] / ((double)cpv * NCLS) +
                         B[0] / ((double)cnv * NCLS) +
                         C[0] / ((double)ROWS * DE));
    }
}

extern "C" void kernel_launch(void* const* d_in, const int* in_sizes, int n_in,
                              void* d_out, int out_size, void* d_ws, size_t ws_size,
                              hipStream_t stream)
{
    const float* det    = (const float*)d_in[0];
    const float* traj   = (const float*)d_in[1];
    const float* relpos = (const float*)d_in[2];
    const float* cw     = (const float*)d_in[3];
    const float* W1     = (const float*)d_in[4];
    const float* b1     = (const float*)d_in[5];
    const float* W2     = (const float*)d_in[6];
    const float* b2     = (const float*)d_in[7];
    const float* W3     = (const float*)d_in[8];
    const float* R1     = (const float*)d_in[9];
    const float* rb1    = (const float*)d_in[10];
    const float* R2     = (const float*)d_in[11];
    const float* temp   = (const float*)d_in[12];
    const int*   labels = (const int*)d_in[13];
    const int*   sids   = (const int*)d_in[14];
    const int*   oids   = (const int*)d_in[15];
    float* out = (float*)d_out;

    // ---- Workspace carve --------------------------------------------------
    char* ws = (char*)d_ws;
    size_t off = 0;
    auto carve = [&](size_t bytes) -> char* {
        char* p = ws + off;
        off = (off + bytes + 255) & ~(size_t)255;
        return p;
    };
    float4* pn       = (float4*)carve((size_t)ROWS * 16);               // 577KB
    float*  dist_arr = (float*)carve((size_t)ROWS * 4);                 // 144KB
    short*  det_bf   = (short*)carve((size_t)BSZ * NDET * DF * 2);      // 3.1MB
    short*  W1t      = (short*)carve((size_t)2048 * 2048 * 2);          // 8.4MB
    short*  W2t      = (short*)carve((size_t)DH * DH * 2);              // 2.1MB
    short*  W3t      = (short*)carve((size_t)DE * DH * 2);              // 1.0MB
    short*  R2t      = (short*)carve((size_t)DE * 256 * 2);             // 0.26MB
    short*  cwt      = (short*)carve((size_t)NPAD * DE * 2);            // 131KB
    float*  UV       = (float*)carve((size_t)BSZ * NDET * 2048 * 4);    // 6.3MB
    size_t fixed_off = off;

    // Per-chunk regions (rows = b_ch*PAIRS):
    //   reg1: h1 bf16 [rows,1024] -> so_proj fp32 [rows,512]   (rows*2048B)
    //   reg2: h2 bf16 [rows,1024] -> re_un  fp32 [rows,512]    (rows*2048B)
    //   reg3: rh bf16 [rows,256]  -> logits fp32 [rows,128]    (rows*512B)
    //   comb: bf16 [rows,512]                                  (rows*1024B)
    int b_ch = 1;
    for (int cand : {16, 8, 4, 2, 1}) {
        size_t rows  = (size_t)cand * PAIRS;
        size_t bytes = fixed_off + rows * 2048 + 256 + rows * 2048 + 256
                     + rows * 512 + 256 + rows * 1024 + 256;
        if (bytes <= ws_size) { b_ch = cand; break; }
    }
    const int chunk_rows = b_ch * PAIRS;
    const int n_chunks = BSZ / b_ch;
    char* reg1 = carve((size_t)chunk_rows * 2048);
    char* reg2 = carve((size_t)chunk_rows * 2048);
    char* reg3 = carve((size_t)chunk_rows * 512);
    short* comb_bf = (short*)carve((size_t)chunk_rows * 1024);

    short* h1      = (short*)reg1;
    short* h2      = (short*)reg2;
    float* so_proj = (float*)reg1;
    float* re_un   = (float*)reg2;
    short* rh      = (short*)reg3;
    float* logits  = (float*)reg3;    // overwrites rh (dead after re_un GEMM)

    // ---- Weight prep ------------------------------------------------------
    convert_bf16_kernel<<<(BSZ * NDET * DF / 4 + 255) / 256, 256, 0, stream>>>(
        det, det_bf, BSZ * NDET * DF / 4);
    transpose_bf16_kernel<<<dim3(DH / 32, DF / 32), 256, 0, stream>>>(W1, W1t, DF, DH);
    transpose_bf16_kernel<<<dim3(DH / 32, DF / 32), 256, 0, stream>>>(
        W1 + (size_t)DF * DH, W1t + (size_t)DH * DF, DF, DH);
    transpose_bf16_kernel<<<dim3(DH / 32, DH / 32), 256, 0, stream>>>(W2, W2t, DH, DH);
    transpose_bf16_kernel<<<dim3(DE / 32, DH / 32), 256, 0, stream>>>(W3, W3t, DH, DE);
    transpose_bf16_kernel<<<dim3(DE / 32, 256 / 32), 256, 0, stream>>>(R2, R2t, 256, DE);
    cwt_kernel<<<(NPAD * DE) / 256, 256, 0, stream>>>(cw, cwt);

    // UV = det_bf @ [W1_top | W1_bot]   (768 x 2048 x 2048)
    mfma_gemm<false, false, false><<<dim3(2048 / 128, (BSZ * NDET) / 128), 256, 0, stream>>>(
        det_bf, W1t, nullptr, UV, BSZ * NDET, 2048, DF);

    const int mg = (chunk_rows + 127) / 128;   // chunk_rows % 128 == 0

    for (int c = 0; c < n_chunks; ++c) {
        int b0 = c * b_ch;
        int r0 = b0 * PAIRS;

        pairs_kernel<<<chunk_rows, 256, 0, stream>>>(UV, b1, sids, oids, h1, b0);

        // h2 = bf16(relu(h1 @ W2 + b2))          (rows x 1024 x 1024)
        mfma_gemm<true, true, true><<<dim3(DH / 128, mg), 256, 0, stream>>>(
            h1, W2t, b2, h2, chunk_rows, DH, DH);

        // so_proj = h2 @ W3                      (rows x 1024 -> 512, fp32)
        mfma_gemm<false, false, false><<<dim3(DE / 128, mg), 256, 0, stream>>>(
            h2, W3t, nullptr, so_proj, chunk_rows, DE, DH);

        rh_kernel<<<chunk_rows, 256, 0, stream>>>(relpos, R1, rb1, rh, r0);

        // re_un = rh @ R2                        (rows x 256 -> 512, fp32)
        mfma_gemm<false, false, false><<<dim3(DE / 128, mg), 256, 0, stream>>>(
            rh, R2t, nullptr, re_un, chunk_rows, DE, 256);

        // comb_bf = bf16(combined/temp), dist partials
        row_prep_kernel<<<chunk_rows / 4, 256, 0, stream>>>(
            so_proj, re_un, traj, temp, sids, oids, comb_bf, dist_arr, b0);

        // logits = comb_bf @ cw^T                (rows x 512 -> 128, fp32)
        mfma_gemm<false, false, false><<<dim3(1, mg), 256, 0, stream>>>(
            comb_bf, cwt, nullptr, logits, chunk_rows, NPAD, DE);

        focal_kernel<<<chunk_rows / 4, 256, 0, stream>>>(logits, labels, pn, b0);
    }

    reduce_kernel<<<1, 256, 0, stream>>>(pn, dist_arr, out);
}

// Round 5
// 521.765 us; speedup vs baseline: 9.5814x; 1.0821x over previous
//
#include <hip/hip_runtime.h>
#include <math.h>

// Problem constants
constexpr int BSZ   = 16;
constexpr int NDET  = 48;
constexpr int PAIRS = NDET * (NDET - 1);      // 2256
constexpr int ROWS  = BSZ * PAIRS;            // 36096
constexpr int DF    = 2048;
constexpr int DH    = 1024;
constexpr int DE    = 512;
constexpr int EHALF = 256;
constexpr int NCLS  = 92;
constexpr int NPAD  = 128;                    // logits N padded for GEMM
constexpr int LABW  = 1 + 92 + 40;            // 133

typedef __attribute__((ext_vector_type(8))) short bf16x8;   // 8 bf16 in 4 VGPRs
typedef __attribute__((ext_vector_type(4))) float f32x4;

__device__ __forceinline__ short f2bf(float f) {
    union { float f; unsigned u; } a; a.f = f;
    unsigned r = a.u + 0x7fffu + ((a.u >> 16) & 1u);   // RNE
    return (short)(r >> 16);
}
__device__ __forceinline__ float bf2f(short h) {
    union { unsigned u; float f; } x;
    x.u = ((unsigned)(unsigned short)h) << 16;
    return x.f;
}

// ---------------------------------------------------------------------------
// Fused elementwise prep: det fp32->bf16 (393216 short4) then cwt build
// (92x512 fp32 -> 128x512 bf16, zero-padded rows).
// ---------------------------------------------------------------------------
constexpr int N4DET = BSZ * NDET * DF / 4;    // 393216
constexpr int N4CWT = NPAD * DE / 4;          // 16384
__global__ __launch_bounds__(256) void convert_all_kernel(
    const float* __restrict__ det, short* __restrict__ det_bf,
    const float* __restrict__ cw, short* __restrict__ cwt)
{
    int i = blockIdx.x * 256 + threadIdx.x;
    if (i < N4DET) {
        float4 v = ((const float4*)det)[i];
        short4 o;
        o.x = f2bf(v.x); o.y = f2bf(v.y); o.z = f2bf(v.z); o.w = f2bf(v.w);
        ((short4*)det_bf)[i] = o;
    } else if (i < N4DET + N4CWT) {
        int k = i - N4DET;
        int n = (k * 4) >> 9;                 // cwt row
        short4 o = {0, 0, 0, 0};
        if (n < NCLS) {
            float4 v = ((const float4*)cw)[k];
            o.x = f2bf(v.x); o.y = f2bf(v.y); o.z = f2bf(v.z); o.w = f2bf(v.w);
        }
        ((short4*)cwt)[k] = o;
    }
}

// ---------------------------------------------------------------------------
// Multi-job transpose+convert: src fp32 [K][N] -> dst bf16 [N][K] (dst row
// stride = K of that job). 5 jobs in one launch (W1 top/bot, W2, W3, R2).
// ---------------------------------------------------------------------------
struct TransJobs {
    const float* src[5];
    short*       dst[5];
    int K[5], N[5];
    int cum[6];          // cumulative 32x32 tile counts
};
__global__ __launch_bounds__(256) void transpose_multi_kernel(TransJobs jobs) {
    __shared__ float tile[32][33];
    int t = blockIdx.x;
    int j = 0;
    while (t >= jobs.cum[j + 1]) ++j;         // block-uniform, <=5 iters
    int lt = t - jobs.cum[j];
    int K = jobs.K[j], N = jobs.N[j];
    int nx = N >> 5;
    int ky = lt / nx, nxi = lt - ky * nx;
    int n0 = nxi * 32, k0 = ky * 32;
    const float* src = jobs.src[j];
    short* dst = jobs.dst[j];
    int tx = threadIdx.x & 31, ty = threadIdx.x >> 5;
#pragma unroll
    for (int i = ty; i < 32; i += 8)
        tile[i][tx] = src[(size_t)(k0 + i) * N + n0 + tx];
    __syncthreads();
#pragma unroll
    for (int i = ty; i < 32; i += 8)
        dst[(size_t)(n0 + i) * K + k0 + tx] = f2bf(tile[tx][i]);
}

// ---------------------------------------------------------------------------
// MFMA bf16 GEMM: C[M,N] = act(A[M,K] @ B[K,N] (+bias)). A bf16 [M,lda],
// Bt bf16 [N,ldb]. N%128==0, K%32==0; M arbitrary. 128x128 tile, BK=32,
// 256 threads = 4 waves. SWIZZLE: XCD-aware remap — each virtual XCD
// (gid%8) owns a contiguous M-slice and iterates N-columns innermost, so an
// A-tile's 8 consumers are temporally adjacent on one XCD's L2 (fixes the
// 3.9x A over-fetch measured in R4: FETCH 292MB vs 76MB ideal).
// Requires gridDim.y % 8 == 0 when SWIZZLE (pad + early-exit).
// ---------------------------------------------------------------------------
__device__ __forceinline__ void load16_lds(const void* g, void* l) {
    __builtin_amdgcn_global_load_lds(
        (const __attribute__((address_space(1))) unsigned int*)g,
        (__attribute__((address_space(3))) unsigned int*)l, 16, 0, 0);
}

template <bool BIAS, bool RELU, bool OUTBF16, bool SWIZZLE>
__global__ __launch_bounds__(256) void mfma_gemm(
    const short* __restrict__ A, const short* __restrict__ Bt,
    const float* __restrict__ bias, void* __restrict__ C,
    int M, int N, int K, int lda, int ldb)
{
    __shared__ short As[128 * 32];
    __shared__ short Bs[128 * 32];

    int bx, by;
    if (SWIZZLE) {
        int nb  = gridDim.x;
        int gid = blockIdx.y * nb + blockIdx.x;     // == HW dispatch order
        int xcd = gid & 7;
        int j   = gid >> 3;
        int rows_per = gridDim.y >> 3;
        int lr  = j / nb;
        bx = j - lr * nb;
        by = xcd * rows_per + lr;
        if (by * 128 >= M) return;                  // padded tail
    } else {
        bx = blockIdx.x; by = blockIdx.y;
    }

    const int tid  = threadIdx.x;
    const int wave = tid >> 6;
    const int lane = tid & 63;
    const int m0 = by * 128;
    const int n0 = bx * 128;
    const int wm = (wave & 1) * 64;
    const int wn = (wave >> 1) * 64;

    f32x4 acc[4][4] = {};

    const int q  = lane >> 4;     // quad 0..3
    const int lm = lane & 15;

    for (int k0 = 0; k0 < K; k0 += 32) {
#pragma unroll
        for (int it = 0; it < 2; ++it) {
            int c   = it * 256 + tid;
            int row = c >> 2;
            int kk  = (c & 3) * 8;
            int ldsc = (it * 256 + wave * 64) * 8;  // wave-uniform chunk base
            int gm = m0 + row; if (gm >= M) gm = M - 1;
            load16_lds(A + (size_t)gm * lda + k0 + kk, (short*)As + ldsc);
            int gn = n0 + row;                       // N%128==0: no tail
            load16_lds(Bt + (size_t)gn * ldb + k0 + kk, (short*)Bs + ldsc);
        }
        __syncthreads();

        bf16x8 af[4], bfr[4];
#pragma unroll
        for (int t = 0; t < 4; ++t) {
            af[t]  = *(const bf16x8*)(As + (wm + t * 16 + lm) * 32 + q * 8);
            bfr[t] = *(const bf16x8*)(Bs + (wn + t * 16 + lm) * 32 + q * 8);
        }
#pragma unroll
        for (int tm = 0; tm < 4; ++tm)
#pragma unroll
            for (int tn = 0; tn < 4; ++tn)
                acc[tm][tn] = __builtin_amdgcn_mfma_f32_16x16x32_bf16(
                    af[tm], bfr[tn], acc[tm][tn], 0, 0, 0);
        __syncthreads();
    }

    // C/D layout col=lane&15, row=(lane>>4)*4+reg (m89-verified)
#pragma unroll
    for (int tm = 0; tm < 4; ++tm) {
#pragma unroll
        for (int tn = 0; tn < 4; ++tn) {
            int col = n0 + wn + tn * 16 + lm;
#pragma unroll
            for (int r = 0; r < 4; ++r) {
                int row = m0 + wm + tm * 16 + q * 4 + r;
                if (row < M) {
                    float v = acc[tm][tn][r];
                    if (BIAS) v += bias[col];
                    if (RELU) v = fmaxf(v, 0.0f);
                    if (OUTBF16) ((short*)C)[(size_t)row * N + col] = f2bf(v);
                    else         ((float*)C)[(size_t)row * N + col] = v;
                }
            }
        }
    }
}

// ---------------------------------------------------------------------------
// h1[r,:] = bf16(relu(UVa[s',j]+UVb[s',j] + UVa[o',1024+j]+UVb[o',1024+j]
//                     + b1[j]))   — UVa/UVb are split-K bf16 partials.
// ---------------------------------------------------------------------------
__global__ __launch_bounds__(256) void pairs_kernel(
    const short* __restrict__ UVa, const short* __restrict__ UVb,
    const float* __restrict__ b1,
    const int* __restrict__ sids, const int* __restrict__ oids,
    short* __restrict__ h1, int b0)
{
    int r = blockIdx.x;
    int b = b0 + r / PAIRS;
    int p = r % PAIRS;
    size_t soff = (size_t)(b * NDET + sids[p]) * 2048;
    size_t ooff = (size_t)(b * NDET + oids[p]) * 2048 + 1024;
    int j = threadIdx.x;                      // 256 threads x 4 elems = 1024
    short4 a1 = ((const short4*)(UVa + soff))[j];
    short4 a2 = ((const short4*)(UVb + soff))[j];
    short4 a3 = ((const short4*)(UVa + ooff))[j];
    short4 a4 = ((const short4*)(UVb + ooff))[j];
    float4 bb = ((const float4*)b1)[j];
    short4 h;
    h.x = f2bf(fmaxf(bf2f(a1.x) + bf2f(a2.x) + bf2f(a3.x) + bf2f(a4.x) + bb.x, 0.0f));
    h.y = f2bf(fmaxf(bf2f(a1.y) + bf2f(a2.y) + bf2f(a3.y) + bf2f(a4.y) + bb.y, 0.0f));
    h.z = f2bf(fmaxf(bf2f(a1.z) + bf2f(a2.z) + bf2f(a3.z) + bf2f(a4.z) + bb.z, 0.0f));
    h.w = f2bf(fmaxf(bf2f(a1.w) + bf2f(a2.w) + bf2f(a3.w) + bf2f(a4.w) + bb.w, 0.0f));
    ((short4*)(h1 + (size_t)r * DH))[j] = h;
}

// ---------------------------------------------------------------------------
// rh[r,j] = bf16(relu(sum_k rp[r,k]*R1[k,j] + rb1[j]))  (K=12, one block/row)
// ---------------------------------------------------------------------------
__global__ __launch_bounds__(256) void rh_kernel(
    const float* __restrict__ rp, const float* __restrict__ R1,
    const float* __restrict__ rb1, short* __restrict__ rh, int r0)
{
    int r = blockIdx.x;
    int j = threadIdx.x;
    const float* row = rp + (size_t)(r0 + r) * 12;
    float acc = rb1[j];
#pragma unroll
    for (int k = 0; k < 12; ++k) acc = fmaf(row[k], R1[k * 256 + j], acc);
    rh[(size_t)r * 256 + j] = f2bf(fmaxf(acc, 0.0f));
}

// ---------------------------------------------------------------------------
// row_prep: one wave per row, butterfly reductions, bf16 inputs.
// comb_bf[r,:] = bf16( normalize(normalize(sp)+normalize(ru)) / temp )
// dist_arr[rg] = sum |concat(traj_s,traj_o) - sp|
// ---------------------------------------------------------------------------
__global__ __launch_bounds__(256) void row_prep_kernel(
    const short* __restrict__ sp_bf, const short* __restrict__ ru_bf,
    const float* __restrict__ traj, const float* __restrict__ temperature,
    const int* __restrict__ sids, const int* __restrict__ oids,
    short* __restrict__ comb_bf, float* __restrict__ dist_arr, int b0)
{
    int wave = threadIdx.x >> 6, lane = threadIdx.x & 63;
    int r = blockIdx.x * 4 + wave;       // chunk_rows % 4 == 0
    int rg = b0 * PAIRS + r;
    int b = b0 + r / PAIRS;
    int p = r % PAIRS;

    bf16x8 sv = ((const bf16x8*)(sp_bf + (size_t)r * DE))[lane];  // elems [lane*8..+8)
    bf16x8 uv = ((const bf16x8*)(ru_bf + (size_t)r * DE))[lane];
    float s[8], u[8];
#pragma unroll
    for (int i = 0; i < 8; ++i) { s[i] = bf2f(sv[i]); u[i] = bf2f(uv[i]); }

    // concat(traj_s, traj_o) elements [lane*8, lane*8+8)
    const float* tsrc = (lane < 32)
        ? (traj + (size_t)(b * NDET + sids[p]) * EHALF + lane * 8)
        : (traj + (size_t)(b * NDET + oids[p]) * EHALF + (lane - 32) * 8);
    float4 t0 = ((const float4*)tsrc)[0], t1 = ((const float4*)tsrc)[1];
    float t[8] = {t0.x, t0.y, t0.z, t0.w, t1.x, t1.y, t1.z, t1.w};

    float ss = 0.0f, sr = 0.0f, sd = 0.0f;
#pragma unroll
    for (int i = 0; i < 8; ++i) {
        ss += s[i] * s[i];
        sr += u[i] * u[i];
        sd += fabsf(t[i] - s[i]);
    }
#pragma unroll
    for (int m = 1; m < 64; m <<= 1) {
        ss += __shfl_xor(ss, m);
        sr += __shfl_xor(sr, m);
        sd += __shfl_xor(sd, m);
    }
    float inv_s = 1.0f / fmaxf(sqrtf(ss), 1e-12f);
    float inv_r = 1.0f / fmaxf(sqrtf(sr), 1e-12f);

    float c[8], sc = 0.0f;
#pragma unroll
    for (int i = 0; i < 8; ++i) {
        c[i] = s[i] * inv_s + u[i] * inv_r;
        sc += c[i] * c[i];
    }
#pragma unroll
    for (int m = 1; m < 64; m <<= 1) sc += __shfl_xor(sc, m);

    float scale = (1.0f / fmaxf(sqrtf(sc), 1e-12f)) / temperature[0];

    bf16x8 o;
#pragma unroll
    for (int i = 0; i < 8; ++i) o[i] = f2bf(c[i] * scale);
    ((bf16x8*)(comb_bf + (size_t)r * DE))[lane] = o;

    if (lane == 0) dist_arr[rg] = sd;
}

// ---------------------------------------------------------------------------
// focal: one wave per row over 92 logits (coalesced). Writes float4 partial
// (pos_masked, neg_masked, 0, flags).
// ---------------------------------------------------------------------------
__global__ __launch_bounds__(256) void focal_kernel(
    const float* __restrict__ logits, const int* __restrict__ labels,
    float4* __restrict__ pn, int b0)
{
    int wave = threadIdx.x >> 6, lane = threadIdx.x & 63;
    int r = blockIdx.x * 4 + wave;
    int rg = b0 * PAIRS + r;
    const float* lrow = logits + (size_t)r * NPAD;
    size_t labbase = (size_t)rg * LABW;

    float flp = 0.0f, fln = 0.0f, fm = 0.0f;
    for (int c = lane; c < NCLS; c += 64) {
        float l = lrow[c];
        int t = labels[labbase + 1 + c];
        if (t > 0) fm = 1.0f;
        float tf = (float)t;
        float pr = 1.0f / (1.0f + expf(-l));
        float lg = log1pf(expf(-fabsf(l)));
        float ce = fmaxf(l, 0.0f) - l * tf + lg;
        float pt = pr * tf + (1.0f - pr) * (1.0f - tf);
        float om = 1.0f - pt;
        float at = 0.25f * tf + 0.75f * (1.0f - tf);
        flp += at * ce * om * om;
        float ce0 = fmaxf(l, 0.0f) + lg;
        fln += 0.75f * ce0 * pr * pr;
    }
#pragma unroll
    for (int m = 1; m < 64; m <<= 1) {
        flp += __shfl_xor(flp, m);
        fln += __shfl_xor(fln, m);
        fm  += __shfl_xor(fm, m);
    }
    if (lane == 0) {
        int posf = (fm > 0.5f) ? 1 : 0;
        int negf = (labels[labbase] > 0) ? 1 : 0;
        pn[rg] = make_float4(posf ? flp : 0.0f, negf ? fln : 0.0f, 0.0f,
                             (float)(posf + 2 * negf));
    }
}

// ---------------------------------------------------------------------------
// Final reduce: one block over ROWS partials.
// ---------------------------------------------------------------------------
__global__ __launch_bounds__(256) void reduce_kernel(
    const float4* __restrict__ pn, const float* __restrict__ dist_arr,
    float* __restrict__ out)
{
    int tid = threadIdx.x;
    double sp = 0.0, sn = 0.0, sd = 0.0;
    int cp = 0, cn = 0;
    for (int i = tid; i < ROWS; i += 256) {
        float4 v = pn[i];
        sp += (double)v.x; sn += (double)v.y; sd += (double)dist_arr[i];
        int f = (int)v.w;
        cp += f & 1; cn += (f >> 1) & 1;
    }
    __shared__ double A[256], B[256], C[256];
    __shared__ int I[256], J[256];
    A[tid] = sp; B[tid] = sn; C[tid] = sd; I[tid] = cp; J[tid] = cn;
    __syncthreads();
    for (int st = 128; st > 0; st >>= 1) {
        if (tid < st) { A[tid] += A[tid + st]; B[tid] += B[tid + st]; C[tid] += C[tid + st];
                        I[tid] += I[tid + st]; J[tid] += J[tid + st]; }
        __syncthreads();
    }
    if (tid == 0) {
        int cpv = I[0] < 1 ? 1 : I[0];
        int cnv = J[0] < 1 ? 1 : J[0];
        out[0] = (float)(A[0] / ((double)cpv * NCLS) +
                         B[0] / ((double)cnv * NCLS) +
                         C[0] / ((double)ROWS * DE));
    }
}

static inline int pad8(int x) { return (x + 7) & ~7; }

extern "C" void kernel_launch(void* const* d_in, const int* in_sizes, int n_in,
                              void* d_out, int out_size, void* d_ws, size_t ws_size,
                              hipStream_t stream)
{
    const float* det    = (const float*)d_in[0];
    const float* traj   = (const float*)d_in[1];
    const float* relpos = (const float*)d_in[2];
    const float* cw     = (const float*)d_in[3];
    const float* W1     = (const float*)d_in[4];
    const float* b1     = (const float*)d_in[5];
    const float* W2     = (const float*)d_in[6];
    const float* b2     = (const float*)d_in[7];
    const float* W3     = (const float*)d_in[8];
    const float* R1     = (const float*)d_in[9];
    const float* rb1    = (const float*)d_in[10];
    const float* R2     = (const float*)d_in[11];
    const float* temp   = (const float*)d_in[12];
    const int*   labels = (const int*)d_in[13];
    const int*   sids   = (const int*)d_in[14];
    const int*   oids   = (const int*)d_in[15];
    float* out = (float*)d_out;

    // ---- Workspace carve (footprint identical to R4: 225.2MB @ b_ch=16) ---
    char* ws = (char*)d_ws;
    size_t off = 0;
    auto carve = [&](size_t bytes) -> char* {
        char* p = ws + off;
        off = (off + bytes + 255) & ~(size_t)255;
        return p;
    };
    float4* pn       = (float4*)carve((size_t)ROWS * 16);               // 577KB
    float*  dist_arr = (float*)carve((size_t)ROWS * 4);                 // 144KB
    short*  det_bf   = (short*)carve((size_t)BSZ * NDET * DF * 2);      // 3.1MB
    short*  W1t      = (short*)carve((size_t)2048 * 2048 * 2);          // 8.4MB
    short*  W2t      = (short*)carve((size_t)DH * DH * 2);              // 2.1MB
    short*  W3t      = (short*)carve((size_t)DE * DH * 2);              // 1.0MB
    short*  R2t      = (short*)carve((size_t)DE * 256 * 2);             // 0.26MB
    short*  cwt      = (short*)carve((size_t)NPAD * DE * 2);            // 131KB
    short*  UVa      = (short*)carve((size_t)BSZ * NDET * 2048 * 2);    // 3.1MB
    short*  UVb      = (short*)carve((size_t)BSZ * NDET * 2048 * 2);    // 3.1MB
    size_t fixed_off = off;

    // Per-chunk regions (rows = b_ch*PAIRS), same 5632B/row as R4:
    //   reg1: h1 bf16 [rows,1024] -> so_proj bf16 [rows,512]
    //   reg2: h2 bf16 [rows,1024] -> re_un  bf16 [rows,512]
    //   reg3: rh bf16 [rows,256]  -> logits fp32 [rows,128]
    //   comb: bf16 [rows,512]
    int b_ch = 1;
    for (int cand : {16, 8, 4, 2, 1}) {
        size_t rows  = (size_t)cand * PAIRS;
        size_t bytes = fixed_off + rows * 2048 + 256 + rows * 2048 + 256
                     + rows * 512 + 256 + rows * 1024 + 256;
        if (bytes <= ws_size) { b_ch = cand; break; }
    }
    const int chunk_rows = b_ch * PAIRS;
    const int n_chunks = BSZ / b_ch;
    char* reg1 = carve((size_t)chunk_rows * 2048);
    char* reg2 = carve((size_t)chunk_rows * 2048);
    char* reg3 = carve((size_t)chunk_rows * 512);
    short* comb_bf = (short*)carve((size_t)chunk_rows * 1024);

    short* h1      = (short*)reg1;
    short* h2      = (short*)reg2;
    short* so_bf   = (short*)reg1;    // overwrites h1 (dead after h2 GEMM)
    short* re_bf   = (short*)reg2;    // overwrites h2 (dead after so_proj GEMM)
    short* rh      = (short*)reg3;
    float* logits  = (float*)reg3;    // overwrites rh (dead after re_un GEMM)

    // ---- Prep (2 launches) ------------------------------------------------
    convert_all_kernel<<<(N4DET + N4CWT + 255) / 256, 256, 0, stream>>>(
        det, det_bf, cw, cwt);

    TransJobs tj;
    tj.src[0] = W1;                    tj.dst[0] = W1t;                  tj.K[0] = DF;  tj.N[0] = DH;
    tj.src[1] = W1 + (size_t)DF * DH;  tj.dst[1] = W1t + (size_t)DH * DF; tj.K[1] = DF; tj.N[1] = DH;
    tj.src[2] = W2;                    tj.dst[2] = W2t;                  tj.K[2] = DH;  tj.N[2] = DH;
    tj.src[3] = W3;                    tj.dst[3] = W3t;                  tj.K[3] = DH;  tj.N[3] = DE;
    tj.src[4] = R2;                    tj.dst[4] = R2t;                  tj.K[4] = 256; tj.N[4] = DE;
    tj.cum[0] = 0;
    for (int i = 0; i < 5; ++i)
        tj.cum[i + 1] = tj.cum[i] + (tj.K[i] / 32) * (tj.N[i] / 32);
    transpose_multi_kernel<<<tj.cum[5], 256, 0, stream>>>(tj);

    // UV split-K halves: UVa = det_bf[:, :1024] @ W1t[:, :1024]^T etc.
    // (768 x 2048 x 1024 each; 192 blocks total vs 96 unsplit)
    mfma_gemm<false, false, true, false><<<dim3(2048 / 128, 6), 256, 0, stream>>>(
        det_bf,        W1t,        nullptr, UVa, BSZ * NDET, 2048, 1024, 2048, 2048);
    mfma_gemm<false, false, true, false><<<dim3(2048 / 128, 6), 256, 0, stream>>>(
        det_bf + 1024, W1t + 1024, nullptr, UVb, BSZ * NDET, 2048, 1024, 2048, 2048);

    const int mg  = (chunk_rows + 127) / 128;
    const int mgp = pad8(mg);

    for (int c = 0; c < n_chunks; ++c) {
        int b0 = c * b_ch;
        int r0 = b0 * PAIRS;

        pairs_kernel<<<chunk_rows, 256, 0, stream>>>(UVa, UVb, b1, sids, oids, h1, b0);

        // h2 = bf16(relu(h1 @ W2 + b2))          (rows x 1024 x 1024)
        mfma_gemm<true, true, true, true><<<dim3(DH / 128, mgp), 256, 0, stream>>>(
            h1, W2t, b2, h2, chunk_rows, DH, DH, DH, DH);

        // so_bf = bf16(h2 @ W3)                  (rows x 1024 -> 512)
        mfma_gemm<false, false, true, true><<<dim3(DE / 128, mgp), 256, 0, stream>>>(
            h2, W3t, nullptr, so_bf, chunk_rows, DE, DH, DH, DH);

        rh_kernel<<<chunk_rows, 256, 0, stream>>>(relpos, R1, rb1, rh, r0);

        // re_bf = bf16(rh @ R2)                  (rows x 256 -> 512)
        mfma_gemm<false, false, true, true><<<dim3(DE / 128, mgp), 256, 0, stream>>>(
            rh, R2t, nullptr, re_bf, chunk_rows, DE, 256, 256, 256);

        // comb_bf = bf16(combined/temp), dist partials
        row_prep_kernel<<<chunk_rows / 4, 256, 0, stream>>>(
            so_bf, re_bf, traj, temp, sids, oids, comb_bf, dist_arr, b0);

        // logits = comb_bf @ cw^T                (rows x 512 -> 128, fp32)
        mfma_gemm<false, false, false, true><<<dim3(1, mgp), 256, 0, stream>>>(
            comb_bf, cwt, nullptr, logits, chunk_rows, NPAD, DE, DE, DE);

        focal_kernel<<<chunk_rows / 4, 256, 0, stream>>>(logits, labels, pn, b0);
    }

    reduce_kernel<<<1, 256, 0, stream>>>(pn, dist_arr, out);
}

// Round 6
// 516.517 us; speedup vs baseline: 9.6787x; 1.0102x over previous
//
#include <hip/hip_runtime.h>
#include <math.h>

// Problem constants
constexpr int BSZ   = 16;
constexpr int NDET  = 48;
constexpr int PAIRS = NDET * (NDET - 1);      // 2256
constexpr int ROWS  = BSZ * PAIRS;            // 36096
constexpr int DF    = 2048;
constexpr int DH    = 1024;
constexpr int DE    = 512;
constexpr int EHALF = 256;
constexpr int NCLS  = 92;
constexpr int NPAD  = 128;                    // logits N padded for GEMM
constexpr int LABW  = 1 + 92 + 40;            // 133

typedef __attribute__((ext_vector_type(8))) short bf16x8;   // 8 bf16 in 4 VGPRs
typedef __attribute__((ext_vector_type(4))) float f32x4;

__device__ __forceinline__ short f2bf(float f) {
    union { float f; unsigned u; } a; a.f = f;
    unsigned r = a.u + 0x7fffu + ((a.u >> 16) & 1u);   // RNE
    return (short)(r >> 16);
}
__device__ __forceinline__ float bf2f(short h) {
    union { unsigned u; float f; } x;
    x.u = ((unsigned)(unsigned short)h) << 16;
    return x.f;
}

// ---------------------------------------------------------------------------
// Fused elementwise prep: det fp32->bf16 then cwt build (zero-padded rows).
// ---------------------------------------------------------------------------
constexpr int N4DET = BSZ * NDET * DF / 4;    // 393216
constexpr int N4CWT = NPAD * DE / 4;          // 16384
__global__ __launch_bounds__(256) void convert_all_kernel(
    const float* __restrict__ det, short* __restrict__ det_bf,
    const float* __restrict__ cw, short* __restrict__ cwt)
{
    int i = blockIdx.x * 256 + threadIdx.x;
    if (i < N4DET) {
        float4 v = ((const float4*)det)[i];
        short4 o;
        o.x = f2bf(v.x); o.y = f2bf(v.y); o.z = f2bf(v.z); o.w = f2bf(v.w);
        ((short4*)det_bf)[i] = o;
    } else if (i < N4DET + N4CWT) {
        int k = i - N4DET;
        int n = (k * 4) >> 9;                 // cwt row
        short4 o = {0, 0, 0, 0};
        if (n < NCLS) {
            float4 v = ((const float4*)cw)[k];
            o.x = f2bf(v.x); o.y = f2bf(v.y); o.z = f2bf(v.z); o.w = f2bf(v.w);
        }
        ((short4*)cwt)[k] = o;
    }
}

// ---------------------------------------------------------------------------
// Multi-job transpose+convert: src fp32 [K][N] -> dst bf16 [N][K].
// ---------------------------------------------------------------------------
struct TransJobs {
    const float* src[5];
    short*       dst[5];
    int K[5], N[5];
    int cum[6];
};
__global__ __launch_bounds__(256) void transpose_multi_kernel(TransJobs jobs) {
    __shared__ float tile[32][33];
    int t = blockIdx.x;
    int j = 0;
    while (t >= jobs.cum[j + 1]) ++j;
    int lt = t - jobs.cum[j];
    int K = jobs.K[j], N = jobs.N[j];
    int nx = N >> 5;
    int ky = lt / nx, nxi = lt - ky * nx;
    int n0 = nxi * 32, k0 = ky * 32;
    const float* src = jobs.src[j];
    short* dst = jobs.dst[j];
    int tx = threadIdx.x & 31, ty = threadIdx.x >> 5;
#pragma unroll
    for (int i = ty; i < 32; i += 8)
        tile[i][tx] = src[(size_t)(k0 + i) * N + n0 + tx];
    __syncthreads();
#pragma unroll
    for (int i = ty; i < 32; i += 8)
        dst[(size_t)(n0 + i) * K + k0 + tx] = f2bf(tile[tx][i]);
}

// ---------------------------------------------------------------------------
// MFMA bf16 GEMM. A bf16 [M,lda]; Bt bf16 [N,ldb]. N%128==0, K%32==0.
// 128x128 tile, BK=32, 4 waves. __launch_bounds__(256,4): total regs<=128
// (64 AGPR acc + arch) -> 4 blocks/CU (was 3 at 136 regs, Occupancy 30%).
// SWIZZLE: XCD-aware remap (R5: FETCH 292->61MB). DUAL: second job at
// by>=msplit (merged UV halves). FOCAL: fused focal-loss epilogue via
// per-row LDS atomics (kills logits round-trip + focal kernel).
// OUTBF16: LDS-repack epilogue -> 8 coalesced 16B stores/lane (was 64
// scattered 2B stores) — cuts the K-independent epilogue tax at short K.
// ---------------------------------------------------------------------------
__device__ __forceinline__ void load16_lds(const void* g, void* l) {
    __builtin_amdgcn_global_load_lds(
        (const __attribute__((address_space(1))) unsigned int*)g,
        (__attribute__((address_space(3))) unsigned int*)l, 16, 0, 0);
}

template <bool BIAS, bool RELU, bool OUTBF16, bool SWIZZLE, bool FOCAL, bool DUAL>
__global__ __launch_bounds__(256, 4) void mfma_gemm(
    const short* __restrict__ A, const short* __restrict__ Bt,
    const float* __restrict__ bias, void* __restrict__ C,
    int M, int N, int K, int lda, int ldb,
    const short* A2, const short* Bt2, void* C2, int msplit,
    const int* __restrict__ labels, float4* __restrict__ pn, int r0)
{
    __shared__ short smem[2 * 128 * 32];          // As | Bs, 16 KB
    __shared__ float rowacc[FOCAL ? 384 : 4];     // focal per-row accumulators
    short* As = smem;
    short* Bs = smem + 128 * 32;

    int bx, by;
    if (SWIZZLE) {
        int nb  = gridDim.x;
        int gid = blockIdx.y * nb + blockIdx.x;
        int xcd = gid & 7;
        int j   = gid >> 3;
        int rows_per = gridDim.y >> 3;
        int lr  = j / nb;
        bx = j - lr * nb;
        by = xcd * rows_per + lr;
        if (by * 128 >= M) return;
    } else {
        bx = blockIdx.x; by = blockIdx.y;
    }
    if (DUAL) {
        if (by >= msplit) { A = A2; Bt = Bt2; C = C2; by -= msplit; }
    }

    const int tid  = threadIdx.x;
    const int wave = tid >> 6;
    const int lane = tid & 63;
    const int m0 = by * 128;
    const int n0 = bx * 128;
    const int wm = (wave & 1) * 64;
    const int wn = (wave >> 1) * 64;

    f32x4 acc[4][4] = {};

    const int q  = lane >> 4;
    const int lm = lane & 15;

    for (int k0 = 0; k0 < K; k0 += 32) {
#pragma unroll
        for (int it = 0; it < 2; ++it) {
            int c   = it * 256 + tid;
            int row = c >> 2;
            int kk  = (c & 3) * 8;
            int ldsc = (it * 256 + wave * 64) * 8;  // wave-uniform chunk base
            int gm = m0 + row; if (gm >= M) gm = M - 1;
            load16_lds(A + (size_t)gm * lda + k0 + kk, As + ldsc);
            int gn = n0 + row;                       // N%128==0: no tail
            load16_lds(Bt + (size_t)gn * ldb + k0 + kk, Bs + ldsc);
        }
        __syncthreads();

        bf16x8 af[4], bfr[4];
#pragma unroll
        for (int t = 0; t < 4; ++t) {
            af[t]  = *(const bf16x8*)(As + (wm + t * 16 + lm) * 32 + q * 8);
            bfr[t] = *(const bf16x8*)(Bs + (wn + t * 16 + lm) * 32 + q * 8);
        }
#pragma unroll
        for (int tm = 0; tm < 4; ++tm)
#pragma unroll
            for (int tn = 0; tn < 4; ++tn)
                acc[tm][tn] = __builtin_amdgcn_mfma_f32_16x16x32_bf16(
                    af[tm], bfr[tn], acc[tm][tn], 0, 0, 0);
        __syncthreads();
    }

    // C/D layout: col=lane&15, row=(lane>>4)*4+reg (m89-verified)
    if (FOCAL) {
        // 1) zero per-row accumulators
        for (int i = tid; i < 384; i += 256) rowacc[i] = 0.0f;
        __syncthreads();
        // 2) each lane folds its 16 logits into row accumulators
#pragma unroll
        for (int tm = 0; tm < 4; ++tm) {
#pragma unroll
            for (int tn = 0; tn < 4; ++tn) {
                int col = wn + tn * 16 + lm;          // n0 == 0 (single col tile)
#pragma unroll
                for (int r = 0; r < 4; ++r) {
                    int row = wm + tm * 16 + q * 4 + r;
                    int grow = m0 + row;
                    if (col < NCLS && grow < M) {
                        float l = acc[tm][tn][r];
                        int rg = r0 + grow;
                        int t = labels[(size_t)rg * LABW + 1 + col];
                        float tf = (float)t;
                        float pr = 1.0f / (1.0f + expf(-l));
                        float lg = log1pf(expf(-fabsf(l)));
                        float ce = fmaxf(l, 0.0f) - l * tf + lg;
                        float pt = pr * tf + (1.0f - pr) * (1.0f - tf);
                        float om = 1.0f - pt;
                        float at = 0.25f * tf + 0.75f * (1.0f - tf);
                        atomicAdd(&rowacc[row], at * ce * om * om);
                        float ce0 = fmaxf(l, 0.0f) + lg;
                        atomicAdd(&rowacc[128 + row], 0.75f * ce0 * pr * pr);
                        if (t > 0) rowacc[256 + row] = 1.0f;   // same-value race: ok
                    }
                }
            }
        }
        __syncthreads();
        // 3) one thread per row writes the partial
        if (tid < 128) {
            int grow = m0 + tid;
            if (grow < M) {
                int rg = r0 + grow;
                int posf = (rowacc[256 + tid] > 0.5f) ? 1 : 0;
                int negf = (labels[(size_t)rg * LABW] > 0) ? 1 : 0;
                pn[rg] = make_float4(posf ? rowacc[tid] : 0.0f,
                                     negf ? rowacc[128 + tid] : 0.0f,
                                     0.0f, (float)(posf + 2 * negf));
            }
        }
    } else if (OUTBF16) {
        // LDS-repack epilogue: wave-private 16x64 fp32 scratch per tm.
        float* scratch = (float*)smem + wave * 1024;   // 4 KB per wave
#pragma unroll
        for (int tm = 0; tm < 4; ++tm) {
            __syncthreads();    // protect scratch from previous tm's readers
#pragma unroll
            for (int tn = 0; tn < 4; ++tn) {
                float bv = BIAS ? bias[n0 + wn + tn * 16 + lm] : 0.0f;
#pragma unroll
                for (int r = 0; r < 4; ++r) {
                    float v = acc[tm][tn][r] + bv;
                    if (RELU) v = fmaxf(v, 0.0f);
                    scratch[(q * 4 + r) * 64 + tn * 16 + lm] = v;
                }
            }
            __syncthreads();    // ordering of LDS write->read
#pragma unroll
            for (int p = 0; p < 2; ++p) {
                int row16 = (lane >> 3) + p * 8;
                int c0 = (lane & 7) * 8;
                float4 v0 = *(float4*)&scratch[row16 * 64 + c0];
                float4 v1 = *(float4*)&scratch[row16 * 64 + c0 + 4];
                bf16x8 o;
                o[0] = f2bf(v0.x); o[1] = f2bf(v0.y); o[2] = f2bf(v0.z); o[3] = f2bf(v0.w);
                o[4] = f2bf(v1.x); o[5] = f2bf(v1.y); o[6] = f2bf(v1.z); o[7] = f2bf(v1.w);
                int grow = m0 + wm + tm * 16 + row16;
                if (grow < M)
                    *(bf16x8*)((short*)C + (size_t)grow * N + n0 + wn + c0) = o;
            }
        }
    } else {
        // fp32 scalar store path (currently unused)
#pragma unroll
        for (int tm = 0; tm < 4; ++tm)
#pragma unroll
            for (int tn = 0; tn < 4; ++tn) {
                int col = n0 + wn + tn * 16 + lm;
#pragma unroll
                for (int r = 0; r < 4; ++r) {
                    int row = m0 + wm + tm * 16 + q * 4 + r;
                    if (row < M) {
                        float v = acc[tm][tn][r];
                        if (BIAS) v += bias[col];
                        if (RELU) v = fmaxf(v, 0.0f);
                        ((float*)C)[(size_t)row * N + col] = v;
                    }
                }
            }
    }
}

// ---------------------------------------------------------------------------
// h1[r,:] = bf16(relu(UVa[s']+UVb[s'] + UVa[o'+1024]+UVb[o'+1024] + b1))
// ---------------------------------------------------------------------------
__global__ __launch_bounds__(256) void pairs_kernel(
    const short* __restrict__ UVa, const short* __restrict__ UVb,
    const float* __restrict__ b1,
    const int* __restrict__ sids, const int* __restrict__ oids,
    short* __restrict__ h1, int b0)
{
    int r = blockIdx.x;
    int b = b0 + r / PAIRS;
    int p = r % PAIRS;
    size_t soff = (size_t)(b * NDET + sids[p]) * 2048;
    size_t ooff = (size_t)(b * NDET + oids[p]) * 2048 + 1024;
    int j = threadIdx.x;
    short4 a1 = ((const short4*)(UVa + soff))[j];
    short4 a2 = ((const short4*)(UVb + soff))[j];
    short4 a3 = ((const short4*)(UVa + ooff))[j];
    short4 a4 = ((const short4*)(UVb + ooff))[j];
    float4 bb = ((const float4*)b1)[j];
    short4 h;
    h.x = f2bf(fmaxf(bf2f(a1.x) + bf2f(a2.x) + bf2f(a3.x) + bf2f(a4.x) + bb.x, 0.0f));
    h.y = f2bf(fmaxf(bf2f(a1.y) + bf2f(a2.y) + bf2f(a3.y) + bf2f(a4.y) + bb.y, 0.0f));
    h.z = f2bf(fmaxf(bf2f(a1.z) + bf2f(a2.z) + bf2f(a3.z) + bf2f(a4.z) + bb.z, 0.0f));
    h.w = f2bf(fmaxf(bf2f(a1.w) + bf2f(a2.w) + bf2f(a3.w) + bf2f(a4.w) + bb.w, 0.0f));
    ((short4*)(h1 + (size_t)r * DH))[j] = h;
}

// ---------------------------------------------------------------------------
// rh[r,j] = bf16(relu(sum_k rp[r,k]*R1[k,j] + rb1[j]))
// ---------------------------------------------------------------------------
__global__ __launch_bounds__(256) void rh_kernel(
    const float* __restrict__ rp, const float* __restrict__ R1,
    const float* __restrict__ rb1, short* __restrict__ rh, int r0)
{
    int r = blockIdx.x;
    int j = threadIdx.x;
    const float* row = rp + (size_t)(r0 + r) * 12;
    float acc = rb1[j];
#pragma unroll
    for (int k = 0; k < 12; ++k) acc = fmaf(row[k], R1[k * 256 + j], acc);
    rh[(size_t)r * 256 + j] = f2bf(fmaxf(acc, 0.0f));
}

// ---------------------------------------------------------------------------
// row_prep: one wave per row, butterfly reductions.
// ---------------------------------------------------------------------------
__global__ __launch_bounds__(256) void row_prep_kernel(
    const short* __restrict__ sp_bf, const short* __restrict__ ru_bf,
    const float* __restrict__ traj, const float* __restrict__ temperature,
    const int* __restrict__ sids, const int* __restrict__ oids,
    short* __restrict__ comb_bf, float* __restrict__ dist_arr, int b0)
{
    int wave = threadIdx.x >> 6, lane = threadIdx.x & 63;
    int r = blockIdx.x * 4 + wave;
    int rg = b0 * PAIRS + r;
    int b = b0 + r / PAIRS;
    int p = r % PAIRS;

    bf16x8 sv = ((const bf16x8*)(sp_bf + (size_t)r * DE))[lane];
    bf16x8 uv = ((const bf16x8*)(ru_bf + (size_t)r * DE))[lane];
    float s[8], u[8];
#pragma unroll
    for (int i = 0; i < 8; ++i) { s[i] = bf2f(sv[i]); u[i] = bf2f(uv[i]); }

    const float* tsrc = (lane < 32)
        ? (traj + (size_t)(b * NDET + sids[p]) * EHALF + lane * 8)
        : (traj + (size_t)(b * NDET + oids[p]) * EHALF + (lane - 32) * 8);
    float4 t0 = ((const float4*)tsrc)[0], t1 = ((const float4*)tsrc)[1];
    float t[8] = {t0.x, t0.y, t0.z, t0.w, t1.x, t1.y, t1.z, t1.w};

    float ss = 0.0f, sr = 0.0f, sd = 0.0f;
#pragma unroll
    for (int i = 0; i < 8; ++i) {
        ss += s[i] * s[i];
        sr += u[i] * u[i];
        sd += fabsf(t[i] - s[i]);
    }
#pragma unroll
    for (int m = 1; m < 64; m <<= 1) {
        ss += __shfl_xor(ss, m);
        sr += __shfl_xor(sr, m);
        sd += __shfl_xor(sd, m);
    }
    float inv_s = 1.0f / fmaxf(sqrtf(ss), 1e-12f);
    float inv_r = 1.0f / fmaxf(sqrtf(sr), 1e-12f);

    float c[8], sc = 0.0f;
#pragma unroll
    for (int i = 0; i < 8; ++i) {
        c[i] = s[i] * inv_s + u[i] * inv_r;
        sc += c[i] * c[i];
    }
#pragma unroll
    for (int m = 1; m < 64; m <<= 1) sc += __shfl_xor(sc, m);

    float scale = (1.0f / fmaxf(sqrtf(sc), 1e-12f)) / temperature[0];

    bf16x8 o;
#pragma unroll
    for (int i = 0; i < 8; ++i) o[i] = f2bf(c[i] * scale);
    ((bf16x8*)(comb_bf + (size_t)r * DE))[lane] = o;

    if (lane == 0) dist_arr[rg] = sd;
}

// ---------------------------------------------------------------------------
// Final reduce.
// ---------------------------------------------------------------------------
__global__ __launch_bounds__(256) void reduce_kernel(
    const float4* __restrict__ pn, const float* __restrict__ dist_arr,
    float* __restrict__ out)
{
    int tid = threadIdx.x;
    double sp = 0.0, sn = 0.0, sd = 0.0;
    int cp = 0, cn = 0;
    for (int i = tid; i < ROWS; i += 256) {
        float4 v = pn[i];
        sp += (double)v.x; sn += (double)v.y; sd += (double)dist_arr[i];
        int f = (int)v.w;
        cp += f & 1; cn += (f >> 1) & 1;
    }
    __shared__ double A[256], B[256], C[256];
    __shared__ int I[256], J[256];
    A[tid] = sp; B[tid] = sn; C[tid] = sd; I[tid] = cp; J[tid] = cn;
    __syncthreads();
    for (int st = 128; st > 0; st >>= 1) {
        if (tid < st) { A[tid] += A[tid + st]; B[tid] += B[tid + st]; C[tid] += C[tid + st];
                        I[tid] += I[tid + st]; J[tid] += J[tid + st]; }
        __syncthreads();
    }
    if (tid == 0) {
        int cpv = I[0] < 1 ? 1 : I[0];
        int cnv = J[0] < 1 ? 1 : J[0];
        out[0] = (float)(A[0] / ((double)cpv * NCLS) +
                         B[0] / ((double)cnv * NCLS) +
                         C[0] / ((double)ROWS * DE));
    }
}

static inline int pad8(int x) { return (x + 7) & ~7; }

extern "C" void kernel_launch(void* const* d_in, const int* in_sizes, int n_in,
                              void* d_out, int out_size, void* d_ws, size_t ws_size,
                              hipStream_t stream)
{
    const float* det    = (const float*)d_in[0];
    const float* traj   = (const float*)d_in[1];
    const float* relpos = (const float*)d_in[2];
    const float* cw     = (const float*)d_in[3];
    const float* W1     = (const float*)d_in[4];
    const float* b1     = (const float*)d_in[5];
    const float* W2     = (const float*)d_in[6];
    const float* b2     = (const float*)d_in[7];
    const float* W3     = (const float*)d_in[8];
    const float* R1     = (const float*)d_in[9];
    const float* rb1    = (const float*)d_in[10];
    const float* R2     = (const float*)d_in[11];
    const float* temp   = (const float*)d_in[12];
    const int*   labels = (const int*)d_in[13];
    const int*   sids   = (const int*)d_in[14];
    const int*   oids   = (const int*)d_in[15];
    float* out = (float*)d_out;

    // ---- Workspace carve (footprint identical to R4/R5) -------------------
    char* ws = (char*)d_ws;
    size_t off = 0;
    auto carve = [&](size_t bytes) -> char* {
        char* p = ws + off;
        off = (off + bytes + 255) & ~(size_t)255;
        return p;
    };
    float4* pn       = (float4*)carve((size_t)ROWS * 16);
    float*  dist_arr = (float*)carve((size_t)ROWS * 4);
    short*  det_bf   = (short*)carve((size_t)BSZ * NDET * DF * 2);
    short*  W1t      = (short*)carve((size_t)2048 * 2048 * 2);
    short*  W2t      = (short*)carve((size_t)DH * DH * 2);
    short*  W3t      = (short*)carve((size_t)DE * DH * 2);
    short*  R2t      = (short*)carve((size_t)DE * 256 * 2);
    short*  cwt      = (short*)carve((size_t)NPAD * DE * 2);
    short*  UVa      = (short*)carve((size_t)BSZ * NDET * 2048 * 2);
    short*  UVb      = (short*)carve((size_t)BSZ * NDET * 2048 * 2);
    size_t fixed_off = off;

    int b_ch = 1;
    for (int cand : {16, 8, 4, 2, 1}) {
        size_t rows  = (size_t)cand * PAIRS;
        size_t bytes = fixed_off + rows * 2048 + 256 + rows * 2048 + 256
                     + rows * 512 + 256 + rows * 1024 + 256;
        if (bytes <= ws_size) { b_ch = cand; break; }
    }
    const int chunk_rows = b_ch * PAIRS;
    const int n_chunks = BSZ / b_ch;
    char* reg1 = carve((size_t)chunk_rows * 2048);
    char* reg2 = carve((size_t)chunk_rows * 2048);
    char* reg3 = carve((size_t)chunk_rows * 512);
    short* comb_bf = (short*)carve((size_t)chunk_rows * 1024);

    short* h1      = (short*)reg1;
    short* h2      = (short*)reg2;
    short* so_bf   = (short*)reg1;    // overwrites h1 (dead after h2 GEMM)
    short* re_bf   = (short*)reg2;    // overwrites h2 (dead after so_proj GEMM)
    short* rh      = (short*)reg3;

    // ---- Prep -------------------------------------------------------------
    convert_all_kernel<<<(N4DET + N4CWT + 255) / 256, 256, 0, stream>>>(
        det, det_bf, cw, cwt);

    TransJobs tj;
    tj.src[0] = W1;                    tj.dst[0] = W1t;                   tj.K[0] = DF;  tj.N[0] = DH;
    tj.src[1] = W1 + (size_t)DF * DH;  tj.dst[1] = W1t + (size_t)DH * DF; tj.K[1] = DF;  tj.N[1] = DH;
    tj.src[2] = W2;                    tj.dst[2] = W2t;                   tj.K[2] = DH;  tj.N[2] = DH;
    tj.src[3] = W3;                    tj.dst[3] = W3t;                   tj.K[3] = DH;  tj.N[3] = DE;
    tj.src[4] = R2;                    tj.dst[4] = R2t;                   tj.K[4] = 256; tj.N[4] = DE;
    tj.cum[0] = 0;
    for (int i = 0; i < 5; ++i)
        tj.cum[i + 1] = tj.cum[i] + (tj.K[i] / 32) * (tj.N[i] / 32);
    transpose_multi_kernel<<<tj.cum[5], 256, 0, stream>>>(tj);

    // UV split-K halves, merged into ONE 192-block launch (DUAL).
    mfma_gemm<false, false, true, false, false, true>
        <<<dim3(2048 / 128, 12), 256, 0, stream>>>(
        det_bf, W1t, nullptr, UVa, BSZ * NDET, 2048, 1024, 2048, 2048,
        det_bf + 1024, W1t + 1024, UVb, 6, nullptr, nullptr, 0);

    const int mg  = (chunk_rows + 127) / 128;
    const int mgp = pad8(mg);

    for (int c = 0; c < n_chunks; ++c) {
        int b0 = c * b_ch;
        int r0 = b0 * PAIRS;

        pairs_kernel<<<chunk_rows, 256, 0, stream>>>(UVa, UVb, b1, sids, oids, h1, b0);

        // h2 = bf16(relu(h1 @ W2 + b2))
        mfma_gemm<true, true, true, true, false, false>
            <<<dim3(DH / 128, mgp), 256, 0, stream>>>(
            h1, W2t, b2, h2, chunk_rows, DH, DH, DH, DH,
            nullptr, nullptr, nullptr, 0, nullptr, nullptr, 0);

        // so_bf = bf16(h2 @ W3)
        mfma_gemm<false, false, true, true, false, false>
            <<<dim3(DE / 128, mgp), 256, 0, stream>>>(
            h2, W3t, nullptr, so_bf, chunk_rows, DE, DH, DH, DH,
            nullptr, nullptr, nullptr, 0, nullptr, nullptr, 0);

        rh_kernel<<<chunk_rows, 256, 0, stream>>>(relpos, R1, rb1, rh, r0);

        // re_bf = bf16(rh @ R2)
        mfma_gemm<false, false, true, true, false, false>
            <<<dim3(DE / 128, mgp), 256, 0, stream>>>(
            rh, R2t, nullptr, re_bf, chunk_rows, DE, 256, 256, 256,
            nullptr, nullptr, nullptr, 0, nullptr, nullptr, 0);

        row_prep_kernel<<<chunk_rows / 4, 256, 0, stream>>>(
            so_bf, re_bf, traj, temp, sids, oids, comb_bf, dist_arr, b0);

        // logits GEMM + fused focal epilogue (no logits buffer, no focal pass)
        mfma_gemm<false, false, false, true, true, false>
            <<<dim3(1, mgp), 256, 0, stream>>>(
            comb_bf, cwt, nullptr, nullptr, chunk_rows, NPAD, DE, DE, DE,
            nullptr, nullptr, nullptr, 0, labels, pn, r0);
    }

    reduce_kernel<<<1, 256, 0, stream>>>(pn, dist_arr, out);
}

// Round 7
// 462.925 us; speedup vs baseline: 10.7992x; 1.1158x over previous
//
#include <hip/hip_runtime.h>
#include <math.h>

// Problem constants
constexpr int BSZ   = 16;
constexpr int NDET  = 48;
constexpr int PAIRS = NDET * (NDET - 1);      // 2256
constexpr int ROWS  = BSZ * PAIRS;            // 36096
constexpr int DF    = 2048;
constexpr int DH    = 1024;
constexpr int DE    = 512;
constexpr int EHALF = 256;
constexpr int NCLS  = 92;
constexpr int NPAD  = 128;                    // logits N padded for GEMM
constexpr int LABW  = 1 + 92 + 40;            // 133

typedef __attribute__((ext_vector_type(8))) short bf16x8;   // 8 bf16 in 4 VGPRs
typedef __attribute__((ext_vector_type(4))) float f32x4;

__device__ __forceinline__ short f2bf(float f) {
    union { float f; unsigned u; } a; a.f = f;
    unsigned r = a.u + 0x7fffu + ((a.u >> 16) & 1u);   // RNE
    return (short)(r >> 16);
}
__device__ __forceinline__ float bf2f(short h) {
    union { unsigned u; float f; } x;
    x.u = ((unsigned)(unsigned short)h) << 16;
    return x.f;
}

// ---------------------------------------------------------------------------
// Merged prep: blocks [0,1600): det fp32->bf16 + cwt build;
// blocks [1600, 1600+5760): 5-job transpose+convert (W1 top/bot, W2, W3, R2).
// ---------------------------------------------------------------------------
constexpr int N4DET = BSZ * NDET * DF / 4;    // 393216
constexpr int N4CWT = NPAD * DE / 4;          // 16384
constexpr int NCONVB = (N4DET + N4CWT) / 256; // 1600 exactly

struct TransJobs {
    const float* src[5];
    short*       dst[5];
    int K[5], N[5];
    int cum[6];
};

__global__ __launch_bounds__(256) void prep_kernel(
    const float* __restrict__ det, short* __restrict__ det_bf,
    const float* __restrict__ cw, short* __restrict__ cwt, TransJobs jobs)
{
    if (blockIdx.x < NCONVB) {
        int i = blockIdx.x * 256 + threadIdx.x;
        if (i < N4DET) {
            float4 v = ((const float4*)det)[i];
            short4 o;
            o.x = f2bf(v.x); o.y = f2bf(v.y); o.z = f2bf(v.z); o.w = f2bf(v.w);
            ((short4*)det_bf)[i] = o;
        } else {
            int k = i - N4DET;
            int n = (k * 4) >> 9;
            short4 o = {0, 0, 0, 0};
            if (n < NCLS) {
                float4 v = ((const float4*)cw)[k];
                o.x = f2bf(v.x); o.y = f2bf(v.y); o.z = f2bf(v.z); o.w = f2bf(v.w);
            }
            ((short4*)cwt)[k] = o;
        }
        return;
    }
    __shared__ float tile[32][33];
    int t = blockIdx.x - NCONVB;
    int j = 0;
    while (t >= jobs.cum[j + 1]) ++j;
    int lt = t - jobs.cum[j];
    int K = jobs.K[j], N = jobs.N[j];
    int nx = N >> 5;
    int ky = lt / nx, nxi = lt - ky * nx;
    int n0 = nxi * 32, k0 = ky * 32;
    const float* src = jobs.src[j];
    short* dst = jobs.dst[j];
    int tx = threadIdx.x & 31, ty = threadIdx.x >> 5;
#pragma unroll
    for (int i = ty; i < 32; i += 8)
        tile[i][tx] = src[(size_t)(k0 + i) * N + n0 + tx];
    __syncthreads();
#pragma unroll
    for (int i = ty; i < 32; i += 8)
        dst[(size_t)(n0 + i) * K + k0 + tx] = f2bf(tile[tx][i]);
}

// ---------------------------------------------------------------------------
// MFMA bf16 GEMM. A bf16 [M,lda]; Bt bf16 [N,ldb]. N%128==0, K%32==0.
// 128x128 tile, BK=32, 4 waves, __launch_bounds__(256,4).
// SWIZZLE: XCD-aware remap (R5: FETCH 292->61MB).
// DUAL: bx>=nsplit selects job2 (own A/Bt/C/K/lda/ldb) — bx-split keeps
//   XCD load balance (by-split would segregate jobs by XCD).
// FOCAL: fused focal epilogue; shfl-reduce over lm then 1 atomic per
//   quad-row (was 128 16-way-serialized LDS atomics per block).
// OUTBF16: LDS-repack store, scratch stride 68 floats (2-way = free).
// ---------------------------------------------------------------------------
__device__ __forceinline__ void load16_lds(const void* g, void* l) {
    __builtin_amdgcn_global_load_lds(
        (const __attribute__((address_space(1))) unsigned int*)g,
        (__attribute__((address_space(3))) unsigned int*)l, 16, 0, 0);
}

template <bool BIAS, bool RELU, bool OUTBF16, bool SWIZZLE, bool FOCAL, bool DUAL>
__global__ __launch_bounds__(256, 4) void mfma_gemm(
    const short* __restrict__ A, const short* __restrict__ Bt,
    const float* __restrict__ bias, void* __restrict__ C,
    int M, int N, int K, int lda, int ldb,
    const short* A2, const short* Bt2, void* C2, int nsplit,
    int K2, int lda2, int ldb2,
    const int* __restrict__ labels, float4* __restrict__ pn, int r0)
{
    __shared__ __align__(16) char smem_raw[17408];   // staging 16KB | scratch 17.4KB
    __shared__ float rowacc[FOCAL ? 384 : 4];
    short* As = (short*)smem_raw;
    short* Bs = As + 128 * 32;

    int bx, by;
    if (SWIZZLE) {
        int nb  = gridDim.x;
        int gid = blockIdx.y * nb + blockIdx.x;
        int xcd = gid & 7;
        int j   = gid >> 3;
        int rows_per = gridDim.y >> 3;
        int lr  = j / nb;
        bx = j - lr * nb;
        by = xcd * rows_per + lr;
    } else {
        bx = blockIdx.x; by = blockIdx.y;
    }
    if (DUAL && bx >= nsplit) {
        bx -= nsplit; A = A2; Bt = Bt2; C = C2; K = K2; lda = lda2; ldb = ldb2;
    }
    if (by * 128 >= M) return;                      // padded tail

    const int tid  = threadIdx.x;
    const int wave = tid >> 6;
    const int lane = tid & 63;
    const int m0 = by * 128;
    const int n0 = bx * 128;
    const int wm = (wave & 1) * 64;
    const int wn = (wave >> 1) * 64;

    f32x4 acc[4][4] = {};

    const int q  = lane >> 4;
    const int lm = lane & 15;

    for (int k0 = 0; k0 < K; k0 += 32) {
#pragma unroll
        for (int it = 0; it < 2; ++it) {
            int c   = it * 256 + tid;
            int row = c >> 2;
            int kk  = (c & 3) * 8;
            int ldsc = (it * 256 + wave * 64) * 8;  // wave-uniform chunk base
            int gm = m0 + row; if (gm >= M) gm = M - 1;
            load16_lds(A + (size_t)gm * lda + k0 + kk, As + ldsc);
            int gn = n0 + row;                       // N%128==0: no tail
            load16_lds(Bt + (size_t)gn * ldb + k0 + kk, Bs + ldsc);
        }
        __syncthreads();

        bf16x8 af[4], bfr[4];
#pragma unroll
        for (int t = 0; t < 4; ++t) {
            af[t]  = *(const bf16x8*)(As + (wm + t * 16 + lm) * 32 + q * 8);
            bfr[t] = *(const bf16x8*)(Bs + (wn + t * 16 + lm) * 32 + q * 8);
        }
#pragma unroll
        for (int tm = 0; tm < 4; ++tm)
#pragma unroll
            for (int tn = 0; tn < 4; ++tn)
                acc[tm][tn] = __builtin_amdgcn_mfma_f32_16x16x32_bf16(
                    af[tm], bfr[tn], acc[tm][tn], 0, 0, 0);
        __syncthreads();
    }

    // C/D layout: col=lane&15, row=(lane>>4)*4+reg (m89-verified)
    if (FOCAL) {
        for (int i = tid; i < 384; i += 256) rowacc[i] = 0.0f;
        __syncthreads();
#pragma unroll
        for (int tm = 0; tm < 4; ++tm) {
#pragma unroll
            for (int r = 0; r < 4; ++r) {
                int row  = wm + tm * 16 + q * 4 + r;
                int grow = m0 + row;
                float fp = 0.0f, fn = 0.0f, fmflag = 0.0f;
                if (grow < M) {
                    size_t labbase = (size_t)(r0 + grow) * LABW;
#pragma unroll
                    for (int tn = 0; tn < 4; ++tn) {
                        int col = wn + tn * 16 + lm;
                        if (col < NCLS) {
                            float l = acc[tm][tn][r];
                            int t = labels[labbase + 1 + col];
                            float tf = (float)t;
                            float pr = 1.0f / (1.0f + expf(-l));
                            float lg = log1pf(expf(-fabsf(l)));
                            float ce = fmaxf(l, 0.0f) - l * tf + lg;
                            float pt = pr * tf + (1.0f - pr) * (1.0f - tf);
                            float om = 1.0f - pt;
                            float at = 0.25f * tf + 0.75f * (1.0f - tf);
                            fp += at * ce * om * om;
                            float ce0 = fmaxf(l, 0.0f) + lg;
                            fn += 0.75f * ce0 * pr * pr;
                            if (t > 0) fmflag = 1.0f;
                        }
                    }
                }
                // reduce over the 16 lm lanes of this quad
#pragma unroll
                for (int m = 1; m < 16; m <<= 1) {
                    fp += __shfl_xor(fp, m);
                    fn += __shfl_xor(fn, m);
                    fmflag += __shfl_xor(fmflag, m);
                }
                if (lm == 0 && grow < M) {
                    atomicAdd(&rowacc[row], fp);
                    atomicAdd(&rowacc[128 + row], fn);
                    if (fmflag > 0.5f) rowacc[256 + row] = 1.0f;
                }
            }
        }
        __syncthreads();
        if (tid < 128) {
            int grow = m0 + tid;
            if (grow < M) {
                int rg = r0 + grow;
                int posf = (rowacc[256 + tid] > 0.5f) ? 1 : 0;
                int negf = (labels[(size_t)rg * LABW] > 0) ? 1 : 0;
                pn[rg] = make_float4(posf ? rowacc[tid] : 0.0f,
                                     negf ? rowacc[128 + tid] : 0.0f,
                                     0.0f, (float)(posf + 2 * negf));
            }
        }
    } else if (OUTBF16) {
        // LDS-repack epilogue: 16x68 fp32 scratch per wave (stride 68: 2-way
        // write aliasing = free; 64 was 4-way).
        float* scratch = (float*)smem_raw + wave * (16 * 68);
#pragma unroll
        for (int tm = 0; tm < 4; ++tm) {
            __syncthreads();
#pragma unroll
            for (int tn = 0; tn < 4; ++tn) {
                float bv = BIAS ? bias[n0 + wn + tn * 16 + lm] : 0.0f;
#pragma unroll
                for (int r = 0; r < 4; ++r) {
                    float v = acc[tm][tn][r] + bv;
                    if (RELU) v = fmaxf(v, 0.0f);
                    scratch[(q * 4 + r) * 68 + tn * 16 + lm] = v;
                }
            }
            __syncthreads();
#pragma unroll
            for (int p = 0; p < 2; ++p) {
                int row16 = (lane >> 3) + p * 8;
                int c0 = (lane & 7) * 8;
                float4 v0 = *(float4*)&scratch[row16 * 68 + c0];
                float4 v1 = *(float4*)&scratch[row16 * 68 + c0 + 4];
                bf16x8 o;
                o[0] = f2bf(v0.x); o[1] = f2bf(v0.y); o[2] = f2bf(v0.z); o[3] = f2bf(v0.w);
                o[4] = f2bf(v1.x); o[5] = f2bf(v1.y); o[6] = f2bf(v1.z); o[7] = f2bf(v1.w);
                int grow = m0 + wm + tm * 16 + row16;
                if (grow < M)
                    *(bf16x8*)((short*)C + (size_t)grow * N + n0 + wn + c0) = o;
            }
        }
    } else {
        // fp32 scalar store path (unused currently)
#pragma unroll
        for (int tm = 0; tm < 4; ++tm)
#pragma unroll
            for (int tn = 0; tn < 4; ++tn) {
                int col = n0 + wn + tn * 16 + lm;
#pragma unroll
                for (int r = 0; r < 4; ++r) {
                    int row = m0 + wm + tm * 16 + q * 4 + r;
                    if (row < M) {
                        float v = acc[tm][tn][r];
                        if (BIAS) v += bias[col];
                        if (RELU) v = fmaxf(v, 0.0f);
                        ((float*)C)[(size_t)row * N + col] = v;
                    }
                }
            }
    }
}

// ---------------------------------------------------------------------------
// Fused pairs + rh (one block per row):
//   h1[r,:] = bf16(relu(UVa[s']+UVb[s'] + UVa[o'+1024]+UVb[o'+1024] + b1))
//   rh[r,j] = bf16(relu(sum_k rp[rg,k]*R1[k,j] + rb1[j]))
// ---------------------------------------------------------------------------
__global__ __launch_bounds__(256) void pairs_rh_kernel(
    const short* __restrict__ UVa, const short* __restrict__ UVb,
    const float* __restrict__ b1,
    const int* __restrict__ sids, const int* __restrict__ oids,
    short* __restrict__ h1,
    const float* __restrict__ rp, const float* __restrict__ R1,
    const float* __restrict__ rb1, short* __restrict__ rh, int b0)
{
    int r = blockIdx.x;
    int b = b0 + r / PAIRS;
    int p = r % PAIRS;
    int j = threadIdx.x;

    // pairs part: 256 threads x short4 = 1024 elems
    size_t soff = (size_t)(b * NDET + sids[p]) * 2048;
    size_t ooff = (size_t)(b * NDET + oids[p]) * 2048 + 1024;
    short4 a1 = ((const short4*)(UVa + soff))[j];
    short4 a2 = ((const short4*)(UVb + soff))[j];
    short4 a3 = ((const short4*)(UVa + ooff))[j];
    short4 a4 = ((const short4*)(UVb + ooff))[j];
    float4 bb = ((const float4*)b1)[j];
    short4 h;
    h.x = f2bf(fmaxf(bf2f(a1.x) + bf2f(a2.x) + bf2f(a3.x) + bf2f(a4.x) + bb.x, 0.0f));
    h.y = f2bf(fmaxf(bf2f(a1.y) + bf2f(a2.y) + bf2f(a3.y) + bf2f(a4.y) + bb.y, 0.0f));
    h.z = f2bf(fmaxf(bf2f(a1.z) + bf2f(a2.z) + bf2f(a3.z) + bf2f(a4.z) + bb.z, 0.0f));
    h.w = f2bf(fmaxf(bf2f(a1.w) + bf2f(a2.w) + bf2f(a3.w) + bf2f(a4.w) + bb.w, 0.0f));
    ((short4*)(h1 + (size_t)r * DH))[j] = h;

    // rh part: 256 threads = 256 outputs
    int rg = b0 * PAIRS + r;
    const float* row = rp + (size_t)rg * 12;
    float acc = rb1[j];
#pragma unroll
    for (int k = 0; k < 12; ++k) acc = fmaf(row[k], R1[k * 256 + j], acc);
    rh[(size_t)r * 256 + j] = f2bf(fmaxf(acc, 0.0f));
}

// ---------------------------------------------------------------------------
// row_prep: one wave per row, butterfly reductions.
// ---------------------------------------------------------------------------
__global__ __launch_bounds__(256) void row_prep_kernel(
    const short* __restrict__ sp_bf, const short* __restrict__ ru_bf,
    const float* __restrict__ traj, const float* __restrict__ temperature,
    const int* __restrict__ sids, const int* __restrict__ oids,
    short* __restrict__ comb_bf, float* __restrict__ dist_arr, int b0)
{
    int wave = threadIdx.x >> 6, lane = threadIdx.x & 63;
    int r = blockIdx.x * 4 + wave;
    int rg = b0 * PAIRS + r;
    int b = b0 + r / PAIRS;
    int p = r % PAIRS;

    bf16x8 sv = ((const bf16x8*)(sp_bf + (size_t)r * DE))[lane];
    bf16x8 uv = ((const bf16x8*)(ru_bf + (size_t)r * DE))[lane];
    float s[8], u[8];
#pragma unroll
    for (int i = 0; i < 8; ++i) { s[i] = bf2f(sv[i]); u[i] = bf2f(uv[i]); }

    const float* tsrc = (lane < 32)
        ? (traj + (size_t)(b * NDET + sids[p]) * EHALF + lane * 8)
        : (traj + (size_t)(b * NDET + oids[p]) * EHALF + (lane - 32) * 8);
    float4 t0 = ((const float4*)tsrc)[0], t1 = ((const float4*)tsrc)[1];
    float t[8] = {t0.x, t0.y, t0.z, t0.w, t1.x, t1.y, t1.z, t1.w};

    float ss = 0.0f, sr = 0.0f, sd = 0.0f;
#pragma unroll
    for (int i = 0; i < 8; ++i) {
        ss += s[i] * s[i];
        sr += u[i] * u[i];
        sd += fabsf(t[i] - s[i]);
    }
#pragma unroll
    for (int m = 1; m < 64; m <<= 1) {
        ss += __shfl_xor(ss, m);
        sr += __shfl_xor(sr, m);
        sd += __shfl_xor(sd, m);
    }
    float inv_s = 1.0f / fmaxf(sqrtf(ss), 1e-12f);
    float inv_r = 1.0f / fmaxf(sqrtf(sr), 1e-12f);

    float c[8], sc = 0.0f;
#pragma unroll
    for (int i = 0; i < 8; ++i) {
        c[i] = s[i] * inv_s + u[i] * inv_r;
        sc += c[i] * c[i];
    }
#pragma unroll
    for (int m = 1; m < 64; m <<= 1) sc += __shfl_xor(sc, m);

    float scale = (1.0f / fmaxf(sqrtf(sc), 1e-12f)) / temperature[0];

    bf16x8 o;
#pragma unroll
    for (int i = 0; i < 8; ++i) o[i] = f2bf(c[i] * scale);
    ((bf16x8*)(comb_bf + (size_t)r * DE))[lane] = o;

    if (lane == 0) dist_arr[rg] = sd;
}

// ---------------------------------------------------------------------------
// Final reduce.
// ---------------------------------------------------------------------------
__global__ __launch_bounds__(256) void reduce_kernel(
    const float4* __restrict__ pn, const float* __restrict__ dist_arr,
    float* __restrict__ out)
{
    int tid = threadIdx.x;
    double sp = 0.0, sn = 0.0, sd = 0.0;
    int cp = 0, cn = 0;
    for (int i = tid; i < ROWS; i += 256) {
        float4 v = pn[i];
        sp += (double)v.x; sn += (double)v.y; sd += (double)dist_arr[i];
        int f = (int)v.w;
        cp += f & 1; cn += (f >> 1) & 1;
    }
    __shared__ double A[256], B[256], C[256];
    __shared__ int I[256], J[256];
    A[tid] = sp; B[tid] = sn; C[tid] = sd; I[tid] = cp; J[tid] = cn;
    __syncthreads();
    for (int st = 128; st > 0; st >>= 1) {
        if (tid < st) { A[tid] += A[tid + st]; B[tid] += B[tid + st]; C[tid] += C[tid + st];
                        I[tid] += I[tid + st]; J[tid] += J[tid + st]; }
        __syncthreads();
    }
    if (tid == 0) {
        int cpv = I[0] < 1 ? 1 : I[0];
        int cnv = J[0] < 1 ? 1 : J[0];
        out[0] = (float)(A[0] / ((double)cpv * NCLS) +
                         B[0] / ((double)cnv * NCLS) +
                         C[0] / ((double)ROWS * DE));
    }
}

static inline int pad8(int x) { return (x + 7) & ~7; }

extern "C" void kernel_launch(void* const* d_in, const int* in_sizes, int n_in,
                              void* d_out, int out_size, void* d_ws, size_t ws_size,
                              hipStream_t stream)
{
    const float* det    = (const float*)d_in[0];
    const float* traj   = (const float*)d_in[1];
    const float* relpos = (const float*)d_in[2];
    const float* cw     = (const float*)d_in[3];
    const float* W1     = (const float*)d_in[4];
    const float* b1     = (const float*)d_in[5];
    const float* W2     = (const float*)d_in[6];
    const float* b2     = (const float*)d_in[7];
    const float* W3     = (const float*)d_in[8];
    const float* R1     = (const float*)d_in[9];
    const float* rb1    = (const float*)d_in[10];
    const float* R2     = (const float*)d_in[11];
    const float* temp   = (const float*)d_in[12];
    const int*   labels = (const int*)d_in[13];
    const int*   sids   = (const int*)d_in[14];
    const int*   oids   = (const int*)d_in[15];
    float* out = (float*)d_out;

    // ---- Workspace carve (footprint identical to R4-R6) -------------------
    char* ws = (char*)d_ws;
    size_t off = 0;
    auto carve = [&](size_t bytes) -> char* {
        char* p = ws + off;
        off = (off + bytes + 255) & ~(size_t)255;
        return p;
    };
    float4* pn       = (float4*)carve((size_t)ROWS * 16);
    float*  dist_arr = (float*)carve((size_t)ROWS * 4);
    short*  det_bf   = (short*)carve((size_t)BSZ * NDET * DF * 2);
    short*  W1t      = (short*)carve((size_t)2048 * 2048 * 2);
    short*  W2t      = (short*)carve((size_t)DH * DH * 2);
    short*  W3t      = (short*)carve((size_t)DE * DH * 2);
    short*  R2t      = (short*)carve((size_t)DE * 256 * 2);
    short*  cwt      = (short*)carve((size_t)NPAD * DE * 2);
    short*  UVa      = (short*)carve((size_t)BSZ * NDET * 2048 * 2);
    short*  UVb      = (short*)carve((size_t)BSZ * NDET * 2048 * 2);
    size_t fixed_off = off;

    int b_ch = 1;
    for (int cand : {16, 8, 4, 2, 1}) {
        size_t rows  = (size_t)cand * PAIRS;
        size_t bytes = fixed_off + rows * 2048 + 256 + rows * 2048 + 256
                     + rows * 512 + 256 + rows * 1024 + 256;
        if (bytes <= ws_size) { b_ch = cand; break; }
    }
    const int chunk_rows = b_ch * PAIRS;
    const int n_chunks = BSZ / b_ch;
    char* reg1 = carve((size_t)chunk_rows * 2048);
    char* reg2 = carve((size_t)chunk_rows * 2048);
    char* reg3 = carve((size_t)chunk_rows * 512);
    short* comb_bf = (short*)carve((size_t)chunk_rows * 1024);

    short* h1      = (short*)reg1;
    short* h2      = (short*)reg2;
    short* so_bf   = (short*)reg1;    // overwrites h1 (dead after h2 GEMM)
    short* re_bf   = (short*)reg2;    // overwrites h2 (dead after so GEMM)
    short* rh      = (short*)reg3;

    // ---- Prep (1 launch) --------------------------------------------------
    TransJobs tj;
    tj.src[0] = W1;                    tj.dst[0] = W1t;                   tj.K[0] = DF;  tj.N[0] = DH;
    tj.src[1] = W1 + (size_t)DF * DH;  tj.dst[1] = W1t + (size_t)DH * DF; tj.K[1] = DF;  tj.N[1] = DH;
    tj.src[2] = W2;                    tj.dst[2] = W2t;                   tj.K[2] = DH;  tj.N[2] = DH;
    tj.src[3] = W3;                    tj.dst[3] = W3t;                   tj.K[3] = DH;  tj.N[3] = DE;
    tj.src[4] = R2;                    tj.dst[4] = R2t;                   tj.K[4] = 256; tj.N[4] = DE;
    tj.cum[0] = 0;
    for (int i = 0; i < 5; ++i)
        tj.cum[i + 1] = tj.cum[i] + (tj.K[i] / 32) * (tj.N[i] / 32);
    prep_kernel<<<NCONVB + tj.cum[5], 256, 0, stream>>>(det, det_bf, cw, cwt, tj);

    // UV split-K halves, one DUAL launch split on bx (grid 32x6 = 192 blocks).
    mfma_gemm<false, false, true, false, false, true>
        <<<dim3(32, 6), 256, 0, stream>>>(
        det_bf, W1t, nullptr, UVa, BSZ * NDET, 2048, 1024, 2048, 2048,
        det_bf + 1024, W1t + 1024, UVb, 16, 1024, 2048, 2048,
        nullptr, nullptr, 0);

    const int mg  = (chunk_rows + 127) / 128;
    const int mgp = pad8(mg);

    for (int c = 0; c < n_chunks; ++c) {
        int b0 = c * b_ch;
        int r0 = b0 * PAIRS;

        pairs_rh_kernel<<<chunk_rows, 256, 0, stream>>>(
            UVa, UVb, b1, sids, oids, h1, relpos, R1, rb1, rh, b0);

        // h2 = bf16(relu(h1 @ W2 + b2))
        mfma_gemm<true, true, true, true, false, false>
            <<<dim3(DH / 128, mgp), 256, 0, stream>>>(
            h1, W2t, b2, h2, chunk_rows, DH, DH, DH, DH,
            nullptr, nullptr, nullptr, 0, 0, 0, 0, nullptr, nullptr, 0);

        // so_bf = bf16(h2 @ W3)  +  re_bf = bf16(rh @ R2): one DUAL launch,
        // bx<4 -> so (K=1024), bx>=4 -> re (K=256). Balanced across XCDs.
        mfma_gemm<false, false, true, true, false, true>
            <<<dim3(8, mgp), 256, 0, stream>>>(
            h2, W3t, nullptr, so_bf, chunk_rows, DE, DH, DH, DH,
            rh, R2t, re_bf, 4, 256, 256, 256, nullptr, nullptr, 0);

        row_prep_kernel<<<chunk_rows / 4, 256, 0, stream>>>(
            so_bf, re_bf, traj, temp, sids, oids, comb_bf, dist_arr, b0);

        // logits GEMM + fused focal epilogue
        mfma_gemm<false, false, false, true, true, false>
            <<<dim3(1, mgp), 256, 0, stream>>>(
            comb_bf, cwt, nullptr, nullptr, chunk_rows, NPAD, DE, DE, DE,
            nullptr, nullptr, nullptr, 0, 0, 0, 0, labels, pn, r0);
    }

    reduce_kernel<<<1, 256, 0, stream>>>(pn, dist_arr, out);
}

// Round 8
// 423.320 us; speedup vs baseline: 11.8095x; 1.0936x over previous
//
#include <hip/hip_runtime.h>
#include <math.h>

// Problem constants
constexpr int BSZ   = 16;
constexpr int NDET  = 48;
constexpr int PAIRS = NDET * (NDET - 1);      // 2256
constexpr int ROWS  = BSZ * PAIRS;            // 36096
constexpr int DF    = 2048;
constexpr int DH    = 1024;
constexpr int DE    = 512;
constexpr int EHALF = 256;
constexpr int NCLS  = 92;
constexpr int NPAD  = 128;                    // logits N padded for GEMM
constexpr int LABW  = 1 + 92 + 40;            // 133

typedef __attribute__((ext_vector_type(8))) short bf16x8;   // 8 bf16 in 4 VGPRs
typedef __attribute__((ext_vector_type(4))) float f32x4;

__device__ __forceinline__ short f2bf(float f) {
    union { float f; unsigned u; } a; a.f = f;
    unsigned r = a.u + 0x7fffu + ((a.u >> 16) & 1u);   // RNE
    return (short)(r >> 16);
}
__device__ __forceinline__ float bf2f(short h) {
    union { unsigned u; float f; } x;
    x.u = ((unsigned)(unsigned short)h) << 16;
    return x.f;
}

// ---------------------------------------------------------------------------
// Merged prep: blocks [0,1600): det fp32->bf16 + cwt build;
// blocks [1600, 1600+5760): 5-job transpose+convert (W1 top/bot, W2, W3, R2).
// ---------------------------------------------------------------------------
constexpr int N4DET = BSZ * NDET * DF / 4;    // 393216
constexpr int N4CWT = NPAD * DE / 4;          // 16384
constexpr int NCONVB = (N4DET + N4CWT) / 256; // 1600 exactly

struct TransJobs {
    const float* src[5];
    short*       dst[5];
    int K[5], N[5];
    int cum[6];
};

__global__ __launch_bounds__(256) void prep_kernel(
    const float* __restrict__ det, short* __restrict__ det_bf,
    const float* __restrict__ cw, short* __restrict__ cwt, TransJobs jobs)
{
    if (blockIdx.x < NCONVB) {
        int i = blockIdx.x * 256 + threadIdx.x;
        if (i < N4DET) {
            float4 v = ((const float4*)det)[i];
            short4 o;
            o.x = f2bf(v.x); o.y = f2bf(v.y); o.z = f2bf(v.z); o.w = f2bf(v.w);
            ((short4*)det_bf)[i] = o;
        } else {
            int k = i - N4DET;
            int n = (k * 4) >> 9;
            short4 o = {0, 0, 0, 0};
            if (n < NCLS) {
                float4 v = ((const float4*)cw)[k];
                o.x = f2bf(v.x); o.y = f2bf(v.y); o.z = f2bf(v.z); o.w = f2bf(v.w);
            }
            ((short4*)cwt)[k] = o;
        }
        return;
    }
    __shared__ float tile[32][33];
    int t = blockIdx.x - NCONVB;
    int j = 0;
    while (t >= jobs.cum[j + 1]) ++j;
    int lt = t - jobs.cum[j];
    int K = jobs.K[j], N = jobs.N[j];
    int nx = N >> 5;
    int ky = lt / nx, nxi = lt - ky * nx;
    int n0 = nxi * 32, k0 = ky * 32;
    const float* src = jobs.src[j];
    short* dst = jobs.dst[j];
    int tx = threadIdx.x & 31, ty = threadIdx.x >> 5;
#pragma unroll
    for (int i = ty; i < 32; i += 8)
        tile[i][tx] = src[(size_t)(k0 + i) * N + n0 + tx];
    __syncthreads();
#pragma unroll
    for (int i = ty; i < 32; i += 8)
        dst[(size_t)(n0 + i) * K + k0 + tx] = f2bf(tile[tx][i]);
}

// ---------------------------------------------------------------------------
// MFMA bf16 GEMM. A bf16 [M,lda]; Bt bf16 [N,ldb]. N%128==0, K%32==0.
// 128x128 tile, BK=32, 4 waves, __launch_bounds__(256,4).
// SWIZZLE: XCD-aware remap (R5: FETCH 292->61MB).
// DUAL: bx>=nsplit selects job2. OUTBF16: LDS-repack store (stride 68).
// Focal is UNFUSED (R8): the R6 fused epilogue ran on a 282-block grid
// (1.1 blocks/CU) with 33% active lanes — net regression vs standalone.
// ---------------------------------------------------------------------------
__device__ __forceinline__ void load16_lds(const void* g, void* l) {
    __builtin_amdgcn_global_load_lds(
        (const __attribute__((address_space(1))) unsigned int*)g,
        (__attribute__((address_space(3))) unsigned int*)l, 16, 0, 0);
}

template <bool BIAS, bool RELU, bool OUTBF16, bool SWIZZLE, bool DUAL>
__global__ __launch_bounds__(256, 4) void mfma_gemm(
    const short* __restrict__ A, const short* __restrict__ Bt,
    const float* __restrict__ bias, void* __restrict__ C,
    int M, int N, int K, int lda, int ldb,
    const short* A2, const short* Bt2, void* C2, int nsplit,
    int K2, int lda2, int ldb2)
{
    __shared__ __align__(16) char smem_raw[17408];   // staging 16KB | scratch 17.4KB
    short* As = (short*)smem_raw;
    short* Bs = As + 128 * 32;

    int bx, by;
    if (SWIZZLE) {
        int nb  = gridDim.x;
        int gid = blockIdx.y * nb + blockIdx.x;
        int xcd = gid & 7;
        int j   = gid >> 3;
        int rows_per = gridDim.y >> 3;
        int lr  = j / nb;
        bx = j - lr * nb;
        by = xcd * rows_per + lr;
    } else {
        bx = blockIdx.x; by = blockIdx.y;
    }
    if (DUAL && bx >= nsplit) {
        bx -= nsplit; A = A2; Bt = Bt2; C = C2; K = K2; lda = lda2; ldb = ldb2;
    }
    if (by * 128 >= M) return;                      // padded tail

    const int tid  = threadIdx.x;
    const int wave = tid >> 6;
    const int lane = tid & 63;
    const int m0 = by * 128;
    const int n0 = bx * 128;
    const int wm = (wave & 1) * 64;
    const int wn = (wave >> 1) * 64;

    f32x4 acc[4][4] = {};

    const int q  = lane >> 4;
    const int lm = lane & 15;

    for (int k0 = 0; k0 < K; k0 += 32) {
#pragma unroll
        for (int it = 0; it < 2; ++it) {
            int c   = it * 256 + tid;
            int row = c >> 2;
            int kk  = (c & 3) * 8;
            int ldsc = (it * 256 + wave * 64) * 8;  // wave-uniform chunk base
            int gm = m0 + row; if (gm >= M) gm = M - 1;
            load16_lds(A + (size_t)gm * lda + k0 + kk, As + ldsc);
            int gn = n0 + row;                       // N%128==0: no tail
            load16_lds(Bt + (size_t)gn * ldb + k0 + kk, Bs + ldsc);
        }
        __syncthreads();

        bf16x8 af[4], bfr[4];
#pragma unroll
        for (int t = 0; t < 4; ++t) {
            af[t]  = *(const bf16x8*)(As + (wm + t * 16 + lm) * 32 + q * 8);
            bfr[t] = *(const bf16x8*)(Bs + (wn + t * 16 + lm) * 32 + q * 8);
        }
#pragma unroll
        for (int tm = 0; tm < 4; ++tm)
#pragma unroll
            for (int tn = 0; tn < 4; ++tn)
                acc[tm][tn] = __builtin_amdgcn_mfma_f32_16x16x32_bf16(
                    af[tm], bfr[tn], acc[tm][tn], 0, 0, 0);
        __syncthreads();
    }

    // C/D layout: col=lane&15, row=(lane>>4)*4+reg (m89-verified)
    if (OUTBF16) {
        // LDS-repack epilogue: 16x68 fp32 scratch per wave (2-way = free).
        float* scratch = (float*)smem_raw + wave * (16 * 68);
#pragma unroll
        for (int tm = 0; tm < 4; ++tm) {
            __syncthreads();
#pragma unroll
            for (int tn = 0; tn < 4; ++tn) {
                float bv = BIAS ? bias[n0 + wn + tn * 16 + lm] : 0.0f;
#pragma unroll
                for (int r = 0; r < 4; ++r) {
                    float v = acc[tm][tn][r] + bv;
                    if (RELU) v = fmaxf(v, 0.0f);
                    scratch[(q * 4 + r) * 68 + tn * 16 + lm] = v;
                }
            }
            __syncthreads();
#pragma unroll
            for (int p = 0; p < 2; ++p) {
                int row16 = (lane >> 3) + p * 8;
                int c0 = (lane & 7) * 8;
                float4 v0 = *(float4*)&scratch[row16 * 68 + c0];
                float4 v1 = *(float4*)&scratch[row16 * 68 + c0 + 4];
                bf16x8 o;
                o[0] = f2bf(v0.x); o[1] = f2bf(v0.y); o[2] = f2bf(v0.z); o[3] = f2bf(v0.w);
                o[4] = f2bf(v1.x); o[5] = f2bf(v1.y); o[6] = f2bf(v1.z); o[7] = f2bf(v1.w);
                int grow = m0 + wm + tm * 16 + row16;
                if (grow < M)
                    *(bf16x8*)((short*)C + (size_t)grow * N + n0 + wn + c0) = o;
            }
        }
    } else {
        // fp32 direct store (logits path: N=128, 64B runs per quad)
#pragma unroll
        for (int tm = 0; tm < 4; ++tm)
#pragma unroll
            for (int tn = 0; tn < 4; ++tn) {
                int col = n0 + wn + tn * 16 + lm;
#pragma unroll
                for (int r = 0; r < 4; ++r) {
                    int row = m0 + wm + tm * 16 + q * 4 + r;
                    if (row < M) {
                        float v = acc[tm][tn][r];
                        if (BIAS) v += bias[col];
                        if (RELU) v = fmaxf(v, 0.0f);
                        ((float*)C)[(size_t)row * N + col] = v;
                    }
                }
            }
    }
}

// ---------------------------------------------------------------------------
// Fused pairs + rh (one block per row).
// ---------------------------------------------------------------------------
__global__ __launch_bounds__(256) void pairs_rh_kernel(
    const short* __restrict__ UVa, const short* __restrict__ UVb,
    const float* __restrict__ b1,
    const int* __restrict__ sids, const int* __restrict__ oids,
    short* __restrict__ h1,
    const float* __restrict__ rp, const float* __restrict__ R1,
    const float* __restrict__ rb1, short* __restrict__ rh, int b0)
{
    int r = blockIdx.x;
    int b = b0 + r / PAIRS;
    int p = r % PAIRS;
    int j = threadIdx.x;

    size_t soff = (size_t)(b * NDET + sids[p]) * 2048;
    size_t ooff = (size_t)(b * NDET + oids[p]) * 2048 + 1024;
    short4 a1 = ((const short4*)(UVa + soff))[j];
    short4 a2 = ((const short4*)(UVb + soff))[j];
    short4 a3 = ((const short4*)(UVa + ooff))[j];
    short4 a4 = ((const short4*)(UVb + ooff))[j];
    float4 bb = ((const float4*)b1)[j];
    short4 h;
    h.x = f2bf(fmaxf(bf2f(a1.x) + bf2f(a2.x) + bf2f(a3.x) + bf2f(a4.x) + bb.x, 0.0f));
    h.y = f2bf(fmaxf(bf2f(a1.y) + bf2f(a2.y) + bf2f(a3.y) + bf2f(a4.y) + bb.y, 0.0f));
    h.z = f2bf(fmaxf(bf2f(a1.z) + bf2f(a2.z) + bf2f(a3.z) + bf2f(a4.z) + bb.z, 0.0f));
    h.w = f2bf(fmaxf(bf2f(a1.w) + bf2f(a2.w) + bf2f(a3.w) + bf2f(a4.w) + bb.w, 0.0f));
    ((short4*)(h1 + (size_t)r * DH))[j] = h;

    int rg = b0 * PAIRS + r;
    const float* row = rp + (size_t)rg * 12;
    float acc = rb1[j];
#pragma unroll
    for (int k = 0; k < 12; ++k) acc = fmaf(row[k], R1[k * 256 + j], acc);
    rh[(size_t)r * 256 + j] = f2bf(fmaxf(acc, 0.0f));
}

// ---------------------------------------------------------------------------
// row_prep: one wave per row, butterfly reductions.
// ---------------------------------------------------------------------------
__global__ __launch_bounds__(256) void row_prep_kernel(
    const short* __restrict__ sp_bf, const short* __restrict__ ru_bf,
    const float* __restrict__ traj, const float* __restrict__ temperature,
    const int* __restrict__ sids, const int* __restrict__ oids,
    short* __restrict__ comb_bf, float* __restrict__ dist_arr, int b0)
{
    int wave = threadIdx.x >> 6, lane = threadIdx.x & 63;
    int r = blockIdx.x * 4 + wave;
    int rg = b0 * PAIRS + r;
    int b = b0 + r / PAIRS;
    int p = r % PAIRS;

    bf16x8 sv = ((const bf16x8*)(sp_bf + (size_t)r * DE))[lane];
    bf16x8 uv = ((const bf16x8*)(ru_bf + (size_t)r * DE))[lane];
    float s[8], u[8];
#pragma unroll
    for (int i = 0; i < 8; ++i) { s[i] = bf2f(sv[i]); u[i] = bf2f(uv[i]); }

    const float* tsrc = (lane < 32)
        ? (traj + (size_t)(b * NDET + sids[p]) * EHALF + lane * 8)
        : (traj + (size_t)(b * NDET + oids[p]) * EHALF + (lane - 32) * 8);
    float4 t0 = ((const float4*)tsrc)[0], t1 = ((const float4*)tsrc)[1];
    float t[8] = {t0.x, t0.y, t0.z, t0.w, t1.x, t1.y, t1.z, t1.w};

    float ss = 0.0f, sr = 0.0f, sd = 0.0f;
#pragma unroll
    for (int i = 0; i < 8; ++i) {
        ss += s[i] * s[i];
        sr += u[i] * u[i];
        sd += fabsf(t[i] - s[i]);
    }
#pragma unroll
    for (int m = 1; m < 64; m <<= 1) {
        ss += __shfl_xor(ss, m);
        sr += __shfl_xor(sr, m);
        sd += __shfl_xor(sd, m);
    }
    float inv_s = 1.0f / fmaxf(sqrtf(ss), 1e-12f);
    float inv_r = 1.0f / fmaxf(sqrtf(sr), 1e-12f);

    float c[8], sc = 0.0f;
#pragma unroll
    for (int i = 0; i < 8; ++i) {
        c[i] = s[i] * inv_s + u[i] * inv_r;
        sc += c[i] * c[i];
    }
#pragma unroll
    for (int m = 1; m < 64; m <<= 1) sc += __shfl_xor(sc, m);

    float scale = (1.0f / fmaxf(sqrtf(sc), 1e-12f)) / temperature[0];

    bf16x8 o;
#pragma unroll
    for (int i = 0; i < 8; ++i) o[i] = f2bf(c[i] * scale);
    ((bf16x8*)(comb_bf + (size_t)r * DE))[lane] = o;

    if (lane == 0) dist_arr[rg] = sd;
}

// ---------------------------------------------------------------------------
// focal (standalone, R4-style): one wave per row over 92 coalesced logits.
// ---------------------------------------------------------------------------
__global__ __launch_bounds__(256) void focal_kernel(
    const float* __restrict__ logits, const int* __restrict__ labels,
    float4* __restrict__ pn, int b0)
{
    int wave = threadIdx.x >> 6, lane = threadIdx.x & 63;
    int r = blockIdx.x * 4 + wave;
    int rg = b0 * PAIRS + r;
    const float* lrow = logits + (size_t)r * NPAD;
    size_t labbase = (size_t)rg * LABW;

    float flp = 0.0f, fln = 0.0f, fm = 0.0f;
    for (int c = lane; c < NCLS; c += 64) {
        float l = lrow[c];
        int t = labels[labbase + 1 + c];
        if (t > 0) fm = 1.0f;
        float tf = (float)t;
        float pr = 1.0f / (1.0f + expf(-l));
        float lg = log1pf(expf(-fabsf(l)));
        float ce = fmaxf(l, 0.0f) - l * tf + lg;
        float pt = pr * tf + (1.0f - pr) * (1.0f - tf);
        float om = 1.0f - pt;
        float at = 0.25f * tf + 0.75f * (1.0f - tf);
        flp += at * ce * om * om;
        float ce0 = fmaxf(l, 0.0f) + lg;
        fln += 0.75f * ce0 * pr * pr;
    }
#pragma unroll
    for (int m = 1; m < 64; m <<= 1) {
        flp += __shfl_xor(flp, m);
        fln += __shfl_xor(fln, m);
        fm  += __shfl_xor(fm, m);
    }
    if (lane == 0) {
        int posf = (fm > 0.5f) ? 1 : 0;
        int negf = (labels[labbase] > 0) ? 1 : 0;
        pn[rg] = make_float4(posf ? flp : 0.0f, negf ? fln : 0.0f, 0.0f,
                             (float)(posf + 2 * negf));
    }
}

// ---------------------------------------------------------------------------
// Two-stage final reduce (stage1: 64 blocks -> scratch; stage2: 1 wave).
// ---------------------------------------------------------------------------
struct RedRec { double sp, sn, sd; int cp, cn; };   // 40B -> pad 48
constexpr int RED1 = 64;
constexpr int ROWS_PER_RED = ROWS / RED1;           // 564

__global__ __launch_bounds__(256) void reduce1_kernel(
    const float4* __restrict__ pn, const float* __restrict__ dist_arr,
    RedRec* __restrict__ scratch)
{
    int tid = threadIdx.x;
    int base = blockIdx.x * ROWS_PER_RED;
    double sp = 0.0, sn = 0.0, sd = 0.0;
    int cp = 0, cn = 0;
    for (int i = tid; i < ROWS_PER_RED; i += 256) {
        float4 v = pn[base + i];
        sp += (double)v.x; sn += (double)v.y; sd += (double)dist_arr[base + i];
        int f = (int)v.w;
        cp += f & 1; cn += (f >> 1) & 1;
    }
    __shared__ double A[256], B[256], C[256];
    __shared__ int I[256], J[256];
    A[tid] = sp; B[tid] = sn; C[tid] = sd; I[tid] = cp; J[tid] = cn;
    __syncthreads();
    for (int st = 128; st > 0; st >>= 1) {
        if (tid < st) { A[tid] += A[tid + st]; B[tid] += B[tid + st]; C[tid] += C[tid + st];
                        I[tid] += I[tid + st]; J[tid] += J[tid + st]; }
        __syncthreads();
    }
    if (tid == 0) {
        RedRec rec; rec.sp = A[0]; rec.sn = B[0]; rec.sd = C[0];
        rec.cp = I[0]; rec.cn = J[0];
        scratch[blockIdx.x] = rec;
    }
}

__global__ __launch_bounds__(64) void reduce2_kernel(
    const RedRec* __restrict__ scratch, float* __restrict__ out)
{
    int lane = threadIdx.x;              // 64 = RED1
    RedRec rec = scratch[lane];
    double sp = rec.sp, sn = rec.sn, sd = rec.sd;
    int cp = rec.cp, cn = rec.cn;
#pragma unroll
    for (int m = 1; m < 64; m <<= 1) {
        sp += __shfl_xor(sp, m);
        sn += __shfl_xor(sn, m);
        sd += __shfl_xor(sd, m);
        cp += __shfl_xor(cp, m);
        cn += __shfl_xor(cn, m);
    }
    if (lane == 0) {
        int cpv = cp < 1 ? 1 : cp;
        int cnv = cn < 1 ? 1 : cn;
        out[0] = (float)(sp / ((double)cpv * NCLS) +
                         sn / ((double)cnv * NCLS) +
                         sd / ((double)ROWS * DE));
    }
}

static inline int pad8(int x) { return (x + 7) & ~7; }

extern "C" void kernel_launch(void* const* d_in, const int* in_sizes, int n_in,
                              void* d_out, int out_size, void* d_ws, size_t ws_size,
                              hipStream_t stream)
{
    const float* det    = (const float*)d_in[0];
    const float* traj   = (const float*)d_in[1];
    const float* relpos = (const float*)d_in[2];
    const float* cw     = (const float*)d_in[3];
    const float* W1     = (const float*)d_in[4];
    const float* b1     = (const float*)d_in[5];
    const float* W2     = (const float*)d_in[6];
    const float* b2     = (const float*)d_in[7];
    const float* W3     = (const float*)d_in[8];
    const float* R1     = (const float*)d_in[9];
    const float* rb1    = (const float*)d_in[10];
    const float* R2     = (const float*)d_in[11];
    const float* temp   = (const float*)d_in[12];
    const int*   labels = (const int*)d_in[13];
    const int*   sids   = (const int*)d_in[14];
    const int*   oids   = (const int*)d_in[15];
    float* out = (float*)d_out;

    // ---- Workspace carve (footprint identical to R4-R7) -------------------
    char* ws = (char*)d_ws;
    size_t off = 0;
    auto carve = [&](size_t bytes) -> char* {
        char* p = ws + off;
        off = (off + bytes + 255) & ~(size_t)255;
        return p;
    };
    float4* pn       = (float4*)carve((size_t)ROWS * 16);
    float*  dist_arr = (float*)carve((size_t)ROWS * 4);
    short*  det_bf   = (short*)carve((size_t)BSZ * NDET * DF * 2);
    short*  W1t      = (short*)carve((size_t)2048 * 2048 * 2);
    short*  W2t      = (short*)carve((size_t)DH * DH * 2);
    short*  W3t      = (short*)carve((size_t)DE * DH * 2);
    short*  R2t      = (short*)carve((size_t)DE * 256 * 2);
    short*  cwt      = (short*)carve((size_t)NPAD * DE * 2);
    short*  UVa      = (short*)carve((size_t)BSZ * NDET * 2048 * 2);
    short*  UVb      = (short*)carve((size_t)BSZ * NDET * 2048 * 2);
    size_t fixed_off = off;

    int b_ch = 1;
    for (int cand : {16, 8, 4, 2, 1}) {
        size_t rows  = (size_t)cand * PAIRS;
        size_t bytes = fixed_off + rows * 2048 + 256 + rows * 2048 + 256
                     + rows * 512 + 256 + rows * 1024 + 256;
        if (bytes <= ws_size) { b_ch = cand; break; }
    }
    const int chunk_rows = b_ch * PAIRS;
    const int n_chunks = BSZ / b_ch;
    char* reg1 = carve((size_t)chunk_rows * 2048);
    char* reg2 = carve((size_t)chunk_rows * 2048);
    char* reg3 = carve((size_t)chunk_rows * 512);
    short* comb_bf = (short*)carve((size_t)chunk_rows * 1024);

    short* h1      = (short*)reg1;
    short* h2      = (short*)reg2;
    short* so_bf   = (short*)reg1;    // overwrites h1 (dead after h2 GEMM)
    short* re_bf   = (short*)reg2;    // overwrites h2 (dead after so GEMM)
    short* rh      = (short*)reg3;
    float* logits  = (float*)reg3;    // overwrites rh (dead after so/re GEMM)
    RedRec* red_scratch = (RedRec*)comb_bf;  // aliases comb (dead after logits GEMM)

    // ---- Prep (1 launch) --------------------------------------------------
    TransJobs tj;
    tj.src[0] = W1;                    tj.dst[0] = W1t;                   tj.K[0] = DF;  tj.N[0] = DH;
    tj.src[1] = W1 + (size_t)DF * DH;  tj.dst[1] = W1t + (size_t)DH * DF; tj.K[1] = DF;  tj.N[1] = DH;
    tj.src[2] = W2;                    tj.dst[2] = W2t;                   tj.K[2] = DH;  tj.N[2] = DH;
    tj.src[3] = W3;                    tj.dst[3] = W3t;                   tj.K[3] = DH;  tj.N[3] = DE;
    tj.src[4] = R2;                    tj.dst[4] = R2t;                   tj.K[4] = 256; tj.N[4] = DE;
    tj.cum[0] = 0;
    for (int i = 0; i < 5; ++i)
        tj.cum[i + 1] = tj.cum[i] + (tj.K[i] / 32) * (tj.N[i] / 32);
    prep_kernel<<<NCONVB + tj.cum[5], 256, 0, stream>>>(det, det_bf, cw, cwt, tj);

    // UV split-K halves, one DUAL launch split on bx (grid 32x6 = 192 blocks).
    mfma_gemm<false, false, true, false, true>
        <<<dim3(32, 6), 256, 0, stream>>>(
        det_bf, W1t, nullptr, UVa, BSZ * NDET, 2048, 1024, 2048, 2048,
        det_bf + 1024, W1t + 1024, UVb, 16, 1024, 2048, 2048);

    const int mg  = (chunk_rows + 127) / 128;
    const int mgp = pad8(mg);

    for (int c = 0; c < n_chunks; ++c) {
        int b0 = c * b_ch;
        int r0 = b0 * PAIRS;

        pairs_rh_kernel<<<chunk_rows, 256, 0, stream>>>(
            UVa, UVb, b1, sids, oids, h1, relpos, R1, rb1, rh, b0);

        // h2 = bf16(relu(h1 @ W2 + b2))
        mfma_gemm<true, true, true, true, false>
            <<<dim3(DH / 128, mgp), 256, 0, stream>>>(
            h1, W2t, b2, h2, chunk_rows, DH, DH, DH, DH,
            nullptr, nullptr, nullptr, 0, 0, 0, 0);

        // so_bf = bf16(h2 @ W3)  +  re_bf = bf16(rh @ R2): one DUAL launch.
        mfma_gemm<false, false, true, true, true>
            <<<dim3(8, mgp), 256, 0, stream>>>(
            h2, W3t, nullptr, so_bf, chunk_rows, DE, DH, DH, DH,
            rh, R2t, re_bf, 4, 256, 256, 256);

        row_prep_kernel<<<chunk_rows / 4, 256, 0, stream>>>(
            so_bf, re_bf, traj, temp, sids, oids, comb_bf, dist_arr, b0);

        // logits = comb_bf @ cwt^T  (fp32, plain store epilogue)
        mfma_gemm<false, false, false, true, false>
            <<<dim3(1, mgp), 256, 0, stream>>>(
            comb_bf, cwt, nullptr, logits, chunk_rows, NPAD, DE, DE, DE,
            nullptr, nullptr, nullptr, 0, 0, 0, 0);

        // standalone focal: 9024 blocks, wave-per-row, coalesced
        focal_kernel<<<chunk_rows / 4, 256, 0, stream>>>(logits, labels, pn, b0);
    }

    reduce1_kernel<<<RED1, 256, 0, stream>>>(pn, dist_arr, red_scratch);
    reduce2_kernel<<<1, 64, 0, stream>>>(red_scratch, out);
}

// Round 9
// 393.749 us; speedup vs baseline: 12.6965x; 1.0751x over previous
//
#include <hip/hip_runtime.h>
#include <math.h>

// Problem constants
constexpr int BSZ   = 16;
constexpr int NDET  = 48;
constexpr int PAIRS = NDET * (NDET - 1);      // 2256
constexpr int ROWS  = BSZ * PAIRS;            // 36096
constexpr int DF    = 2048;
constexpr int DH    = 1024;
constexpr int DE    = 512;
constexpr int EHALF = 256;
constexpr int NCLS  = 92;
constexpr int NPAD  = 128;                    // logits N padded for GEMM
constexpr int LABW  = 1 + 92 + 40;            // 133

typedef __attribute__((ext_vector_type(8))) short bf16x8;   // 8 bf16 in 4 VGPRs
typedef __attribute__((ext_vector_type(4))) float f32x4;

__device__ __forceinline__ short f2bf(float f) {
    union { float f; unsigned u; } a; a.f = f;
    unsigned r = a.u + 0x7fffu + ((a.u >> 16) & 1u);   // RNE
    return (short)(r >> 16);
}
__device__ __forceinline__ float bf2f(short h) {
    union { unsigned u; float f; } x;
    x.u = ((unsigned)(unsigned short)h) << 16;
    return x.f;
}

// ---------------------------------------------------------------------------
// Merged prep: blocks [0,1600): det fp32->bf16 + cwt build;
// blocks [1600, 1600+5760): 5-job transpose+convert (W1 top/bot, W2, W3, R2).
// ---------------------------------------------------------------------------
constexpr int N4DET = BSZ * NDET * DF / 4;    // 393216
constexpr int N4CWT = NPAD * DE / 4;          // 16384
constexpr int NCONVB = (N4DET + N4CWT) / 256; // 1600 exactly

struct TransJobs {
    const float* src[5];
    short*       dst[5];
    int K[5], N[5];
    int cum[6];
};

__global__ __launch_bounds__(256) void prep_kernel(
    const float* __restrict__ det, short* __restrict__ det_bf,
    const float* __restrict__ cw, short* __restrict__ cwt, TransJobs jobs)
{
    if (blockIdx.x < NCONVB) {
        int i = blockIdx.x * 256 + threadIdx.x;
        if (i < N4DET) {
            float4 v = ((const float4*)det)[i];
            short4 o;
            o.x = f2bf(v.x); o.y = f2bf(v.y); o.z = f2bf(v.z); o.w = f2bf(v.w);
            ((short4*)det_bf)[i] = o;
        } else {
            int k = i - N4DET;
            int n = (k * 4) >> 9;
            short4 o = {0, 0, 0, 0};
            if (n < NCLS) {
                float4 v = ((const float4*)cw)[k];
                o.x = f2bf(v.x); o.y = f2bf(v.y); o.z = f2bf(v.z); o.w = f2bf(v.w);
            }
            ((short4*)cwt)[k] = o;
        }
        return;
    }
    __shared__ float tile[32][33];
    int t = blockIdx.x - NCONVB;
    int j = 0;
    while (t >= jobs.cum[j + 1]) ++j;
    int lt = t - jobs.cum[j];
    int K = jobs.K[j], N = jobs.N[j];
    int nx = N >> 5;
    int ky = lt / nx, nxi = lt - ky * nx;
    int n0 = nxi * 32, k0 = ky * 32;
    const float* src = jobs.src[j];
    short* dst = jobs.dst[j];
    int tx = threadIdx.x & 31, ty = threadIdx.x >> 5;
#pragma unroll
    for (int i = ty; i < 32; i += 8)
        tile[i][tx] = src[(size_t)(k0 + i) * N + n0 + tx];
    __syncthreads();
#pragma unroll
    for (int i = ty; i < 32; i += 8)
        dst[(size_t)(n0 + i) * K + k0 + tx] = f2bf(tile[tx][i]);
}

// ---------------------------------------------------------------------------
// MFMA bf16 GEMM. A bf16 [M,lda]; Bt bf16 [N,ldb]. N%128==0, K%64==0.
// 128x128 tile, BK=64 staged as TWO 128x32 row-major half-tiles (keeps the
// conflict-free 64B row stride AND load16_lds's contiguous-dest constraint)
// -> one barrier pair per 64 k instead of two (R8: barrier drain was the
// stall; MfmaUtil 30%, VALU 18%, HBM 16%). LDS 32KB staging; 4 blocks/CU
// still fits (128KB < 160KB). 4 waves, __launch_bounds__(256,4).
// SWIZZLE: XCD-aware remap (R5: FETCH 292->61MB). DUAL: bx>=nsplit -> job2.
// OUTBF16: LDS-repack store (stride 68), scratch reuses staging LDS.
// ---------------------------------------------------------------------------
__device__ __forceinline__ void load16_lds(const void* g, void* l) {
    __builtin_amdgcn_global_load_lds(
        (const __attribute__((address_space(1))) unsigned int*)g,
        (__attribute__((address_space(3))) unsigned int*)l, 16, 0, 0);
}

template <bool BIAS, bool RELU, bool OUTBF16, bool SWIZZLE, bool DUAL>
__global__ __launch_bounds__(256, 4) void mfma_gemm(
    const short* __restrict__ A, const short* __restrict__ Bt,
    const float* __restrict__ bias, void* __restrict__ C,
    int M, int N, int K, int lda, int ldb,
    const short* A2, const short* Bt2, void* C2, int nsplit,
    int K2, int lda2, int ldb2)
{
    __shared__ __align__(16) char smem_raw[32768];   // As 16KB | Bs 16KB
    short* As = (short*)smem_raw;                    // two 128x32 halves
    short* Bs = As + 128 * 64;

    int bx, by;
    if (SWIZZLE) {
        int nb  = gridDim.x;
        int gid = blockIdx.y * nb + blockIdx.x;
        int xcd = gid & 7;
        int j   = gid >> 3;
        int rows_per = gridDim.y >> 3;
        int lr  = j / nb;
        bx = j - lr * nb;
        by = xcd * rows_per + lr;
    } else {
        bx = blockIdx.x; by = blockIdx.y;
    }
    if (DUAL && bx >= nsplit) {
        bx -= nsplit; A = A2; Bt = Bt2; C = C2; K = K2; lda = lda2; ldb = ldb2;
    }
    if (by * 128 >= M) return;                      // padded tail

    const int tid  = threadIdx.x;
    const int wave = tid >> 6;
    const int lane = tid & 63;
    const int m0 = by * 128;
    const int n0 = bx * 128;
    const int wm = (wave & 1) * 64;
    const int wn = (wave >> 1) * 64;

    f32x4 acc[4][4] = {};

    const int q  = lane >> 4;
    const int lm = lane & 15;

    for (int k0 = 0; k0 < K; k0 += 64) {
        // Stage two 128x32 half-tiles for A and Bt (8 load16_lds per thread).
#pragma unroll
        for (int it = 0; it < 4; ++it) {
            int c    = (it & 1) * 256 + tid;        // chunk within half
            int half = it >> 1;
            int row  = c >> 2;
            int kk   = (c & 3) * 8 + half * 32;
            int ldsc = half * 4096 + ((it & 1) * 256 + wave * 64) * 8;  // elems
            int gm = m0 + row; if (gm >= M) gm = M - 1;
            load16_lds(A + (size_t)gm * lda + k0 + kk, As + ldsc);
            int gn = n0 + row;                       // N%128==0: no tail
            load16_lds(Bt + (size_t)gn * ldb + k0 + kk, Bs + ldsc);
        }
        __syncthreads();

#pragma unroll
        for (int half = 0; half < 2; ++half) {
            const short* Ah = As + half * 4096;
            const short* Bh = Bs + half * 4096;
            bf16x8 af[4], bfr[4];
#pragma unroll
            for (int t = 0; t < 4; ++t) {
                af[t]  = *(const bf16x8*)(Ah + (wm + t * 16 + lm) * 32 + q * 8);
                bfr[t] = *(const bf16x8*)(Bh + (wn + t * 16 + lm) * 32 + q * 8);
            }
#pragma unroll
            for (int tm = 0; tm < 4; ++tm)
#pragma unroll
                for (int tn = 0; tn < 4; ++tn)
                    acc[tm][tn] = __builtin_amdgcn_mfma_f32_16x16x32_bf16(
                        af[tm], bfr[tn], acc[tm][tn], 0, 0, 0);
        }
        __syncthreads();
    }

    // C/D layout: col=lane&15, row=(lane>>4)*4+reg (m89-verified)
    if (OUTBF16) {
        // LDS-repack epilogue: 16x68 fp32 scratch per wave (2-way = free).
        float* scratch = (float*)smem_raw + wave * (16 * 68);
#pragma unroll
        for (int tm = 0; tm < 4; ++tm) {
            __syncthreads();
#pragma unroll
            for (int tn = 0; tn < 4; ++tn) {
                float bv = BIAS ? bias[n0 + wn + tn * 16 + lm] : 0.0f;
#pragma unroll
                for (int r = 0; r < 4; ++r) {
                    float v = acc[tm][tn][r] + bv;
                    if (RELU) v = fmaxf(v, 0.0f);
                    scratch[(q * 4 + r) * 68 + tn * 16 + lm] = v;
                }
            }
            __syncthreads();
#pragma unroll
            for (int p = 0; p < 2; ++p) {
                int row16 = (lane >> 3) + p * 8;
                int c0 = (lane & 7) * 8;
                float4 v0 = *(float4*)&scratch[row16 * 68 + c0];
                float4 v1 = *(float4*)&scratch[row16 * 68 + c0 + 4];
                bf16x8 o;
                o[0] = f2bf(v0.x); o[1] = f2bf(v0.y); o[2] = f2bf(v0.z); o[3] = f2bf(v0.w);
                o[4] = f2bf(v1.x); o[5] = f2bf(v1.y); o[6] = f2bf(v1.z); o[7] = f2bf(v1.w);
                int grow = m0 + wm + tm * 16 + row16;
                if (grow < M)
                    *(bf16x8*)((short*)C + (size_t)grow * N + n0 + wn + c0) = o;
            }
        }
    } else {
        // fp32 direct store (logits path: N=128, 64B runs per quad)
#pragma unroll
        for (int tm = 0; tm < 4; ++tm)
#pragma unroll
            for (int tn = 0; tn < 4; ++tn) {
                int col = n0 + wn + tn * 16 + lm;
#pragma unroll
                for (int r = 0; r < 4; ++r) {
                    int row = m0 + wm + tm * 16 + q * 4 + r;
                    if (row < M) {
                        float v = acc[tm][tn][r];
                        if (BIAS) v += bias[col];
                        if (RELU) v = fmaxf(v, 0.0f);
                        ((float*)C)[(size_t)row * N + col] = v;
                    }
                }
            }
    }
}

// ---------------------------------------------------------------------------
// UV merge (in-place, race-free): UVa[i] = UVa[i] + UVb[i] + b1[col] for
// U-half columns (col<1024). Halves pairs_rh's gather streams (4->2) and
// the gather working set (12.6->6.3MB, closer to a 4MB XCD L2).
// ---------------------------------------------------------------------------
constexpr int N4UV = BSZ * NDET * 2048 / 4;   // 393216 short4s
__global__ __launch_bounds__(256) void uvmerge_kernel(
    short* __restrict__ UVa, const short* __restrict__ UVb,
    const float* __restrict__ b1)
{
    int i = blockIdx.x * 256 + threadIdx.x;
    if (i >= N4UV) return;
    short4 a = ((const short4*)UVa)[i];
    short4 b = ((const short4*)UVb)[i];
    int col4 = i & 511;                       // short4 column within 2048-row
    float4 bb = {0.0f, 0.0f, 0.0f, 0.0f};
    if (col4 < 256) bb = ((const float4*)b1)[col4];   // U-half gets b1
    short4 o;
    o.x = f2bf(bf2f(a.x) + bf2f(b.x) + bb.x);
    o.y = f2bf(bf2f(a.y) + bf2f(b.y) + bb.y);
    o.z = f2bf(bf2f(a.z) + bf2f(b.z) + bb.z);
    o.w = f2bf(bf2f(a.w) + bf2f(b.w) + bb.w);
    ((short4*)UVa)[i] = o;
}

// ---------------------------------------------------------------------------
// Fused pairs + rh (one block per row). UVs is the merged buffer (b1 baked).
// ---------------------------------------------------------------------------
__global__ __launch_bounds__(256) void pairs_rh_kernel(
    const short* __restrict__ UVs,
    const int* __restrict__ sids, const int* __restrict__ oids,
    short* __restrict__ h1,
    const float* __restrict__ rp, const float* __restrict__ R1,
    const float* __restrict__ rb1, short* __restrict__ rh, int b0)
{
    int r = blockIdx.x;
    int b = b0 + r / PAIRS;
    int p = r % PAIRS;
    int j = threadIdx.x;

    size_t soff = (size_t)(b * NDET + sids[p]) * 2048;
    size_t ooff = (size_t)(b * NDET + oids[p]) * 2048 + 1024;
    short4 a1 = ((const short4*)(UVs + soff))[j];
    short4 a3 = ((const short4*)(UVs + ooff))[j];
    short4 h;
    h.x = f2bf(fmaxf(bf2f(a1.x) + bf2f(a3.x), 0.0f));
    h.y = f2bf(fmaxf(bf2f(a1.y) + bf2f(a3.y), 0.0f));
    h.z = f2bf(fmaxf(bf2f(a1.z) + bf2f(a3.z), 0.0f));
    h.w = f2bf(fmaxf(bf2f(a1.w) + bf2f(a3.w), 0.0f));
    ((short4*)(h1 + (size_t)r * DH))[j] = h;

    int rg = b0 * PAIRS + r;
    const float* row = rp + (size_t)rg * 12;
    float acc = rb1[j];
#pragma unroll
    for (int k = 0; k < 12; ++k) acc = fmaf(row[k], R1[k * 256 + j], acc);
    rh[(size_t)r * 256 + j] = f2bf(fmaxf(acc, 0.0f));
}

// ---------------------------------------------------------------------------
// row_prep: one wave per row, butterfly reductions.
// ---------------------------------------------------------------------------
__global__ __launch_bounds__(256) void row_prep_kernel(
    const short* __restrict__ sp_bf, const short* __restrict__ ru_bf,
    const float* __restrict__ traj, const float* __restrict__ temperature,
    const int* __restrict__ sids, const int* __restrict__ oids,
    short* __restrict__ comb_bf, float* __restrict__ dist_arr, int b0)
{
    int wave = threadIdx.x >> 6, lane = threadIdx.x & 63;
    int r = blockIdx.x * 4 + wave;
    int rg = b0 * PAIRS + r;
    int b = b0 + r / PAIRS;
    int p = r % PAIRS;

    bf16x8 sv = ((const bf16x8*)(sp_bf + (size_t)r * DE))[lane];
    bf16x8 uv = ((const bf16x8*)(ru_bf + (size_t)r * DE))[lane];
    float s[8], u[8];
#pragma unroll
    for (int i = 0; i < 8; ++i) { s[i] = bf2f(sv[i]); u[i] = bf2f(uv[i]); }

    const float* tsrc = (lane < 32)
        ? (traj + (size_t)(b * NDET + sids[p]) * EHALF + lane * 8)
        : (traj + (size_t)(b * NDET + oids[p]) * EHALF + (lane - 32) * 8);
    float4 t0 = ((const float4*)tsrc)[0], t1 = ((const float4*)tsrc)[1];
    float t[8] = {t0.x, t0.y, t0.z, t0.w, t1.x, t1.y, t1.z, t1.w};

    float ss = 0.0f, sr = 0.0f, sd = 0.0f;
#pragma unroll
    for (int i = 0; i < 8; ++i) {
        ss += s[i] * s[i];
        sr += u[i] * u[i];
        sd += fabsf(t[i] - s[i]);
    }
#pragma unroll
    for (int m = 1; m < 64; m <<= 1) {
        ss += __shfl_xor(ss, m);
        sr += __shfl_xor(sr, m);
        sd += __shfl_xor(sd, m);
    }
    float inv_s = 1.0f / fmaxf(sqrtf(ss), 1e-12f);
    float inv_r = 1.0f / fmaxf(sqrtf(sr), 1e-12f);

    float c[8], sc = 0.0f;
#pragma unroll
    for (int i = 0; i < 8; ++i) {
        c[i] = s[i] * inv_s + u[i] * inv_r;
        sc += c[i] * c[i];
    }
#pragma unroll
    for (int m = 1; m < 64; m <<= 1) sc += __shfl_xor(sc, m);

    float scale = (1.0f / fmaxf(sqrtf(sc), 1e-12f)) / temperature[0];

    bf16x8 o;
#pragma unroll
    for (int i = 0; i < 8; ++i) o[i] = f2bf(c[i] * scale);
    ((bf16x8*)(comb_bf + (size_t)r * DE))[lane] = o;

    if (lane == 0) dist_arr[rg] = sd;
}

// ---------------------------------------------------------------------------
// focal (standalone): one wave per row over 92 coalesced logits.
// ---------------------------------------------------------------------------
__global__ __launch_bounds__(256) void focal_kernel(
    const float* __restrict__ logits, const int* __restrict__ labels,
    float4* __restrict__ pn, int b0)
{
    int wave = threadIdx.x >> 6, lane = threadIdx.x & 63;
    int r = blockIdx.x * 4 + wave;
    int rg = b0 * PAIRS + r;
    const float* lrow = logits + (size_t)r * NPAD;
    size_t labbase = (size_t)rg * LABW;

    float flp = 0.0f, fln = 0.0f, fm = 0.0f;
    for (int c = lane; c < NCLS; c += 64) {
        float l = lrow[c];
        int t = labels[labbase + 1 + c];
        if (t > 0) fm = 1.0f;
        float tf = (float)t;
        float pr = 1.0f / (1.0f + expf(-l));
        float lg = log1pf(expf(-fabsf(l)));
        float ce = fmaxf(l, 0.0f) - l * tf + lg;
        float pt = pr * tf + (1.0f - pr) * (1.0f - tf);
        float om = 1.0f - pt;
        float at = 0.25f * tf + 0.75f * (1.0f - tf);
        flp += at * ce * om * om;
        float ce0 = fmaxf(l, 0.0f) + lg;
        fln += 0.75f * ce0 * pr * pr;
    }
#pragma unroll
    for (int m = 1; m < 64; m <<= 1) {
        flp += __shfl_xor(flp, m);
        fln += __shfl_xor(fln, m);
        fm  += __shfl_xor(fm, m);
    }
    if (lane == 0) {
        int posf = (fm > 0.5f) ? 1 : 0;
        int negf = (labels[labbase] > 0) ? 1 : 0;
        pn[rg] = make_float4(posf ? flp : 0.0f, negf ? fln : 0.0f, 0.0f,
                             (float)(posf + 2 * negf));
    }
}

// ---------------------------------------------------------------------------
// Two-stage final reduce.
// ---------------------------------------------------------------------------
struct RedRec { double sp, sn, sd; int cp, cn; };
constexpr int RED1 = 64;
constexpr int ROWS_PER_RED = ROWS / RED1;           // 564

__global__ __launch_bounds__(256) void reduce1_kernel(
    const float4* __restrict__ pn, const float* __restrict__ dist_arr,
    RedRec* __restrict__ scratch)
{
    int tid = threadIdx.x;
    int base = blockIdx.x * ROWS_PER_RED;
    double sp = 0.0, sn = 0.0, sd = 0.0;
    int cp = 0, cn = 0;
    for (int i = tid; i < ROWS_PER_RED; i += 256) {
        float4 v = pn[base + i];
        sp += (double)v.x; sn += (double)v.y; sd += (double)dist_arr[base + i];
        int f = (int)v.w;
        cp += f & 1; cn += (f >> 1) & 1;
    }
    __shared__ double A[256], B[256], C[256];
    __shared__ int I[256], J[256];
    A[tid] = sp; B[tid] = sn; C[tid] = sd; I[tid] = cp; J[tid] = cn;
    __syncthreads();
    for (int st = 128; st > 0; st >>= 1) {
        if (tid < st) { A[tid] += A[tid + st]; B[tid] += B[tid + st]; C[tid] += C[tid + st];
                        I[tid] += I[tid + st]; J[tid] += J[tid + st]; }
        __syncthreads();
    }
    if (tid == 0) {
        RedRec rec; rec.sp = A[0]; rec.sn = B[0]; rec.sd = C[0];
        rec.cp = I[0]; rec.cn = J[0];
        scratch[blockIdx.x] = rec;
    }
}

__global__ __launch_bounds__(64) void reduce2_kernel(
    const RedRec* __restrict__ scratch, float* __restrict__ out)
{
    int lane = threadIdx.x;
    RedRec rec = scratch[lane];
    double sp = rec.sp, sn = rec.sn, sd = rec.sd;
    int cp = rec.cp, cn = rec.cn;
#pragma unroll
    for (int m = 1; m < 64; m <<= 1) {
        sp += __shfl_xor(sp, m);
        sn += __shfl_xor(sn, m);
        sd += __shfl_xor(sd, m);
        cp += __shfl_xor(cp, m);
        cn += __shfl_xor(cn, m);
    }
    if (lane == 0) {
        int cpv = cp < 1 ? 1 : cp;
        int cnv = cn < 1 ? 1 : cn;
        out[0] = (float)(sp / ((double)cpv * NCLS) +
                         sn / ((double)cnv * NCLS) +
                         sd / ((double)ROWS * DE));
    }
}

static inline int pad8(int x) { return (x + 7) & ~7; }

extern "C" void kernel_launch(void* const* d_in, const int* in_sizes, int n_in,
                              void* d_out, int out_size, void* d_ws, size_t ws_size,
                              hipStream_t stream)
{
    const float* det    = (const float*)d_in[0];
    const float* traj   = (const float*)d_in[1];
    const float* relpos = (const float*)d_in[2];
    const float* cw     = (const float*)d_in[3];
    const float* W1     = (const float*)d_in[4];
    const float* b1     = (const float*)d_in[5];
    const float* W2     = (const float*)d_in[6];
    const float* b2     = (const float*)d_in[7];
    const float* W3     = (const float*)d_in[8];
    const float* R1     = (const float*)d_in[9];
    const float* rb1    = (const float*)d_in[10];
    const float* R2     = (const float*)d_in[11];
    const float* temp   = (const float*)d_in[12];
    const int*   labels = (const int*)d_in[13];
    const int*   sids   = (const int*)d_in[14];
    const int*   oids   = (const int*)d_in[15];
    float* out = (float*)d_out;

    // ---- Workspace carve (footprint identical to R4-R8) -------------------
    char* ws = (char*)d_ws;
    size_t off = 0;
    auto carve = [&](size_t bytes) -> char* {
        char* p = ws + off;
        off = (off + bytes + 255) & ~(size_t)255;
        return p;
    };
    float4* pn       = (float4*)carve((size_t)ROWS * 16);
    float*  dist_arr = (float*)carve((size_t)ROWS * 4);
    short*  det_bf   = (short*)carve((size_t)BSZ * NDET * DF * 2);
    short*  W1t      = (short*)carve((size_t)2048 * 2048 * 2);
    short*  W2t      = (short*)carve((size_t)DH * DH * 2);
    short*  W3t      = (short*)carve((size_t)DE * DH * 2);
    short*  R2t      = (short*)carve((size_t)DE * 256 * 2);
    short*  cwt      = (short*)carve((size_t)NPAD * DE * 2);
    short*  UVa      = (short*)carve((size_t)BSZ * NDET * 2048 * 2);
    short*  UVb      = (short*)carve((size_t)BSZ * NDET * 2048 * 2);
    size_t fixed_off = off;

    int b_ch = 1;
    for (int cand : {16, 8, 4, 2, 1}) {
        size_t rows  = (size_t)cand * PAIRS;
        size_t bytes = fixed_off + rows * 2048 + 256 + rows * 2048 + 256
                     + rows * 512 + 256 + rows * 1024 + 256;
        if (bytes <= ws_size) { b_ch = cand; break; }
    }
    const int chunk_rows = b_ch * PAIRS;
    const int n_chunks = BSZ / b_ch;
    char* reg1 = carve((size_t)chunk_rows * 2048);
    char* reg2 = carve((size_t)chunk_rows * 2048);
    char* reg3 = carve((size_t)chunk_rows * 512);
    short* comb_bf = (short*)carve((size_t)chunk_rows * 1024);

    short* h1      = (short*)reg1;
    short* h2      = (short*)reg2;
    short* so_bf   = (short*)reg1;    // overwrites h1 (dead after h2 GEMM)
    short* re_bf   = (short*)reg2;    // overwrites h2 (dead after so GEMM)
    short* rh      = (short*)reg3;
    float* logits  = (float*)reg3;    // overwrites rh (dead after so/re GEMM)
    RedRec* red_scratch = (RedRec*)comb_bf;  // aliases comb (dead after logits GEMM)

    // ---- Prep (1 launch) --------------------------------------------------
    TransJobs tj;
    tj.src[0] = W1;                    tj.dst[0] = W1t;                   tj.K[0] = DF;  tj.N[0] = DH;
    tj.src[1] = W1 + (size_t)DF * DH;  tj.dst[1] = W1t + (size_t)DH * DF; tj.K[1] = DF;  tj.N[1] = DH;
    tj.src[2] = W2;                    tj.dst[2] = W2t;                   tj.K[2] = DH;  tj.N[2] = DH;
    tj.src[3] = W3;                    tj.dst[3] = W3t;                   tj.K[3] = DH;  tj.N[3] = DE;
    tj.src[4] = R2;                    tj.dst[4] = R2t;                   tj.K[4] = 256; tj.N[4] = DE;
    tj.cum[0] = 0;
    for (int i = 0; i < 5; ++i)
        tj.cum[i + 1] = tj.cum[i] + (tj.K[i] / 32) * (tj.N[i] / 32);
    prep_kernel<<<NCONVB + tj.cum[5], 256, 0, stream>>>(det, det_bf, cw, cwt, tj);

    // UV split-K halves, one DUAL launch split on bx (grid 32x6 = 192 blocks).
    mfma_gemm<false, false, true, false, true>
        <<<dim3(32, 6), 256, 0, stream>>>(
        det_bf, W1t, nullptr, UVa, BSZ * NDET, 2048, 1024, 2048, 2048,
        det_bf + 1024, W1t + 1024, UVb, 16, 1024, 2048, 2048);

    // Merge: UVa += UVb + b1 (in-place, race-free)
    uvmerge_kernel<<<(N4UV + 255) / 256, 256, 0, stream>>>(UVa, UVb, b1);

    const int mg  = (chunk_rows + 127) / 128;
    const int mgp = pad8(mg);

    for (int c = 0; c < n_chunks; ++c) {
        int b0 = c * b_ch;
        int r0 = b0 * PAIRS;

        pairs_rh_kernel<<<chunk_rows, 256, 0, stream>>>(
            UVa, sids, oids, h1, relpos, R1, rb1, rh, b0);

        // h2 = bf16(relu(h1 @ W2 + b2))
        mfma_gemm<true, true, true, true, false>
            <<<dim3(DH / 128, mgp), 256, 0, stream>>>(
            h1, W2t, b2, h2, chunk_rows, DH, DH, DH, DH,
            nullptr, nullptr, nullptr, 0, 0, 0, 0);

        // so_bf = bf16(h2 @ W3)  +  re_bf = bf16(rh @ R2): one DUAL launch.
        mfma_gemm<false, false, true, true, true>
            <<<dim3(8, mgp), 256, 0, stream>>>(
            h2, W3t, nullptr, so_bf, chunk_rows, DE, DH, DH, DH,
            rh, R2t, re_bf, 4, 256, 256, 256);

        row_prep_kernel<<<chunk_rows / 4, 256, 0, stream>>>(
            so_bf, re_bf, traj, temp, sids, oids, comb_bf, dist_arr, b0);

        // logits = comb_bf @ cwt^T  (fp32, plain store epilogue)
        mfma_gemm<false, false, false, true, false>
            <<<dim3(1, mgp), 256, 0, stream>>>(
            comb_bf, cwt, nullptr, logits, chunk_rows, NPAD, DE, DE, DE,
            nullptr, nullptr, nullptr, 0, 0, 0, 0);

        // standalone focal: wave-per-row, coalesced
        focal_kernel<<<chunk_rows / 4, 256, 0, stream>>>(logits, labels, pn, b0);
    }

    reduce1_kernel<<<RED1, 256, 0, stream>>>(pn, dist_arr, red_scratch);
    reduce2_kernel<<<1, 64, 0, stream>>>(red_scratch, out);
}

// Round 10
// 388.418 us; speedup vs baseline: 12.8707x; 1.0137x over previous
//
#include <hip/hip_runtime.h>
#include <math.h>

// Problem constants
constexpr int BSZ   = 16;
constexpr int NDET  = 48;
constexpr int PAIRS = NDET * (NDET - 1);      // 2256
constexpr int ROWS  = BSZ * PAIRS;            // 36096
constexpr int DF    = 2048;
constexpr int DH    = 1024;
constexpr int DE    = 512;
constexpr int EHALF = 256;
constexpr int NCLS  = 92;
constexpr int NEXT  = DE + 128;               // 640: so/re GEMM width incl. classifier cols
constexpr int LABW  = 1 + 92 + 40;            // 133

typedef __attribute__((ext_vector_type(8))) short bf16x8;   // 8 bf16 in 4 VGPRs
typedef __attribute__((ext_vector_type(4))) float f32x4;

__device__ __forceinline__ short f2bf(float f) {
    union { float f; unsigned u; } a; a.f = f;
    unsigned r = a.u + 0x7fffu + ((a.u >> 16) & 1u);   // RNE
    return (short)(r >> 16);
}
__device__ __forceinline__ float bf2f(short h) {
    union { unsigned u; float f; } x;
    x.u = ((unsigned)(unsigned short)h) << 16;
    return x.f;
}

// ---------------------------------------------------------------------------
// Merged prep. Elementwise ranges: det conv | cwt build | W3->bf16 | R2->bf16;
// then 5-job transpose (W1 top/bot, W2, W3, R2).
// ---------------------------------------------------------------------------
constexpr int N4DET = BSZ * NDET * DF / 4;    // 393216
constexpr int N4CWT = 128 * DE / 4;           // 16384
constexpr int N4W3  = DH * DE / 4;            // 131072
constexpr int N4R2  = 256 * DE / 4;           // 32768
constexpr int NCONVB = (N4DET + N4CWT + N4W3 + N4R2) / 256;   // 2240

struct TransJobs {
    const float* src[5];
    short*       dst[5];
    int K[5], N[5];
    int cum[6];
};

__global__ __launch_bounds__(256) void prep_kernel(
    const float* __restrict__ det, short* __restrict__ det_bf,
    const float* __restrict__ cw, short* __restrict__ cwt,
    const float* __restrict__ W3, short* __restrict__ W3bf,
    const float* __restrict__ R2, short* __restrict__ R2bf,
    TransJobs jobs)
{
    if (blockIdx.x < NCONVB) {
        int i = blockIdx.x * 256 + threadIdx.x;
        const float* src; short* dst; int k;
        if (i < N4DET) { src = det; dst = det_bf; k = i; }
        else if (i < N4DET + N4CWT) {
            k = i - N4DET;
            int n = (k * 4) >> 9;
            short4 o = {0, 0, 0, 0};
            if (n < NCLS) {
                float4 v = ((const float4*)cw)[k];
                o.x = f2bf(v.x); o.y = f2bf(v.y); o.z = f2bf(v.z); o.w = f2bf(v.w);
            }
            ((short4*)cwt)[k] = o;
            return;
        }
        else if (i < N4DET + N4CWT + N4W3) { src = W3; dst = W3bf; k = i - N4DET - N4CWT; }
        else { src = R2; dst = R2bf; k = i - N4DET - N4CWT - N4W3; }
        float4 v = ((const float4*)src)[k];
        short4 o;
        o.x = f2bf(v.x); o.y = f2bf(v.y); o.z = f2bf(v.z); o.w = f2bf(v.w);
        ((short4*)dst)[k] = o;
        return;
    }
    __shared__ float tile[32][33];
    int t = blockIdx.x - NCONVB;
    int j = 0;
    while (t >= jobs.cum[j + 1]) ++j;
    int lt = t - jobs.cum[j];
    int K = jobs.K[j], N = jobs.N[j];
    int nx = N >> 5;
    int ky = lt / nx, nxi = lt - ky * nx;
    int n0 = nxi * 32, k0 = ky * 32;
    const float* src = jobs.src[j];
    short* dst = jobs.dst[j];
    int tx = threadIdx.x & 31, ty = threadIdx.x >> 5;
#pragma unroll
    for (int i = ty; i < 32; i += 8)
        tile[i][tx] = src[(size_t)(k0 + i) * N + n0 + tx];
    __syncthreads();
#pragma unroll
    for (int i = ty; i < 32; i += 8)
        dst[(size_t)(n0 + i) * K + k0 + tx] = f2bf(tile[tx][i]);
}

// ---------------------------------------------------------------------------
// MFMA bf16 GEMM. A bf16 [M,lda]; Bt bf16 [N,ldb]. N%128==0, K%64==0.
// 128x128 tile, BK=64 as two 128x32 halves (R9: one barrier pair per 64 k).
// SWIZZLE: XCD-aware remap. DUAL: bx>=nsplit -> job2 (incl. its own N2 —
// fixes the latent stride bug when jobs differ in N). OUTBF16: LDS-repack.
// ---------------------------------------------------------------------------
__device__ __forceinline__ void load16_lds(const void* g, void* l) {
    __builtin_amdgcn_global_load_lds(
        (const __attribute__((address_space(1))) unsigned int*)g,
        (__attribute__((address_space(3))) unsigned int*)l, 16, 0, 0);
}

template <bool BIAS, bool RELU, bool OUTBF16, bool SWIZZLE, bool DUAL>
__global__ __launch_bounds__(256, 4) void mfma_gemm(
    const short* __restrict__ A, const short* __restrict__ Bt,
    const float* __restrict__ bias, void* __restrict__ C,
    int M, int N, int K, int lda, int ldb,
    const short* A2, const short* Bt2, void* C2, int nsplit,
    int K2, int lda2, int ldb2, int N2)
{
    __shared__ __align__(16) char smem_raw[32768];   // As 16KB | Bs 16KB
    short* As = (short*)smem_raw;                    // two 128x32 halves
    short* Bs = As + 128 * 64;

    int bx, by;
    if (SWIZZLE) {
        int nb  = gridDim.x;
        int gid = blockIdx.y * nb + blockIdx.x;
        int xcd = gid & 7;
        int j   = gid >> 3;
        int rows_per = gridDim.y >> 3;
        int lr  = j / nb;
        bx = j - lr * nb;
        by = xcd * rows_per + lr;
    } else {
        bx = blockIdx.x; by = blockIdx.y;
    }
    if (DUAL && bx >= nsplit) {
        bx -= nsplit; A = A2; Bt = Bt2; C = C2;
        K = K2; lda = lda2; ldb = ldb2; N = N2;
    }
    if (by * 128 >= M) return;                      // padded tail

    const int tid  = threadIdx.x;
    const int wave = tid >> 6;
    const int lane = tid & 63;
    const int m0 = by * 128;
    const int n0 = bx * 128;
    const int wm = (wave & 1) * 64;
    const int wn = (wave >> 1) * 64;

    f32x4 acc[4][4] = {};

    const int q  = lane >> 4;
    const int lm = lane & 15;

    for (int k0 = 0; k0 < K; k0 += 64) {
#pragma unroll
        for (int it = 0; it < 4; ++it) {
            int c    = (it & 1) * 256 + tid;
            int half = it >> 1;
            int row  = c >> 2;
            int kk   = (c & 3) * 8 + half * 32;
            int ldsc = half * 4096 + ((it & 1) * 256 + wave * 64) * 8;
            int gm = m0 + row; if (gm >= M) gm = M - 1;
            load16_lds(A + (size_t)gm * lda + k0 + kk, As + ldsc);
            int gn = n0 + row;                       // N%128==0: no tail
            load16_lds(Bt + (size_t)gn * ldb + k0 + kk, Bs + ldsc);
        }
        __syncthreads();

#pragma unroll
        for (int half = 0; half < 2; ++half) {
            const short* Ah = As + half * 4096;
            const short* Bh = Bs + half * 4096;
            bf16x8 af[4], bfr[4];
#pragma unroll
            for (int t = 0; t < 4; ++t) {
                af[t]  = *(const bf16x8*)(Ah + (wm + t * 16 + lm) * 32 + q * 8);
                bfr[t] = *(const bf16x8*)(Bh + (wn + t * 16 + lm) * 32 + q * 8);
            }
#pragma unroll
            for (int tm = 0; tm < 4; ++tm)
#pragma unroll
                for (int tn = 0; tn < 4; ++tn)
                    acc[tm][tn] = __builtin_amdgcn_mfma_f32_16x16x32_bf16(
                        af[tm], bfr[tn], acc[tm][tn], 0, 0, 0);
        }
        __syncthreads();
    }

    // C/D layout: col=lane&15, row=(lane>>4)*4+reg (m89-verified)
    if (OUTBF16) {
        float* scratch = (float*)smem_raw + wave * (16 * 68);
#pragma unroll
        for (int tm = 0; tm < 4; ++tm) {
            __syncthreads();
#pragma unroll
            for (int tn = 0; tn < 4; ++tn) {
                float bv = BIAS ? bias[n0 + wn + tn * 16 + lm] : 0.0f;
#pragma unroll
                for (int r = 0; r < 4; ++r) {
                    float v = acc[tm][tn][r] + bv;
                    if (RELU) v = fmaxf(v, 0.0f);
                    scratch[(q * 4 + r) * 68 + tn * 16 + lm] = v;
                }
            }
            __syncthreads();
#pragma unroll
            for (int p = 0; p < 2; ++p) {
                int row16 = (lane >> 3) + p * 8;
                int c0 = (lane & 7) * 8;
                float4 v0 = *(float4*)&scratch[row16 * 68 + c0];
                float4 v1 = *(float4*)&scratch[row16 * 68 + c0 + 4];
                bf16x8 o;
                o[0] = f2bf(v0.x); o[1] = f2bf(v0.y); o[2] = f2bf(v0.z); o[3] = f2bf(v0.w);
                o[4] = f2bf(v1.x); o[5] = f2bf(v1.y); o[6] = f2bf(v1.z); o[7] = f2bf(v1.w);
                int grow = m0 + wm + tm * 16 + row16;
                if (grow < M)
                    *(bf16x8*)((short*)C + (size_t)grow * N + n0 + wn + c0) = o;
            }
        }
    } else {
#pragma unroll
        for (int tm = 0; tm < 4; ++tm)
#pragma unroll
            for (int tn = 0; tn < 4; ++tn) {
                int col = n0 + wn + tn * 16 + lm;
#pragma unroll
                for (int r = 0; r < 4; ++r) {
                    int row = m0 + wm + tm * 16 + q * 4 + r;
                    if (row < M) {
                        float v = acc[tm][tn][r];
                        if (BIAS) v += bias[col];
                        if (RELU) v = fmaxf(v, 0.0f);
                        ((float*)C)[(size_t)row * N + col] = v;
                    }
                }
            }
    }
}

// ---------------------------------------------------------------------------
// UV merge (in-place): UVa = UVa + UVb + b1 (U-half cols only).
// ---------------------------------------------------------------------------
constexpr int N4UV = BSZ * NDET * 2048 / 4;   // 393216 short4s
__global__ __launch_bounds__(256) void uvmerge_kernel(
    short* __restrict__ UVa, const short* __restrict__ UVb,
    const float* __restrict__ b1)
{
    int i = blockIdx.x * 256 + threadIdx.x;
    if (i >= N4UV) return;
    short4 a = ((const short4*)UVa)[i];
    short4 b = ((const short4*)UVb)[i];
    int col4 = i & 511;
    float4 bb = {0.0f, 0.0f, 0.0f, 0.0f};
    if (col4 < 256) bb = ((const float4*)b1)[col4];
    short4 o;
    o.x = f2bf(bf2f(a.x) + bf2f(b.x) + bb.x);
    o.y = f2bf(bf2f(a.y) + bf2f(b.y) + bb.y);
    o.z = f2bf(bf2f(a.z) + bf2f(b.z) + bb.z);
    o.w = f2bf(bf2f(a.w) + bf2f(b.w) + bb.w);
    ((short4*)UVa)[i] = o;
}

// ---------------------------------------------------------------------------
// Fused pairs + rh (one block per row), b1 baked into merged UVs.
// ---------------------------------------------------------------------------
__global__ __launch_bounds__(256) void pairs_rh_kernel(
    const short* __restrict__ UVs,
    const int* __restrict__ sids, const int* __restrict__ oids,
    short* __restrict__ h1,
    const float* __restrict__ rp, const float* __restrict__ R1,
    const float* __restrict__ rb1, short* __restrict__ rh, int b0)
{
    int r = blockIdx.x;
    int b = b0 + r / PAIRS;
    int p = r % PAIRS;
    int j = threadIdx.x;

    size_t soff = (size_t)(b * NDET + sids[p]) * 2048;
    size_t ooff = (size_t)(b * NDET + oids[p]) * 2048 + 1024;
    short4 a1 = ((const short4*)(UVs + soff))[j];
    short4 a3 = ((const short4*)(UVs + ooff))[j];
    short4 h;
    h.x = f2bf(fmaxf(bf2f(a1.x) + bf2f(a3.x), 0.0f));
    h.y = f2bf(fmaxf(bf2f(a1.y) + bf2f(a3.y), 0.0f));
    h.z = f2bf(fmaxf(bf2f(a1.z) + bf2f(a3.z), 0.0f));
    h.w = f2bf(fmaxf(bf2f(a1.w) + bf2f(a3.w), 0.0f));
    ((short4*)(h1 + (size_t)r * DH))[j] = h;

    int rg = b0 * PAIRS + r;
    const float* row = rp + (size_t)rg * 12;
    float acc = rb1[j];
#pragma unroll
    for (int k = 0; k < 12; ++k) acc = fmaf(row[k], R1[k * 256 + j], acc);
    rh[(size_t)r * 256 + j] = f2bf(fmaxf(acc, 0.0f));
}

// ---------------------------------------------------------------------------
// Fused row_prep + focal: wave-per-row. Inputs so_ext/re_ext [r][640]:
// cols 0..511 = so/re values; cols 512..603 = Lso/Lre = (so|re)·cw_c.
// logit_c = (Lso_c/||so|| + Lre_c/||re||) / (||comb||·temp),
// ||comb||^2 = 2 + 2·(so·re)/(||so||·||re||). Eliminates comb + logits GEMM
// + focal pass (the R9 tail: 3 dispatches, ~110MB round-trips).
// ---------------------------------------------------------------------------
__global__ __launch_bounds__(256) void rowprep_focal_kernel(
    const short* __restrict__ so_ext, const short* __restrict__ re_ext,
    const float* __restrict__ traj, const float* __restrict__ temperature,
    const int* __restrict__ sids, const int* __restrict__ oids,
    const int* __restrict__ labels,
    float4* __restrict__ pn, float* __restrict__ dist_arr, int b0)
{
    int wave = threadIdx.x >> 6, lane = threadIdx.x & 63;
    int r = blockIdx.x * 4 + wave;
    int rg = b0 * PAIRS + r;
    int b = b0 + r / PAIRS;
    int p = r % PAIRS;

    const short* srow = so_ext + (size_t)r * NEXT;
    const short* rrow = re_ext + (size_t)r * NEXT;
    bf16x8 sv = *(const bf16x8*)(srow + lane * 8);
    bf16x8 uv = *(const bf16x8*)(rrow + lane * 8);
    float s[8], u[8];
#pragma unroll
    for (int i = 0; i < 8; ++i) { s[i] = bf2f(sv[i]); u[i] = bf2f(uv[i]); }

    const float* tsrc = (lane < 32)
        ? (traj + (size_t)(b * NDET + sids[p]) * EHALF + lane * 8)
        : (traj + (size_t)(b * NDET + oids[p]) * EHALF + (lane - 32) * 8);
    float4 t0 = ((const float4*)tsrc)[0], t1 = ((const float4*)tsrc)[1];
    float t[8] = {t0.x, t0.y, t0.z, t0.w, t1.x, t1.y, t1.z, t1.w};

    float ss = 0.0f, sr = 0.0f, rho = 0.0f, sd = 0.0f;
#pragma unroll
    for (int i = 0; i < 8; ++i) {
        ss  += s[i] * s[i];
        sr  += u[i] * u[i];
        rho += s[i] * u[i];
        sd  += fabsf(t[i] - s[i]);
    }
#pragma unroll
    for (int m = 1; m < 64; m <<= 1) {
        ss  += __shfl_xor(ss, m);
        sr  += __shfl_xor(sr, m);
        rho += __shfl_xor(rho, m);
        sd  += __shfl_xor(sd, m);
    }
    float inv_s = 1.0f / fmaxf(sqrtf(ss), 1e-12f);
    float inv_r = 1.0f / fmaxf(sqrtf(sr), 1e-12f);
    float ncomb = sqrtf(fmaxf(2.0f + 2.0f * rho * inv_s * inv_r, 0.0f));
    float scale = 1.0f / (fmaxf(ncomb, 1e-12f) * temperature[0]);

    float flp = 0.0f, fln = 0.0f, fm = 0.0f;
    size_t labbase = (size_t)rg * LABW;
#pragma unroll
    for (int h = 0; h < 2; ++h) {
        int c = lane + h * 64;
        if (c < NCLS) {
            float l = (bf2f(srow[DE + c]) * inv_s + bf2f(rrow[DE + c]) * inv_r) * scale;
            int tl = labels[labbase + 1 + c];
            if (tl > 0) fm = 1.0f;
            float tf = (float)tl;
            float pr = 1.0f / (1.0f + expf(-l));
            float lg = log1pf(expf(-fabsf(l)));
            float ce = fmaxf(l, 0.0f) - l * tf + lg;
            float pt = pr * tf + (1.0f - pr) * (1.0f - tf);
            float om = 1.0f - pt;
            float at = 0.25f * tf + 0.75f * (1.0f - tf);
            flp += at * ce * om * om;
            float ce0 = fmaxf(l, 0.0f) + lg;
            fln += 0.75f * ce0 * pr * pr;
        }
    }
#pragma unroll
    for (int m = 1; m < 64; m <<= 1) {
        flp += __shfl_xor(flp, m);
        fln += __shfl_xor(fln, m);
        fm  += __shfl_xor(fm, m);
    }
    if (lane == 0) {
        int posf = (fm > 0.5f) ? 1 : 0;
        int negf = (labels[labbase] > 0) ? 1 : 0;
        pn[rg] = make_float4(posf ? flp : 0.0f, negf ? fln : 0.0f, 0.0f,
                             (float)(posf + 2 * negf));
        dist_arr[rg] = sd;
    }
}

// ---------------------------------------------------------------------------
// Two-stage final reduce.
// ---------------------------------------------------------------------------
struct RedRec { double sp, sn, sd; int cp, cn; };
constexpr int RED1 = 64;
constexpr int ROWS_PER_RED = ROWS / RED1;           // 564

__global__ __launch_bounds__(256) void reduce1_kernel(
    const float4* __restrict__ pn, const float* __restrict__ dist_arr,
    RedRec* __restrict__ scratch)
{
    int tid = threadIdx.x;
    int base = blockIdx.x * ROWS_PER_RED;
    double sp = 0.0, sn = 0.0, sd = 0.0;
    int cp = 0, cn = 0;
    for (int i = tid; i < ROWS_PER_RED; i += 256) {
        float4 v = pn[base + i];
        sp += (double)v.x; sn += (double)v.y; sd += (double)dist_arr[base + i];
        int f = (int)v.w;
        cp += f & 1; cn += (f >> 1) & 1;
    }
    __shared__ double A[256], B[256], C[256];
    __shared__ int I[256], J[256];
    A[tid] = sp; B[tid] = sn; C[tid] = sd; I[tid] = cp; J[tid] = cn;
    __syncthreads();
    for (int st = 128; st > 0; st >>= 1) {
        if (tid < st) { A[tid] += A[tid + st]; B[tid] += B[tid + st]; C[tid] += C[tid + st];
                        I[tid] += I[tid + st]; J[tid] += J[tid + st]; }
        __syncthreads();
    }
    if (tid == 0) {
        RedRec rec; rec.sp = A[0]; rec.sn = B[0]; rec.sd = C[0];
        rec.cp = I[0]; rec.cn = J[0];
        scratch[blockIdx.x] = rec;
    }
}

__global__ __launch_bounds__(64) void reduce2_kernel(
    const RedRec* __restrict__ scratch, float* __restrict__ out)
{
    int lane = threadIdx.x;
    RedRec rec = scratch[lane];
    double sp = rec.sp, sn = rec.sn, sd = rec.sd;
    int cp = rec.cp, cn = rec.cn;
#pragma unroll
    for (int m = 1; m < 64; m <<= 1) {
        sp += __shfl_xor(sp, m);
        sn += __shfl_xor(sn, m);
        sd += __shfl_xor(sd, m);
        cp += __shfl_xor(cp, m);
        cn += __shfl_xor(cn, m);
    }
    if (lane == 0) {
        int cpv = cp < 1 ? 1 : cp;
        int cnv = cn < 1 ? 1 : cn;
        out[0] = (float)(sp / ((double)cpv * NCLS) +
                         sn / ((double)cnv * NCLS) +
                         sd / ((double)ROWS * DE));
    }
}

static inline int pad8(int x) { return (x + 7) & ~7; }

extern "C" void kernel_launch(void* const* d_in, const int* in_sizes, int n_in,
                              void* d_out, int out_size, void* d_ws, size_t ws_size,
                              hipStream_t stream)
{
    const float* det    = (const float*)d_in[0];
    const float* traj   = (const float*)d_in[1];
    const float* relpos = (const float*)d_in[2];
    const float* cw     = (const float*)d_in[3];
    const float* W1     = (const float*)d_in[4];
    const float* b1     = (const float*)d_in[5];
    const float* W2     = (const float*)d_in[6];
    const float* b2     = (const float*)d_in[7];
    const float* W3     = (const float*)d_in[8];
    const float* R1     = (const float*)d_in[9];
    const float* rb1    = (const float*)d_in[10];
    const float* R2     = (const float*)d_in[11];
    const float* temp   = (const float*)d_in[12];
    const int*   labels = (const int*)d_in[13];
    const int*   sids   = (const int*)d_in[14];
    const int*   oids   = (const int*)d_in[15];
    float* out = (float*)d_out;

    // ---- Workspace carve --------------------------------------------------
    char* ws = (char*)d_ws;
    size_t off = 0;
    auto carve = [&](size_t bytes) -> char* {
        char* p = ws + off;
        off = (off + bytes + 255) & ~(size_t)255;
        return p;
    };
    float4* pn       = (float4*)carve((size_t)ROWS * 16);
    float*  dist_arr = (float*)carve((size_t)ROWS * 4);
    short*  det_bf   = (short*)carve((size_t)BSZ * NDET * DF * 2);
    short*  W1t      = (short*)carve((size_t)2048 * 2048 * 2);
    short*  W2t      = (short*)carve((size_t)DH * DH * 2);
    short*  W3t      = (short*)carve((size_t)NEXT * DH * 2);      // [640][1024]: W3^T | (W3·cw^T)^T
    short*  R2t      = (short*)carve((size_t)NEXT * 256 * 2);     // [640][256]:  R2^T | (R2·cw^T)^T
    short*  cwt      = (short*)carve((size_t)128 * DE * 2);
    short*  W3bf     = (short*)carve((size_t)DH * DE * 2);        // W3 bf16 [1024][512]
    short*  R2bf     = (short*)carve((size_t)256 * DE * 2);       // R2 bf16 [256][512]
    short*  UVa      = (short*)carve((size_t)BSZ * NDET * 2048 * 2);
    short*  UVb      = (short*)carve((size_t)BSZ * NDET * 2048 * 2);
    RedRec* red_scratch = (RedRec*)carve((size_t)RED1 * sizeof(RedRec));
    size_t fixed_off = off;

    // Per-chunk: reg1 (h1 bf16 [r,1024] -> so_ext bf16 [r,640]) rows*2048B,
    // reg2 (h2 bf16 [r,1024]) rows*2048B, reg3 (rh bf16 [r,256]) rows*512B,
    // reg4 (re_ext bf16 [r,640]) rows*1280B — OWN region: fixes the latent
    // R7-R9 race (re output aliased live h2). Fallback to b_ch=8 if tight.
    int b_ch = 1;
    for (int cand : {16, 8, 4, 2, 1}) {
        size_t rows  = (size_t)cand * PAIRS;
        size_t bytes = fixed_off + rows * 2048 + 256 + rows * 2048 + 256
                     + rows * 512 + 256 + rows * 1280 + 256;
        if (bytes <= ws_size) { b_ch = cand; break; }
    }
    const int chunk_rows = b_ch * PAIRS;
    const int n_chunks = BSZ / b_ch;
    char* reg1 = carve((size_t)chunk_rows * 2048);
    char* reg2 = carve((size_t)chunk_rows * 2048);
    char* reg3 = carve((size_t)chunk_rows * 512);
    char* reg4 = carve((size_t)chunk_rows * 1280);

    short* h1     = (short*)reg1;
    short* h2     = (short*)reg2;
    short* so_ext = (short*)reg1;     // overwrites h1 (dead after h2 GEMM)
    short* rh     = (short*)reg3;
    short* re_ext = (short*)reg4;

    // ---- Prep (1 launch) --------------------------------------------------
    TransJobs tj;
    tj.src[0] = W1;                    tj.dst[0] = W1t;                   tj.K[0] = DF;  tj.N[0] = DH;
    tj.src[1] = W1 + (size_t)DF * DH;  tj.dst[1] = W1t + (size_t)DH * DF; tj.K[1] = DF;  tj.N[1] = DH;
    tj.src[2] = W2;                    tj.dst[2] = W2t;                   tj.K[2] = DH;  tj.N[2] = DH;
    tj.src[3] = W3;                    tj.dst[3] = W3t;                   tj.K[3] = DH;  tj.N[3] = DE;
    tj.src[4] = R2;                    tj.dst[4] = R2t;                   tj.K[4] = 256; tj.N[4] = DE;
    tj.cum[0] = 0;
    for (int i = 0; i < 5; ++i)
        tj.cum[i + 1] = tj.cum[i] + (tj.K[i] / 32) * (tj.N[i] / 32);
    prep_kernel<<<NCONVB + tj.cum[5], 256, 0, stream>>>(
        det, det_bf, cw, cwt, W3, W3bf, R2, R2bf, tj);

    // Classifier-projection weights: W34t[c][k] = sum_m cw[c][m]·W3[k][m]
    // = (cwt @ W3bf^T): M=128, N=1024, K=512; likewise Wret with R2bf (N=256).
    // One DUAL launch, outputs land in rows 512..639 of W3t / R2t.
    mfma_gemm<false, false, true, false, true>
        <<<dim3(10, 1), 256, 0, stream>>>(
        cwt, W3bf, nullptr, W3t + (size_t)512 * DH, 128, 1024, 512, 512, 512,
        cwt, R2bf, R2t + (size_t)512 * 256, 8, 512, 512, 512, 256);

    // UV split-K halves, one DUAL launch split on bx (grid 32x6).
    mfma_gemm<false, false, true, false, true>
        <<<dim3(32, 6), 256, 0, stream>>>(
        det_bf, W1t, nullptr, UVa, BSZ * NDET, 2048, 1024, 2048, 2048,
        det_bf + 1024, W1t + 1024, UVb, 16, 1024, 2048, 2048, 2048);

    // Merge: UVa += UVb + b1 (in-place)
    uvmerge_kernel<<<(N4UV + 255) / 256, 256, 0, stream>>>(UVa, UVb, b1);

    const int mg  = (chunk_rows + 127) / 128;
    const int mgp = pad8(mg);

    for (int c = 0; c < n_chunks; ++c) {
        int b0 = c * b_ch;
        int r0 = b0 * PAIRS;

        pairs_rh_kernel<<<chunk_rows, 256, 0, stream>>>(
            UVa, sids, oids, h1, relpos, R1, rb1, rh, b0);

        // h2 = bf16(relu(h1 @ W2 + b2))
        mfma_gemm<true, true, true, true, false>
            <<<dim3(DH / 128, mgp), 256, 0, stream>>>(
            h1, W2t, b2, h2, chunk_rows, DH, DH, DH, DH,
            nullptr, nullptr, nullptr, 0, 0, 0, 0, 0);

        // so_ext = bf16(h2 @ [W3 | W3·cw^T])   (N=640, K=1024)
        // re_ext = bf16(rh @ [R2 | R2·cw^T])   (N=640, K=256) — one DUAL launch.
        mfma_gemm<false, false, true, true, true>
            <<<dim3(10, mgp), 256, 0, stream>>>(
            h2, W3t, nullptr, so_ext, chunk_rows, NEXT, DH, DH, DH,
            rh, R2t, re_ext, 5, 256, 256, 256, NEXT);

        // fused norms + combine + logits + focal + distil (no comb/logits bufs)
        rowprep_focal_kernel<<<chunk_rows / 4, 256, 0, stream>>>(
            so_ext, re_ext, traj, temp, sids, oids, labels, pn, dist_arr, b0);
    }

    reduce1_kernel<<<RED1, 256, 0, stream>>>(pn, dist_arr, red_scratch);
    reduce2_kernel<<<1, 64, 0, stream>>>(red_scratch, out);
}

// Round 11
// 370.055 us; speedup vs baseline: 13.5094x; 1.0496x over previous
//
#include <hip/hip_runtime.h>
#include <math.h>

// Problem constants
constexpr int BSZ   = 16;
constexpr int NDET  = 48;
constexpr int PAIRS = NDET * (NDET - 1);      // 2256
constexpr int ROWS  = BSZ * PAIRS;            // 36096
constexpr int DF    = 2048;
constexpr int DH    = 1024;
constexpr int DE    = 512;
constexpr int EHALF = 256;
constexpr int NCLS  = 92;
constexpr int NEXT  = DE + 128;               // 640: so/re GEMM width incl. classifier cols
constexpr int LABW  = 1 + 92 + 40;            // 133

typedef __attribute__((ext_vector_type(8))) short bf16x8;   // 8 bf16 in 4 VGPRs
typedef __attribute__((ext_vector_type(4))) float f32x4;

__device__ __forceinline__ short f2bf(float f) {
    union { float f; unsigned u; } a; a.f = f;
    unsigned r = a.u + 0x7fffu + ((a.u >> 16) & 1u);   // RNE
    return (short)(r >> 16);
}
__device__ __forceinline__ float bf2f(short h) {
    union { unsigned u; float f; } x;
    x.u = ((unsigned)(unsigned short)h) << 16;
    return x.f;
}

// ---------------------------------------------------------------------------
// Merged prep. Elementwise ranges: det conv | cwt build | W3->bf16 | R2->bf16;
// then 5-job transpose (W1 top/bot, W2, W3, R2).
// ---------------------------------------------------------------------------
constexpr int N4DET = BSZ * NDET * DF / 4;    // 393216
constexpr int N4CWT = 128 * DE / 4;           // 16384
constexpr int N4W3  = DH * DE / 4;            // 131072
constexpr int N4R2  = 256 * DE / 4;           // 32768
constexpr int NCONVB = (N4DET + N4CWT + N4W3 + N4R2) / 256;   // 2240

struct TransJobs {
    const float* src[5];
    short*       dst[5];
    int K[5], N[5];
    int cum[6];
};

__global__ __launch_bounds__(256) void prep_kernel(
    const float* __restrict__ det, short* __restrict__ det_bf,
    const float* __restrict__ cw, short* __restrict__ cwt,
    const float* __restrict__ W3, short* __restrict__ W3bf,
    const float* __restrict__ R2, short* __restrict__ R2bf,
    TransJobs jobs)
{
    if (blockIdx.x < NCONVB) {
        int i = blockIdx.x * 256 + threadIdx.x;
        const float* src; short* dst; int k;
        if (i < N4DET) { src = det; dst = det_bf; k = i; }
        else if (i < N4DET + N4CWT) {
            k = i - N4DET;
            int n = (k * 4) >> 9;
            short4 o = {0, 0, 0, 0};
            if (n < NCLS) {
                float4 v = ((const float4*)cw)[k];
                o.x = f2bf(v.x); o.y = f2bf(v.y); o.z = f2bf(v.z); o.w = f2bf(v.w);
            }
            ((short4*)cwt)[k] = o;
            return;
        }
        else if (i < N4DET + N4CWT + N4W3) { src = W3; dst = W3bf; k = i - N4DET - N4CWT; }
        else { src = R2; dst = R2bf; k = i - N4DET - N4CWT - N4W3; }
        float4 v = ((const float4*)src)[k];
        short4 o;
        o.x = f2bf(v.x); o.y = f2bf(v.y); o.z = f2bf(v.z); o.w = f2bf(v.w);
        ((short4*)dst)[k] = o;
        return;
    }
    __shared__ float tile[32][33];
    int t = blockIdx.x - NCONVB;
    int j = 0;
    while (t >= jobs.cum[j + 1]) ++j;
    int lt = t - jobs.cum[j];
    int K = jobs.K[j], N = jobs.N[j];
    int nx = N >> 5;
    int ky = lt / nx, nxi = lt - ky * nx;
    int n0 = nxi * 32, k0 = ky * 32;
    const float* src = jobs.src[j];
    short* dst = jobs.dst[j];
    int tx = threadIdx.x & 31, ty = threadIdx.x >> 5;
#pragma unroll
    for (int i = ty; i < 32; i += 8)
        tile[i][tx] = src[(size_t)(k0 + i) * N + n0 + tx];
    __syncthreads();
#pragma unroll
    for (int i = ty; i < 32; i += 8)
        dst[(size_t)(n0 + i) * K + k0 + tx] = f2bf(tile[tx][i]);
}

// ---------------------------------------------------------------------------
// MFMA GEMM core pieces (BK=64 as two 128x32 halves; R9-verified).
// ---------------------------------------------------------------------------
__device__ __forceinline__ void load16_lds(const void* g, void* l) {
    __builtin_amdgcn_global_load_lds(
        (const __attribute__((address_space(1))) unsigned int*)g,
        (__attribute__((address_space(3))) unsigned int*)l, 16, 0, 0);
}

// Main-loop GEMM (SWIZZLE/DUAL/BIAS/RELU/OUTBF16 as in R10).
template <bool BIAS, bool RELU, bool OUTBF16, bool SWIZZLE, bool DUAL>
__global__ __launch_bounds__(256, 4) void mfma_gemm(
    const short* __restrict__ A, const short* __restrict__ Bt,
    const float* __restrict__ bias, void* __restrict__ C,
    int M, int N, int K, int lda, int ldb,
    const short* A2, const short* Bt2, void* C2, int nsplit,
    int K2, int lda2, int ldb2, int N2)
{
    __shared__ __align__(16) char smem_raw[32768];   // As 16KB | Bs 16KB
    short* As = (short*)smem_raw;
    short* Bs = As + 128 * 64;

    int bx, by;
    if (SWIZZLE) {
        int nb  = gridDim.x;
        int gid = blockIdx.y * nb + blockIdx.x;
        int xcd = gid & 7;
        int j   = gid >> 3;
        int rows_per = gridDim.y >> 3;
        int lr  = j / nb;
        bx = j - lr * nb;
        by = xcd * rows_per + lr;
    } else {
        bx = blockIdx.x; by = blockIdx.y;
    }
    if (DUAL && bx >= nsplit) {
        bx -= nsplit; A = A2; Bt = Bt2; C = C2;
        K = K2; lda = lda2; ldb = ldb2; N = N2;
    }
    if (by * 128 >= M) return;                      // padded tail

    const int tid  = threadIdx.x;
    const int wave = tid >> 6;
    const int lane = tid & 63;
    const int m0 = by * 128;
    const int n0 = bx * 128;
    const int wm = (wave & 1) * 64;
    const int wn = (wave >> 1) * 64;

    f32x4 acc[4][4] = {};

    const int q  = lane >> 4;
    const int lm = lane & 15;

    for (int k0 = 0; k0 < K; k0 += 64) {
#pragma unroll
        for (int it = 0; it < 4; ++it) {
            int c    = (it & 1) * 256 + tid;
            int half = it >> 1;
            int row  = c >> 2;
            int kk   = (c & 3) * 8 + half * 32;
            int ldsc = half * 4096 + ((it & 1) * 256 + wave * 64) * 8;
            int gm = m0 + row; if (gm >= M) gm = M - 1;
            load16_lds(A + (size_t)gm * lda + k0 + kk, As + ldsc);
            int gn = n0 + row;                       // N%128==0: no tail
            load16_lds(Bt + (size_t)gn * ldb + k0 + kk, Bs + ldsc);
        }
        __syncthreads();

#pragma unroll
        for (int half = 0; half < 2; ++half) {
            const short* Ah = As + half * 4096;
            const short* Bh = Bs + half * 4096;
            bf16x8 af[4], bfr[4];
#pragma unroll
            for (int t = 0; t < 4; ++t) {
                af[t]  = *(const bf16x8*)(Ah + (wm + t * 16 + lm) * 32 + q * 8);
                bfr[t] = *(const bf16x8*)(Bh + (wn + t * 16 + lm) * 32 + q * 8);
            }
#pragma unroll
            for (int tm = 0; tm < 4; ++tm)
#pragma unroll
                for (int tn = 0; tn < 4; ++tn)
                    acc[tm][tn] = __builtin_amdgcn_mfma_f32_16x16x32_bf16(
                        af[tm], bfr[tn], acc[tm][tn], 0, 0, 0);
        }
        __syncthreads();
    }

    // C/D layout: col=lane&15, row=(lane>>4)*4+reg (m89-verified)
    if (OUTBF16) {
        float* scratch = (float*)smem_raw + wave * (16 * 68);
#pragma unroll
        for (int tm = 0; tm < 4; ++tm) {
            __syncthreads();
#pragma unroll
            for (int tn = 0; tn < 4; ++tn) {
                float bv = BIAS ? bias[n0 + wn + tn * 16 + lm] : 0.0f;
#pragma unroll
                for (int r = 0; r < 4; ++r) {
                    float v = acc[tm][tn][r] + bv;
                    if (RELU) v = fmaxf(v, 0.0f);
                    scratch[(q * 4 + r) * 68 + tn * 16 + lm] = v;
                }
            }
            __syncthreads();
#pragma unroll
            for (int p = 0; p < 2; ++p) {
                int row16 = (lane >> 3) + p * 8;
                int c0 = (lane & 7) * 8;
                float4 v0 = *(float4*)&scratch[row16 * 68 + c0];
                float4 v1 = *(float4*)&scratch[row16 * 68 + c0 + 4];
                bf16x8 o;
                o[0] = f2bf(v0.x); o[1] = f2bf(v0.y); o[2] = f2bf(v0.z); o[3] = f2bf(v0.w);
                o[4] = f2bf(v1.x); o[5] = f2bf(v1.y); o[6] = f2bf(v1.z); o[7] = f2bf(v1.w);
                int grow = m0 + wm + tm * 16 + row16;
                if (grow < M)
                    *(bf16x8*)((short*)C + (size_t)grow * N + n0 + wn + c0) = o;
            }
        }
    } else {
#pragma unroll
        for (int tm = 0; tm < 4; ++tm)
#pragma unroll
            for (int tn = 0; tn < 4; ++tn) {
                int col = n0 + wn + tn * 16 + lm;
#pragma unroll
                for (int r = 0; r < 4; ++r) {
                    int row = m0 + wm + tm * 16 + q * 4 + r;
                    if (row < M) {
                        float v = acc[tm][tn][r];
                        if (BIAS) v += bias[col];
                        if (RELU) v = fmaxf(v, 0.0f);
                        ((float*)C)[(size_t)row * N + col] = v;
                    }
                }
            }
    }
}

// ---------------------------------------------------------------------------
// Multi-job GEMM (up to 4 independent bf16-out jobs, flat 1-D grid).
// R11: merges the UV split-K pair + the two classifier-projection jobs into
// ONE 202-block launch (was 10-block proj launch + 192-block UV launch —
// the 10-block launch ran alone on a 256-CU chip).
// ---------------------------------------------------------------------------
struct GemmJobs {
    const short* A[4]; const short* Bt[4]; short* C[4];
    int M[4], N[4], K[4], lda[4], ldb[4];
    int cum[5];
};

__global__ __launch_bounds__(256, 4) void mfma_gemm_multi(GemmJobs jobs)
{
    __shared__ __align__(16) char smem_raw[32768];
    short* As = (short*)smem_raw;
    short* Bs = As + 128 * 64;

    int bid = blockIdx.x;
    int j = 0;
    while (bid >= jobs.cum[j + 1]) ++j;             // <=4, block-uniform
    int lt = bid - jobs.cum[j];
    const short* A  = jobs.A[j];
    const short* Bt = jobs.Bt[j];
    short* C = jobs.C[j];
    int M = jobs.M[j], N = jobs.N[j], K = jobs.K[j];
    int lda = jobs.lda[j], ldb = jobs.ldb[j];
    int ncols = N >> 7;
    int by = lt / ncols;
    int bx = lt - by * ncols;

    const int tid  = threadIdx.x;
    const int wave = tid >> 6;
    const int lane = tid & 63;
    const int m0 = by * 128;
    const int n0 = bx * 128;
    const int wm = (wave & 1) * 64;
    const int wn = (wave >> 1) * 64;

    f32x4 acc[4][4] = {};
    const int q  = lane >> 4;
    const int lm = lane & 15;

    for (int k0 = 0; k0 < K; k0 += 64) {
#pragma unroll
        for (int it = 0; it < 4; ++it) {
            int c    = (it & 1) * 256 + tid;
            int half = it >> 1;
            int row  = c >> 2;
            int kk   = (c & 3) * 8 + half * 32;
            int ldsc = half * 4096 + ((it & 1) * 256 + wave * 64) * 8;
            int gm = m0 + row; if (gm >= M) gm = M - 1;
            load16_lds(A + (size_t)gm * lda + k0 + kk, As + ldsc);
            load16_lds(Bt + (size_t)(n0 + row) * ldb + k0 + kk, Bs + ldsc);
        }
        __syncthreads();
#pragma unroll
        for (int half = 0; half < 2; ++half) {
            const short* Ah = As + half * 4096;
            const short* Bh = Bs + half * 4096;
            bf16x8 af[4], bfr[4];
#pragma unroll
            for (int t = 0; t < 4; ++t) {
                af[t]  = *(const bf16x8*)(Ah + (wm + t * 16 + lm) * 32 + q * 8);
                bfr[t] = *(const bf16x8*)(Bh + (wn + t * 16 + lm) * 32 + q * 8);
            }
#pragma unroll
            for (int tm = 0; tm < 4; ++tm)
#pragma unroll
                for (int tn = 0; tn < 4; ++tn)
                    acc[tm][tn] = __builtin_amdgcn_mfma_f32_16x16x32_bf16(
                        af[tm], bfr[tn], acc[tm][tn], 0, 0, 0);
        }
        __syncthreads();
    }

    float* scratch = (float*)smem_raw + wave * (16 * 68);
#pragma unroll
    for (int tm = 0; tm < 4; ++tm) {
        __syncthreads();
#pragma unroll
        for (int tn = 0; tn < 4; ++tn)
#pragma unroll
            for (int r = 0; r < 4; ++r)
                scratch[(q * 4 + r) * 68 + tn * 16 + lm] = acc[tm][tn][r];
        __syncthreads();
#pragma unroll
        for (int p = 0; p < 2; ++p) {
            int row16 = (lane >> 3) + p * 8;
            int c0 = (lane & 7) * 8;
            float4 v0 = *(float4*)&scratch[row16 * 68 + c0];
            float4 v1 = *(float4*)&scratch[row16 * 68 + c0 + 4];
            bf16x8 o;
            o[0] = f2bf(v0.x); o[1] = f2bf(v0.y); o[2] = f2bf(v0.z); o[3] = f2bf(v0.w);
            o[4] = f2bf(v1.x); o[5] = f2bf(v1.y); o[6] = f2bf(v1.z); o[7] = f2bf(v1.w);
            int grow = m0 + wm + tm * 16 + row16;
            if (grow < M)
                *(bf16x8*)(C + (size_t)grow * N + n0 + wn + c0) = o;
        }
    }
}

// ---------------------------------------------------------------------------
// UV merge (in-place): UVa = UVa + UVb + b1 (U-half cols only).
// ---------------------------------------------------------------------------
constexpr int N4UV = BSZ * NDET * 2048 / 4;   // 393216 short4s
__global__ __launch_bounds__(256) void uvmerge_kernel(
    short* __restrict__ UVa, const short* __restrict__ UVb,
    const float* __restrict__ b1)
{
    int i = blockIdx.x * 256 + threadIdx.x;
    if (i >= N4UV) return;
    short4 a = ((const short4*)UVa)[i];
    short4 b = ((const short4*)UVb)[i];
    int col4 = i & 511;
    float4 bb = {0.0f, 0.0f, 0.0f, 0.0f};
    if (col4 < 256) bb = ((const float4*)b1)[col4];
    short4 o;
    o.x = f2bf(bf2f(a.x) + bf2f(b.x) + bb.x);
    o.y = f2bf(bf2f(a.y) + bf2f(b.y) + bb.y);
    o.z = f2bf(bf2f(a.z) + bf2f(b.z) + bb.z);
    o.w = f2bf(bf2f(a.w) + bf2f(b.w) + bb.w);
    ((short4*)UVa)[i] = o;
}

// ---------------------------------------------------------------------------
// Fused pairs + rh: wave-per-row (R11: grid 36096->9024 blocks, 1/4 the
// per-block dispatch overhead; traffic & math unchanged).
// ---------------------------------------------------------------------------
__global__ __launch_bounds__(256) void pairs_rh_kernel(
    const short* __restrict__ UVs,
    const int* __restrict__ sids, const int* __restrict__ oids,
    short* __restrict__ h1,
    const float* __restrict__ rp, const float* __restrict__ R1,
    const float* __restrict__ rb1, short* __restrict__ rh, int b0)
{
    int wave = threadIdx.x >> 6, lane = threadIdx.x & 63;
    int r = blockIdx.x * 4 + wave;
    int b = b0 + r / PAIRS;
    int p = r % PAIRS;

    const bf16x8* us = (const bf16x8*)(UVs + (size_t)(b * NDET + sids[p]) * 2048);
    const bf16x8* uo = (const bf16x8*)(UVs + (size_t)(b * NDET + oids[p]) * 2048 + 1024);
    bf16x8* hrow = (bf16x8*)(h1 + (size_t)r * DH);
#pragma unroll
    for (int i = 0; i < 2; ++i) {
        int idx = lane + i * 64;            // 128 bf16x8 per 1024-elem row
        bf16x8 a = us[idx], c = uo[idx];
        bf16x8 h;
#pragma unroll
        for (int e = 0; e < 8; ++e)
            h[e] = f2bf(fmaxf(bf2f(a[e]) + bf2f(c[e]), 0.0f));
        hrow[idx] = h;
    }

    // rh: 256 cols, 4 per lane
    int rg = b0 * PAIRS + r;
    const float* rowp = rp + (size_t)rg * 12;
    float4 acc = ((const float4*)rb1)[lane];
#pragma unroll
    for (int k = 0; k < 12; ++k) {
        float rv = rowp[k];
        float4 w = ((const float4*)(R1 + k * 256))[lane];
        acc.x = fmaf(rv, w.x, acc.x);
        acc.y = fmaf(rv, w.y, acc.y);
        acc.z = fmaf(rv, w.z, acc.z);
        acc.w = fmaf(rv, w.w, acc.w);
    }
    short4 o;
    o.x = f2bf(fmaxf(acc.x, 0.0f));
    o.y = f2bf(fmaxf(acc.y, 0.0f));
    o.z = f2bf(fmaxf(acc.z, 0.0f));
    o.w = f2bf(fmaxf(acc.w, 0.0f));
    ((short4*)(rh + (size_t)r * 256))[lane] = o;
}

// ---------------------------------------------------------------------------
// Fused row_prep + focal: wave-per-row (R10 algebra: logits from extended
// GEMM columns; ||comb||^2 = 2 + 2*rho/(||so||*||re||)).
// ---------------------------------------------------------------------------
__global__ __launch_bounds__(256) void rowprep_focal_kernel(
    const short* __restrict__ so_ext, const short* __restrict__ re_ext,
    const float* __restrict__ traj, const float* __restrict__ temperature,
    const int* __restrict__ sids, const int* __restrict__ oids,
    const int* __restrict__ labels,
    float4* __restrict__ pn, float* __restrict__ dist_arr, int b0)
{
    int wave = threadIdx.x >> 6, lane = threadIdx.x & 63;
    int r = blockIdx.x * 4 + wave;
    int rg = b0 * PAIRS + r;
    int b = b0 + r / PAIRS;
    int p = r % PAIRS;

    const short* srow = so_ext + (size_t)r * NEXT;
    const short* rrow = re_ext + (size_t)r * NEXT;
    bf16x8 sv = *(const bf16x8*)(srow + lane * 8);
    bf16x8 uv = *(const bf16x8*)(rrow + lane * 8);
    float s[8], u[8];
#pragma unroll
    for (int i = 0; i < 8; ++i) { s[i] = bf2f(sv[i]); u[i] = bf2f(uv[i]); }

    const float* tsrc = (lane < 32)
        ? (traj + (size_t)(b * NDET + sids[p]) * EHALF + lane * 8)
        : (traj + (size_t)(b * NDET + oids[p]) * EHALF + (lane - 32) * 8);
    float4 t0 = ((const float4*)tsrc)[0], t1 = ((const float4*)tsrc)[1];
    float t[8] = {t0.x, t0.y, t0.z, t0.w, t1.x, t1.y, t1.z, t1.w};

    float ss = 0.0f, sr = 0.0f, rho = 0.0f, sd = 0.0f;
#pragma unroll
    for (int i = 0; i < 8; ++i) {
        ss  += s[i] * s[i];
        sr  += u[i] * u[i];
        rho += s[i] * u[i];
        sd  += fabsf(t[i] - s[i]);
    }
#pragma unroll
    for (int m = 1; m < 64; m <<= 1) {
        ss  += __shfl_xor(ss, m);
        sr  += __shfl_xor(sr, m);
        rho += __shfl_xor(rho, m);
        sd  += __shfl_xor(sd, m);
    }
    float inv_s = 1.0f / fmaxf(sqrtf(ss), 1e-12f);
    float inv_r = 1.0f / fmaxf(sqrtf(sr), 1e-12f);
    float ncomb = sqrtf(fmaxf(2.0f + 2.0f * rho * inv_s * inv_r, 0.0f));
    float scale = 1.0f / (fmaxf(ncomb, 1e-12f) * temperature[0]);

    float flp = 0.0f, fln = 0.0f, fm = 0.0f;
    size_t labbase = (size_t)rg * LABW;
#pragma unroll
    for (int h = 0; h < 2; ++h) {
        int c = lane + h * 64;
        if (c < NCLS) {
            float l = (bf2f(srow[DE + c]) * inv_s + bf2f(rrow[DE + c]) * inv_r) * scale;
            int tl = labels[labbase + 1 + c];
            if (tl > 0) fm = 1.0f;
            float tf = (float)tl;
            float pr = 1.0f / (1.0f + expf(-l));
            float lg = log1pf(expf(-fabsf(l)));
            float ce = fmaxf(l, 0.0f) - l * tf + lg;
            float pt = pr * tf + (1.0f - pr) * (1.0f - tf);
            float om = 1.0f - pt;
            float at = 0.25f * tf + 0.75f * (1.0f - tf);
            flp += at * ce * om * om;
            float ce0 = fmaxf(l, 0.0f) + lg;
            fln += 0.75f * ce0 * pr * pr;
        }
    }
#pragma unroll
    for (int m = 1; m < 64; m <<= 1) {
        flp += __shfl_xor(flp, m);
        fln += __shfl_xor(fln, m);
        fm  += __shfl_xor(fm, m);
    }
    if (lane == 0) {
        int posf = (fm > 0.5f) ? 1 : 0;
        int negf = (labels[labbase] > 0) ? 1 : 0;
        pn[rg] = make_float4(posf ? flp : 0.0f, negf ? fln : 0.0f, 0.0f,
                             (float)(posf + 2 * negf));
        dist_arr[rg] = sd;
    }
}

// ---------------------------------------------------------------------------
// Two-stage final reduce.
// ---------------------------------------------------------------------------
struct RedRec { double sp, sn, sd; int cp, cn; };
constexpr int RED1 = 64;
constexpr int ROWS_PER_RED = ROWS / RED1;           // 564

__global__ __launch_bounds__(256) void reduce1_kernel(
    const float4* __restrict__ pn, const float* __restrict__ dist_arr,
    RedRec* __restrict__ scratch)
{
    int tid = threadIdx.x;
    int base = blockIdx.x * ROWS_PER_RED;
    double sp = 0.0, sn = 0.0, sd = 0.0;
    int cp = 0, cn = 0;
    for (int i = tid; i < ROWS_PER_RED; i += 256) {
        float4 v = pn[base + i];
        sp += (double)v.x; sn += (double)v.y; sd += (double)dist_arr[base + i];
        int f = (int)v.w;
        cp += f & 1; cn += (f >> 1) & 1;
    }
    __shared__ double A[256], B[256], C[256];
    __shared__ int I[256], J[256];
    A[tid] = sp; B[tid] = sn; C[tid] = sd; I[tid] = cp; J[tid] = cn;
    __syncthreads();
    for (int st = 128; st > 0; st >>= 1) {
        if (tid < st) { A[tid] += A[tid + st]; B[tid] += B[tid + st]; C[tid] += C[tid + st];
                        I[tid] += I[tid + st]; J[tid] += J[tid + st]; }
        __syncthreads();
    }
    if (tid == 0) {
        RedRec rec; rec.sp = A[0]; rec.sn = B[0]; rec.sd = C[0];
        rec.cp = I[0]; rec.cn = J[0];
        scratch[blockIdx.x] = rec;
    }
}

__global__ __launch_bounds__(64) void reduce2_kernel(
    const RedRec* __restrict__ scratch, float* __restrict__ out)
{
    int lane = threadIdx.x;
    RedRec rec = scratch[lane];
    double sp = rec.sp, sn = rec.sn, sd = rec.sd;
    int cp = rec.cp, cn = rec.cn;
#pragma unroll
    for (int m = 1; m < 64; m <<= 1) {
        sp += __shfl_xor(sp, m);
        sn += __shfl_xor(sn, m);
        sd += __shfl_xor(sd, m);
        cp += __shfl_xor(cp, m);
        cn += __shfl_xor(cn, m);
    }
    if (lane == 0) {
        int cpv = cp < 1 ? 1 : cp;
        int cnv = cn < 1 ? 1 : cn;
        out[0] = (float)(sp / ((double)cpv * NCLS) +
                         sn / ((double)cnv * NCLS) +
                         sd / ((double)ROWS * DE));
    }
}

static inline int pad8(int x) { return (x + 7) & ~7; }

extern "C" void kernel_launch(void* const* d_in, const int* in_sizes, int n_in,
                              void* d_out, int out_size, void* d_ws, size_t ws_size,
                              hipStream_t stream)
{
    const float* det    = (const float*)d_in[0];
    const float* traj   = (const float*)d_in[1];
    const float* relpos = (const float*)d_in[2];
    const float* cw     = (const float*)d_in[3];
    const float* W1     = (const float*)d_in[4];
    const float* b1     = (const float*)d_in[5];
    const float* W2     = (const float*)d_in[6];
    const float* b2     = (const float*)d_in[7];
    const float* W3     = (const float*)d_in[8];
    const float* R1     = (const float*)d_in[9];
    const float* rb1    = (const float*)d_in[10];
    const float* R2     = (const float*)d_in[11];
    const float* temp   = (const float*)d_in[12];
    const int*   labels = (const int*)d_in[13];
    const int*   sids   = (const int*)d_in[14];
    const int*   oids   = (const int*)d_in[15];
    float* out = (float*)d_out;

    // ---- Workspace carve --------------------------------------------------
    char* ws = (char*)d_ws;
    size_t off = 0;
    auto carve = [&](size_t bytes) -> char* {
        char* p = ws + off;
        off = (off + bytes + 255) & ~(size_t)255;
        return p;
    };
    float4* pn       = (float4*)carve((size_t)ROWS * 16);
    float*  dist_arr = (float*)carve((size_t)ROWS * 4);
    short*  det_bf   = (short*)carve((size_t)BSZ * NDET * DF * 2);
    short*  W1t      = (short*)carve((size_t)2048 * 2048 * 2);
    short*  W2t      = (short*)carve((size_t)DH * DH * 2);
    short*  W3t      = (short*)carve((size_t)NEXT * DH * 2);      // [640][1024]
    short*  R2t      = (short*)carve((size_t)NEXT * 256 * 2);     // [640][256]
    short*  cwt      = (short*)carve((size_t)128 * DE * 2);
    short*  W3bf     = (short*)carve((size_t)DH * DE * 2);
    short*  R2bf     = (short*)carve((size_t)256 * DE * 2);
    short*  UVa      = (short*)carve((size_t)BSZ * NDET * 2048 * 2);
    short*  UVb      = (short*)carve((size_t)BSZ * NDET * 2048 * 2);
    RedRec* red_scratch = (RedRec*)carve((size_t)RED1 * sizeof(RedRec));
    size_t fixed_off = off;

    int b_ch = 1;
    for (int cand : {16, 8, 4, 2, 1}) {
        size_t rows  = (size_t)cand * PAIRS;
        size_t bytes = fixed_off + rows * 2048 + 256 + rows * 2048 + 256
                     + rows * 512 + 256 + rows * 1280 + 256;
        if (bytes <= ws_size) { b_ch = cand; break; }
    }
    const int chunk_rows = b_ch * PAIRS;
    const int n_chunks = BSZ / b_ch;
    char* reg1 = carve((size_t)chunk_rows * 2048);
    char* reg2 = carve((size_t)chunk_rows * 2048);
    char* reg3 = carve((size_t)chunk_rows * 512);
    char* reg4 = carve((size_t)chunk_rows * 1280);

    short* h1     = (short*)reg1;
    short* h2     = (short*)reg2;
    short* so_ext = (short*)reg1;     // overwrites h1 (dead after h2 GEMM)
    short* rh     = (short*)reg3;
    short* re_ext = (short*)reg4;     // own region (R10 race fix)

    // ---- Prep (1 launch) --------------------------------------------------
    TransJobs tj;
    tj.src[0] = W1;                    tj.dst[0] = W1t;                   tj.K[0] = DF;  tj.N[0] = DH;
    tj.src[1] = W1 + (size_t)DF * DH;  tj.dst[1] = W1t + (size_t)DH * DF; tj.K[1] = DF;  tj.N[1] = DH;
    tj.src[2] = W2;                    tj.dst[2] = W2t;                   tj.K[2] = DH;  tj.N[2] = DH;
    tj.src[3] = W3;                    tj.dst[3] = W3t;                   tj.K[3] = DH;  tj.N[3] = DE;
    tj.src[4] = R2;                    tj.dst[4] = R2t;                   tj.K[4] = 256; tj.N[4] = DE;
    tj.cum[0] = 0;
    for (int i = 0; i < 5; ++i)
        tj.cum[i + 1] = tj.cum[i] + (tj.K[i] / 32) * (tj.N[i] / 32);
    prep_kernel<<<NCONVB + tj.cum[5], 256, 0, stream>>>(
        det, det_bf, cw, cwt, W3, W3bf, R2, R2bf, tj);

    // One multi-job GEMM launch: UV split-K halves + classifier projections.
    GemmJobs gj;
    gj.A[0] = det_bf;        gj.Bt[0] = W1t;        gj.C[0] = UVa;
    gj.M[0] = BSZ * NDET;    gj.N[0] = 2048;        gj.K[0] = 1024;
    gj.lda[0] = 2048;        gj.ldb[0] = 2048;
    gj.A[1] = det_bf + 1024; gj.Bt[1] = W1t + 1024; gj.C[1] = UVb;
    gj.M[1] = BSZ * NDET;    gj.N[1] = 2048;        gj.K[1] = 1024;
    gj.lda[1] = 2048;        gj.ldb[1] = 2048;
    gj.A[2] = cwt;           gj.Bt[2] = W3bf;       gj.C[2] = W3t + (size_t)512 * DH;
    gj.M[2] = 128;           gj.N[2] = 1024;        gj.K[2] = 512;
    gj.lda[2] = 512;         gj.ldb[2] = 512;
    gj.A[3] = cwt;           gj.Bt[3] = R2bf;       gj.C[3] = R2t + (size_t)512 * 256;
    gj.M[3] = 128;           gj.N[3] = 256;         gj.K[3] = 512;
    gj.lda[3] = 512;         gj.ldb[3] = 512;
    gj.cum[0] = 0;
    for (int i = 0; i < 4; ++i)
        gj.cum[i + 1] = gj.cum[i] + (gj.N[i] / 128) * ((gj.M[i] + 127) / 128);
    mfma_gemm_multi<<<gj.cum[4], 256, 0, stream>>>(gj);   // 202 blocks

    // Merge: UVa += UVb + b1 (in-place)
    uvmerge_kernel<<<(N4UV + 255) / 256, 256, 0, stream>>>(UVa, UVb, b1);

    const int mg  = (chunk_rows + 127) / 128;
    const int mgp = pad8(mg);

    for (int c = 0; c < n_chunks; ++c) {
        int b0 = c * b_ch;

        pairs_rh_kernel<<<chunk_rows / 4, 256, 0, stream>>>(
            UVa, sids, oids, h1, relpos, R1, rb1, rh, b0);

        // h2 = bf16(relu(h1 @ W2 + b2))
        mfma_gemm<true, true, true, true, false>
            <<<dim3(DH / 128, mgp), 256, 0, stream>>>(
            h1, W2t, b2, h2, chunk_rows, DH, DH, DH, DH,
            nullptr, nullptr, nullptr, 0, 0, 0, 0, 0);

        // so_ext = bf16(h2 @ [W3 | W3·cw^T]) + re_ext = bf16(rh @ [R2 | R2·cw^T])
        mfma_gemm<false, false, true, true, true>
            <<<dim3(10, mgp), 256, 0, stream>>>(
            h2, W3t, nullptr, so_ext, chunk_rows, NEXT, DH, DH, DH,
            rh, R2t, re_ext, 5, 256, 256, 256, NEXT);

        rowprep_focal_kernel<<<chunk_rows / 4, 256, 0, stream>>>(
            so_ext, re_ext, traj, temp, sids, oids, labels, pn, dist_arr, b0);
    }

    reduce1_kernel<<<RED1, 256, 0, stream>>>(pn, dist_arr, red_scratch);
    reduce2_kernel<<<1, 64, 0, stream>>>(red_scratch, out);
}